// Round 3
// baseline (1291.722 us; speedup 1.0000x reference)
//
#include <hip/hip_runtime.h>
#include <hip/hip_bf16.h>

#define N_NODESC 50000
#define N_EDGESC 800000
#define N_GRAPHSC 512
#define HDIM 64
#define FNODE 32
#define FEDGE 8
#define NCLS 10
#define BN_EPS 1e-5f
#define SCAN_B 256
#define SCAN_G 196  // 196*256 = 50176 >= 50000

typedef __bf16 bf16x8 __attribute__((ext_vector_type(8)));
typedef float f32x4 __attribute__((ext_vector_type(4)));
typedef unsigned int uint32;

static __device__ __forceinline__ float bcast(float v, int k) {
  return __uint_as_float(__builtin_amdgcn_readlane(__float_as_uint(v), k));
}

// ---------------- degree ----------------
__global__ void k_deg(const int* __restrict__ dst, uint32* __restrict__ degi) {
  int e = blockIdx.x * blockDim.x + threadIdx.x;
  if (e < N_EDGESC) atomicAdd(&degi[dst[e]], 1u);
}

__global__ void k_dinv(const uint32* __restrict__ degi, float* __restrict__ dinv) {
  int n = blockIdx.x * blockDim.x + threadIdx.x;
  if (n < N_NODESC) dinv[n] = rsqrtf(fmaxf((float)degi[n], 1.0f));
}

// ---------------- exclusive prefix sum over degi -> ptr ----------------
__global__ void k_scan1(const uint32* __restrict__ degi, uint32* __restrict__ ptr,
                        uint32* __restrict__ bsum) {
  __shared__ uint32 s[SCAN_B];
  int t = threadIdx.x;
  int i = blockIdx.x * SCAN_B + t;
  uint32 v = (i < N_NODESC) ? degi[i] : 0u;
  s[t] = v; __syncthreads();
  for (int off = 1; off < SCAN_B; off <<= 1) {
    uint32 x = (t >= off) ? s[t - off] : 0u; __syncthreads();
    s[t] += x; __syncthreads();
  }
  if (i < N_NODESC) ptr[i] = s[t] - v;  // exclusive local scan
  if (t == SCAN_B - 1) bsum[blockIdx.x] = s[t];
}

__global__ void k_scan2(uint32* __restrict__ bsum) {
  __shared__ uint32 s[256];
  int t = threadIdx.x;
  uint32 v = (t < SCAN_G) ? bsum[t] : 0u;
  s[t] = v; __syncthreads();
  for (int off = 1; off < 256; off <<= 1) {
    uint32 x = (t >= off) ? s[t - off] : 0u; __syncthreads();
    s[t] += x; __syncthreads();
  }
  if (t < SCAN_G) bsum[t] = s[t] - v;  // exclusive
}

__global__ void k_scan3(uint32* __restrict__ ptr, const uint32* __restrict__ bsum) {
  int i = blockIdx.x * SCAN_B + threadIdx.x;
  if (i < N_NODESC) ptr[i] += bsum[blockIdx.x];
}

// ---------------- scatter edges into dst-sorted order ----------------
__global__ void k_scatter(const int* __restrict__ src, const int* __restrict__ dst,
                          const uint32* __restrict__ ptr, uint32* __restrict__ cursor,
                          int* __restrict__ srcs, int* __restrict__ dsts,
                          int* __restrict__ eorig) {
  int e = blockIdx.x * blockDim.x + threadIdx.x;
  if (e < N_EDGESC) {
    int d = dst[e];
    uint32 r = atomicAdd(&cursor[d], 1u);
    uint32 i = ptr[d] + r;
    srcs[i] = src[e];
    dsts[i] = d;
    eorig[i] = e;
  }
}

// ---------------- column stats (sum, sumsq) ----------------
template <int C>
__global__ void k_colstats(const float* __restrict__ in, int nrows, float* __restrict__ stats) {
  const int RPB = 256 / C;
  int tid = threadIdx.x;
  int col = tid % C;
  int rowOff = tid / C;
  float s = 0.f, s2 = 0.f;
  for (int r = blockIdx.x * RPB + rowOff; r < nrows; r += gridDim.x * RPB) {
    float v = in[r * C + col];
    s += v; s2 += v * v;
  }
  __shared__ float ls[256], ls2[256];
  ls[tid] = s; ls2[tid] = s2;
  __syncthreads();
  for (int off = 128; off >= C; off >>= 1) {
    if (tid < off) { ls[tid] += ls[tid + off]; ls2[tid] += ls2[tid + off]; }
    __syncthreads();
  }
  if (tid < C) {
    atomicAdd(&stats[tid], ls[tid]);
    atomicAdd(&stats[C + tid], ls2[tid]);
  }
}

// ---------------- fold BN into weights ----------------
template <int CIN, int COUT>
__global__ void k_foldbn(const float* __restrict__ stats, float invN,
                         const float* __restrict__ bnw, const float* __restrict__ bnb,
                         const float* __restrict__ W, const float* __restrict__ bias,
                         float* __restrict__ Wf, float* __restrict__ bf) {
  __shared__ float a[CIN], sh[CIN];
  int tid = threadIdx.x;
  if (tid < CIN) {
    float m = stats[tid] * invN;
    float v = stats[CIN + tid] * invN - m * m;
    float inv = rsqrtf(v + BN_EPS);
    float aa = bnw[tid] * inv;
    a[tid] = aa;
    sh[tid] = bnb[tid] - m * aa;
  }
  __syncthreads();
  for (int i = tid; i < CIN * COUT; i += 256) {
    int r = i / COUT;
    Wf[i] = a[r] * W[i];
  }
  if (tid < COUT) {
    float acc = bias ? bias[tid] : 0.f;
    for (int r = 0; r < CIN; ++r) acc += sh[r] * W[r * COUT + tid];
    bf[tid] = acc;
  }
}

// ---------------- out[N,64] = in[N,K](ld LDIN) @ W[K,64] + bias ----------------
template <int K, bool RELU, int LDIN, int LDOUT>
__global__ void k_nodemm(const float* __restrict__ in, int nrows,
                         const float* __restrict__ W, const float* __restrict__ bias,
                         float* __restrict__ out) {
  int tid = threadIdx.x;
  int lane = tid & 63;
  float w[K];
#pragma unroll
  for (int k = 0; k < K; ++k) w[k] = W[k * 64 + lane];
  float bv = bias ? bias[lane] : 0.f;
  int wave = (blockIdx.x * blockDim.x + tid) >> 6;
  int nwaves = (gridDim.x * blockDim.x) >> 6;
  for (int r = wave; r < nrows; r += nwaves) {
    float rv = (lane < K) ? in[(size_t)r * LDIN + lane] : 0.f;
    float acc = bv;
#pragma unroll
    for (int k = 0; k < K; ++k) acc = fmaf(bcast(rv, k), w[k], acc);
    if (RELU) acc = fmaxf(acc, 0.f);
    out[(size_t)r * LDOUT + lane] = acc;
  }
}

// ---------------- e = relu(hA[src]+hB[dst]+ea@We0c) -> bf16 (sorted order) + normf ----------------
__global__ void k_edgeinit(const float* __restrict__ hA, const float* __restrict__ hB,
                           const float* __restrict__ ea, const float* __restrict__ Wc,
                           const int* __restrict__ srcs, const int* __restrict__ dsts,
                           const int* __restrict__ eorig, const float* __restrict__ dinv,
                           __hip_bfloat16* __restrict__ ebf, float* __restrict__ normf) {
  int tid = threadIdx.x;
  int lane = tid & 63;
  float w[FEDGE];
#pragma unroll
  for (int k = 0; k < FEDGE; ++k) w[k] = Wc[k * 64 + lane];
  int wave = (blockIdx.x * blockDim.x + tid) >> 6;
  int nwaves = (gridDim.x * blockDim.x) >> 6;
  for (int e = wave; e < N_EDGESC; e += nwaves) {
    int s = srcs[e], d = dsts[e], eo = eorig[e];
    float av = (lane < FEDGE) ? ea[(size_t)eo * FEDGE + lane] : 0.f;
    float acc = hA[s * 64 + lane] + hB[d * 64 + lane];
#pragma unroll
    for (int k = 0; k < FEDGE; ++k) acc = fmaf(bcast(av, k), w[k], acc);
    acc = fmaxf(acc, 0.f);
    ebf[(size_t)e * 64 + lane] = __float2bfloat16(acc);
    if (lane == 0) normf[e] = dinv[s] * dinv[d];
  }
}

// ---------------- edge-gated conv, MFMA gate GEMM, dst-sorted run-accumulate ----------------
// htS: [N,128] interleaved -> htS[s*128+c] = ht (message source), htS[s*128+64+c] = htA
__global__ void __launch_bounds__(256) k_conv_mfma(
    const __hip_bfloat16* __restrict__ ebf,
    const float* __restrict__ We2,
    const float* __restrict__ htS, const float* __restrict__ htB,
    const float* __restrict__ normf,
    const int* __restrict__ srcs, const int* __restrict__ dsts,
    float* __restrict__ hacc) {
  const int lane = threadIdx.x & 63;
  const int m  = lane & 15;   // A-row / B-col within 16-tile
  const int kg = lane >> 4;   // k-group

  // B fragments: b[t][s] -> B[k = s*32 + kg*8 + j][c = t*16 + m]
  bf16x8 b[4][2];
#pragma unroll
  for (int t = 0; t < 4; ++t)
#pragma unroll
    for (int s = 0; s < 2; ++s)
#pragma unroll
      for (int j = 0; j < 8; ++j) {
        int k = s * 32 + kg * 8 + j;
        int c = t * 16 + m;
        b[t][s][j] = (__bf16)We2[k * 64 + c];
      }

  int wave = (blockIdx.x * blockDim.x + threadIdx.x) >> 6;
  int nwaves = (gridDim.x * blockDim.x) >> 6;
  const int ntiles = N_EDGESC / 16;
  for (int tile = wave; tile < ntiles; tile += nwaves) {
    int base = tile * 16;
    const __hip_bfloat16* arow = ebf + (size_t)(base + m) * 64 + kg * 8;
    bf16x8 a0 = *reinterpret_cast<const bf16x8*>(arow);
    bf16x8 a1 = *reinterpret_cast<const bf16x8*>(arow + 32);
    f32x4 acc[4];
#pragma unroll
    for (int t = 0; t < 4; ++t) {
      f32x4 z = {0.f, 0.f, 0.f, 0.f};
      acc[t] = __builtin_amdgcn_mfma_f32_16x16x32_bf16(a0, b[t][0], z, 0, 0, 0);
      acc[t] = __builtin_amdgcn_mfma_f32_16x16x32_bf16(a1, b[t][1], acc[t], 0, 0, 0);
    }
    // D mapping: lane holds col c=t*16+m, rows r = kg*4+j (consecutive sorted edges)
    int rbase = base + kg * 4;
    float run[4] = {0.f, 0.f, 0.f, 0.f};
    int dcur = dsts[rbase];
#pragma unroll
    for (int j = 0; j < 4; ++j) {
      int er = rbase + j;
      int s = srcs[er], d = dsts[er];
      float nrm = normf[er];
      if (d != dcur) {
#pragma unroll
        for (int t = 0; t < 4; ++t) {
          atomicAdd(&hacc[dcur * 64 + t * 16 + m], run[t]);
          run[t] = 0.f;
        }
        dcur = d;
      }
#pragma unroll
      for (int t = 0; t < 4; ++t) {
        int c = t * 16 + m;
        float gate = acc[t][j] + htS[s * 128 + 64 + c] + htB[d * 64 + c];
        float sig = 1.0f / (1.0f + __expf(-gate));
        run[t] = fmaf(nrm * htS[s * 128 + c], sig, run[t]);
      }
    }
#pragma unroll
    for (int t = 0; t < 4; ++t)
      atomicAdd(&hacc[dcur * 64 + t * 16 + m], run[t]);
  }
}

// ---------------- h = relu(in), column stats of result ----------------
__global__ void k_relu_stats(const float* __restrict__ in, float* __restrict__ h,
                             float* __restrict__ stats, int nrows) {
  int tid = threadIdx.x;
  float s = 0.f, s2 = 0.f;
  int total = nrows * 64;
  for (int i = blockIdx.x * 256 + tid; i < total; i += gridDim.x * 256) {
    float v = fmaxf(in[i], 0.f);
    h[i] = v;
    s += v; s2 += v * v;
  }
  __shared__ float ls[256], ls2[256];
  ls[tid] = s; ls2[tid] = s2;
  __syncthreads();
  for (int off = 128; off >= 64; off >>= 1) {
    if (tid < off) { ls[tid] += ls[tid + off]; ls2[tid] += ls2[tid + off]; }
    __syncthreads();
  }
  if (tid < 64) {
    atomicAdd(&stats[tid], ls[tid]);
    atomicAdd(&stats[64 + tid], ls2[tid]);
  }
}

// ---------------- global_add_pool (batch is sorted) ----------------
__global__ void k_pool(const float* __restrict__ h, const int* __restrict__ batch,
                       float* __restrict__ g) {
  int lane = threadIdx.x & 63;
  int wave = (blockIdx.x * blockDim.x + threadIdx.x) >> 6;
  int nwaves = (gridDim.x * blockDim.x) >> 6;
  int chunk = (N_NODESC + nwaves - 1) / nwaves;
  int r0 = wave * chunk;
  int r1 = min(r0 + chunk, N_NODESC);
  if (r0 >= r1) return;
  int cur = batch[r0];
  float acc = 0.f;
  for (int r = r0; r < r1; ++r) {
    int b = batch[r];
    if (b != cur) {
      atomicAdd(&g[cur * 64 + lane], acc);
      acc = 0.f;
      cur = b;
    }
    acc += h[r * 64 + lane];
  }
  atomicAdd(&g[cur * 64 + lane], acc);
}

// ---------------- classifier + log_softmax ----------------
__global__ void k_cls(const float* __restrict__ g2, const float* __restrict__ Wc,
                      const float* __restrict__ bc, float* __restrict__ out) {
  int r = blockIdx.x * blockDim.x + threadIdx.x;
  if (r >= N_GRAPHSC) return;
  float z[NCLS];
#pragma unroll
  for (int c = 0; c < NCLS; ++c) z[c] = bc[c];
  for (int k = 0; k < HDIM; ++k) {
    float v = g2[r * HDIM + k];
#pragma unroll
    for (int c = 0; c < NCLS; ++c) z[c] = fmaf(v, Wc[k * NCLS + c], z[c]);
  }
  float m = z[0];
#pragma unroll
  for (int c = 1; c < NCLS; ++c) m = fmaxf(m, z[c]);
  float ssum = 0.f;
#pragma unroll
  for (int c = 0; c < NCLS; ++c) ssum += __expf(z[c] - m);
  float l = __logf(ssum);
#pragma unroll
  for (int c = 0; c < NCLS; ++c) out[r * NCLS + c] = z[c] - m - l;
}

extern "C" void kernel_launch(void* const* d_in, const int* in_sizes, int n_in,
                              void* d_out, int out_size, void* d_ws, size_t ws_size,
                              hipStream_t stream) {
  const float* x         = (const float*)d_in[0];
  const float* edge_attr = (const float*)d_in[1];
  const int*   ei        = (const int*)d_in[2];
  const int*   batch     = (const int*)d_in[3];
  const float* bn_feat_w = (const float*)d_in[4];
  const float* bn_feat_b = (const float*)d_in[5];
  const float* Wn0       = (const float*)d_in[6];
  const float* bn0       = (const float*)d_in[7];
  const float* We0       = (const float*)d_in[8];
  const float* be0       = (const float*)d_in[9];
  const float* bns_w     = (const float*)d_in[10];
  const float* bns_b     = (const float*)d_in[11];
  const float* Wn        = (const float*)d_in[12];
  const float* Wnb       = (const float*)d_in[13];
  const float* We        = (const float*)d_in[14];
  const float* Web       = (const float*)d_in[15];
  const float* bn_fc_w   = (const float*)d_in[16];
  const float* bn_fc_b   = (const float*)d_in[17];
  const float* Wfc       = (const float*)d_in[18];
  const float* bfc       = (const float*)d_in[19];
  const float* bn_hid_w  = (const float*)d_in[20];
  const float* bn_hid_b  = (const float*)d_in[21];
  const float* Wcls      = (const float*)d_in[22];
  const float* bcls      = (const float*)d_in[23];
  float* out = (float*)d_out;
  const int* src = ei;
  const int* dst = ei + N_EDGESC;

  char* p = (char*)d_ws;
  auto carve = [&](size_t bytes) {
    char* q = p;
    p += (bytes + 255) & ~(size_t)255;
    return q;
  };
  __hip_bfloat16* ebf = (__hip_bfloat16*)carve((size_t)N_EDGESC * 64 * 2);
  float* h    = (float*)carve((size_t)N_NODESC * 64 * 4);
  float* hA   = (float*)carve((size_t)N_NODESC * 64 * 4);  // stage0; reused as htS[0:64]
  float* hB   = (float*)carve((size_t)N_NODESC * 64 * 4);  // stage0; reused as htS[64:128]
  float* htB  = (float*)carve((size_t)N_NODESC * 64 * 4);
  float* hacc = (float*)carve((size_t)N_NODESC * 64 * 4);
  float* dinv = (float*)carve((size_t)N_NODESC * 4);
  float* g    = (float*)carve((size_t)N_GRAPHSC * 64 * 4);
  float* g2   = (float*)carve((size_t)N_GRAPHSC * 64 * 4);
  float* stats= (float*)carve(2 * 64 * 4);
  float* Wf   = (float*)carve(64 * 64 * 4);
  float* bf   = (float*)carve(64 * 4);
  uint32* degi   = (uint32*)carve((size_t)50176 * 4);
  uint32* ptr    = (uint32*)carve((size_t)50176 * 4);
  uint32* cursor = (uint32*)carve((size_t)50176 * 4);
  uint32* bsum   = (uint32*)carve(256 * 4);
  int* srcs  = (int*)carve((size_t)N_EDGESC * 4);
  int* dsts  = (int*)carve((size_t)N_EDGESC * 4);
  int* eorig = (int*)carve((size_t)N_EDGESC * 4);
  float* normf = (float*)carve((size_t)N_EDGESC * 4);
  float* htS = hA;  // [N,128]: ht interleaved with htA (hA+hB are contiguous)

  // ---- degree, dinv, dst-sorted edge permutation ----
  hipMemsetAsync(degi, 0, 50176 * 4, stream);
  k_deg<<<(N_EDGESC + 255) / 256, 256, 0, stream>>>(dst, degi);
  k_dinv<<<(N_NODESC + 255) / 256, 256, 0, stream>>>(degi, dinv);
  k_scan1<<<SCAN_G, SCAN_B, 0, stream>>>(degi, ptr, bsum);
  k_scan2<<<1, 256, 0, stream>>>(bsum);
  k_scan3<<<SCAN_G, SCAN_B, 0, stream>>>(ptr, bsum);
  hipMemsetAsync(cursor, 0, 50176 * 4, stream);
  k_scatter<<<(N_EDGESC + 255) / 256, 256, 0, stream>>>(src, dst, ptr, cursor, srcs, dsts, eorig);

  // ---- h0 = BN(x)@Wn0 + bn0 (BN folded) ----
  hipMemsetAsync(stats, 0, 512, stream);
  k_colstats<FNODE><<<256, 256, 0, stream>>>(x, N_NODESC, stats);
  k_foldbn<FNODE, HDIM><<<1, 256, 0, stream>>>(stats, 1.f / N_NODESC, bn_feat_w, bn_feat_b, Wn0, bn0, Wf, bf);
  k_nodemm<FNODE, false, FNODE, 64><<<512, 256, 0, stream>>>(x, N_NODESC, Wf, bf, h);

  // ---- edge features (sorted order) + normf ----
  k_nodemm<HDIM, false, 64, 64><<<512, 256, 0, stream>>>(h, N_NODESC, We0, be0, hA);
  k_nodemm<HDIM, false, 64, 64><<<512, 256, 0, stream>>>(h, N_NODESC, We0 + 64 * 64, nullptr, hB);
  k_edgeinit<<<1024, 256, 0, stream>>>(hA, hB, edge_attr, We0 + 128 * 64, srcs, dsts, eorig, dinv, ebf, normf);

  // ---- h = relu(h0), stats(h) ----
  hipMemsetAsync(stats, 0, 512, stream);
  k_relu_stats<<<256, 256, 0, stream>>>(h, h, stats, N_NODESC);

  for (int i = 0; i < 3; ++i) {
    const float* WeI = We + (size_t)i * 192 * 64;
    k_foldbn<HDIM, HDIM><<<1, 256, 0, stream>>>(stats, 1.f / N_NODESC, bns_w + i * 64, bns_b + i * 64,
                                                Wn + (size_t)i * 64 * 64, Wnb + i * 64, Wf, bf);
    k_nodemm<HDIM, false, 64, 128><<<512, 256, 0, stream>>>(h, N_NODESC, Wf, bf, htS);            // ht
    k_nodemm<HDIM, false, 128, 128><<<512, 256, 0, stream>>>(htS, N_NODESC, WeI, Web + i * 64, htS + 64);  // htA (+Web)
    k_nodemm<HDIM, false, 128, 64><<<512, 256, 0, stream>>>(htS, N_NODESC, WeI + 64 * 64, nullptr, htB);   // htB
    hipMemsetAsync(hacc, 0, (size_t)N_NODESC * 64 * 4, stream);
    k_conv_mfma<<<2048, 256, 0, stream>>>(ebf, WeI + 128 * 64, htS, htB, normf, srcs, dsts, hacc);
    hipMemsetAsync(stats, 0, 512, stream);
    k_relu_stats<<<256, 256, 0, stream>>>(hacc, h, stats, N_NODESC);
  }

  // ---- pool + head ----
  hipMemsetAsync(g, 0, N_GRAPHSC * 64 * 4, stream);
  k_pool<<<64, 256, 0, stream>>>(h, batch, g);
  hipMemsetAsync(stats, 0, 512, stream);
  k_colstats<HDIM><<<32, 256, 0, stream>>>(g, N_GRAPHSC, stats);
  k_foldbn<HDIM, HDIM><<<1, 256, 0, stream>>>(stats, 1.f / N_GRAPHSC, bn_fc_w, bn_fc_b, Wfc, bfc, Wf, bf);
  k_nodemm<HDIM, true, 64, 64><<<128, 256, 0, stream>>>(g, N_GRAPHSC, Wf, bf, g2);
  hipMemsetAsync(stats, 0, 512, stream);
  k_colstats<HDIM><<<32, 256, 0, stream>>>(g2, N_GRAPHSC, stats);
  k_foldbn<HDIM, NCLS><<<1, 256, 0, stream>>>(stats, 1.f / N_GRAPHSC, bn_hid_w, bn_hid_b, Wcls, bcls, Wf, bf);
  k_cls<<<(N_GRAPHSC + 255) / 256, 256, 0, stream>>>(g2, Wf, bf, out);
}

// Round 4
// 1214.030 us; speedup vs baseline: 1.0640x; 1.0640x over previous
//
#include <hip/hip_runtime.h>
#include <hip/hip_bf16.h>

#define N_NODESC 50000
#define N_EDGESC 800000
#define N_GRAPHSC 512
#define HDIM 64
#define FNODE 32
#define FEDGE 8
#define NCLS 10
#define BN_EPS 1e-5f
#define SCAN_B 256
#define SCAN_G 196  // 196*256 = 50176 >= 50000

typedef __bf16 bf16x8 __attribute__((ext_vector_type(8)));
typedef float f32x4 __attribute__((ext_vector_type(4)));
typedef unsigned int uint32;

static __device__ __forceinline__ float bcast(float v, int k) {
  return __uint_as_float(__builtin_amdgcn_readlane(__float_as_uint(v), k));
}

// ---------------- degree ----------------
__global__ void k_deg(const int* __restrict__ dst, uint32* __restrict__ degi) {
  int e = blockIdx.x * blockDim.x + threadIdx.x;
  if (e < N_EDGESC) atomicAdd(&degi[dst[e]], 1u);
}

__global__ void k_dinv(const uint32* __restrict__ degi, float* __restrict__ dinv) {
  int n = blockIdx.x * blockDim.x + threadIdx.x;
  if (n < N_NODESC) dinv[n] = rsqrtf(fmaxf((float)degi[n], 1.0f));
}

// ---------------- exclusive prefix sum over degi -> ptr ----------------
__global__ void k_scan1(const uint32* __restrict__ degi, uint32* __restrict__ ptr,
                        uint32* __restrict__ bsum) {
  __shared__ uint32 s[SCAN_B];
  int t = threadIdx.x;
  int i = blockIdx.x * SCAN_B + t;
  uint32 v = (i < N_NODESC) ? degi[i] : 0u;
  s[t] = v; __syncthreads();
  for (int off = 1; off < SCAN_B; off <<= 1) {
    uint32 x = (t >= off) ? s[t - off] : 0u; __syncthreads();
    s[t] += x; __syncthreads();
  }
  if (i < N_NODESC) ptr[i] = s[t] - v;  // exclusive local scan
  if (t == SCAN_B - 1) bsum[blockIdx.x] = s[t];
}

__global__ void k_scan2(uint32* __restrict__ bsum) {
  __shared__ uint32 s[256];
  int t = threadIdx.x;
  uint32 v = (t < SCAN_G) ? bsum[t] : 0u;
  s[t] = v; __syncthreads();
  for (int off = 1; off < 256; off <<= 1) {
    uint32 x = (t >= off) ? s[t - off] : 0u; __syncthreads();
    s[t] += x; __syncthreads();
  }
  if (t < SCAN_G) bsum[t] = s[t] - v;  // exclusive
}

__global__ void k_scan3(uint32* __restrict__ ptr, const uint32* __restrict__ bsum) {
  int i = blockIdx.x * SCAN_B + threadIdx.x;
  if (i < N_NODESC) ptr[i] += bsum[blockIdx.x];
}

// ---------------- scatter edges into dst-sorted order (+ea permute, +normf) ----------------
__global__ void k_scatter(const int* __restrict__ src, const int* __restrict__ dst,
                          const float* __restrict__ ea, const float* __restrict__ dinv,
                          const uint32* __restrict__ ptr, uint32* __restrict__ cursor,
                          int* __restrict__ srcs, int* __restrict__ dsts,
                          float* __restrict__ ea_s, float* __restrict__ normf) {
  int e = blockIdx.x * blockDim.x + threadIdx.x;
  if (e < N_EDGESC) {
    int d = dst[e];
    int s = src[e];
    float4 a0 = *reinterpret_cast<const float4*>(ea + (size_t)e * FEDGE);
    float4 a1 = *reinterpret_cast<const float4*>(ea + (size_t)e * FEDGE + 4);
    uint32 r = atomicAdd(&cursor[d], 1u);
    uint32 i = ptr[d] + r;
    srcs[i] = s;
    dsts[i] = d;
    normf[i] = dinv[s] * dinv[d];
    *reinterpret_cast<float4*>(ea_s + (size_t)i * FEDGE) = a0;
    *reinterpret_cast<float4*>(ea_s + (size_t)i * FEDGE + 4) = a1;
  }
}

// ---------------- column stats (sum, sumsq) ----------------
template <int C>
__global__ void k_colstats(const float* __restrict__ in, int nrows, float* __restrict__ stats) {
  const int RPB = 256 / C;
  int tid = threadIdx.x;
  int col = tid % C;
  int rowOff = tid / C;
  float s = 0.f, s2 = 0.f;
  for (int r = blockIdx.x * RPB + rowOff; r < nrows; r += gridDim.x * RPB) {
    float v = in[r * C + col];
    s += v; s2 += v * v;
  }
  __shared__ float ls[256], ls2[256];
  ls[tid] = s; ls2[tid] = s2;
  __syncthreads();
  for (int off = 128; off >= C; off >>= 1) {
    if (tid < off) { ls[tid] += ls[tid + off]; ls2[tid] += ls2[tid + off]; }
    __syncthreads();
  }
  if (tid < C) {
    atomicAdd(&stats[tid], ls[tid]);
    atomicAdd(&stats[C + tid], ls2[tid]);
  }
}

// ---------------- fold BN into weights ----------------
template <int CIN, int COUT>
__global__ void k_foldbn(const float* __restrict__ stats, float invN,
                         const float* __restrict__ bnw, const float* __restrict__ bnb,
                         const float* __restrict__ W, const float* __restrict__ bias,
                         float* __restrict__ Wf, float* __restrict__ bf) {
  __shared__ float a[CIN], sh[CIN];
  int tid = threadIdx.x;
  if (tid < CIN) {
    float m = stats[tid] * invN;
    float v = stats[CIN + tid] * invN - m * m;
    float inv = rsqrtf(v + BN_EPS);
    float aa = bnw[tid] * inv;
    a[tid] = aa;
    sh[tid] = bnb[tid] - m * aa;
  }
  __syncthreads();
  for (int i = tid; i < CIN * COUT; i += 256) {
    int r = i / COUT;
    Wf[i] = a[r] * W[i];
  }
  if (tid < COUT) {
    float acc = bias ? bias[tid] : 0.f;
    for (int r = 0; r < CIN; ++r) acc += sh[r] * W[r * COUT + tid];
    bf[tid] = acc;
  }
}

// ---------------- out[N,64] = in[N,K](ld LDIN) @ W[K,64] + bias ----------------
template <int K, bool RELU, int LDIN, int LDOUT>
__global__ void k_nodemm(const float* __restrict__ in, int nrows,
                         const float* __restrict__ W, const float* __restrict__ bias,
                         float* __restrict__ out) {
  int tid = threadIdx.x;
  int lane = tid & 63;
  float w[K];
#pragma unroll
  for (int k = 0; k < K; ++k) w[k] = W[k * 64 + lane];
  float bv = bias ? bias[lane] : 0.f;
  int wave = (blockIdx.x * blockDim.x + tid) >> 6;
  int nwaves = (gridDim.x * blockDim.x) >> 6;
  for (int r = wave; r < nrows; r += nwaves) {
    float rv = (lane < K) ? in[(size_t)r * LDIN + lane] : 0.f;
    float acc = bv;
#pragma unroll
    for (int k = 0; k < K; ++k) acc = fmaf(bcast(rv, k), w[k], acc);
    if (RELU) acc = fmaxf(acc, 0.f);
    out[(size_t)r * LDOUT + lane] = acc;
  }
}

// ---------------- e = relu(hA[src]+hB[dst]+ea_s@We0c) -> bf16 (sorted order) ----------------
__global__ void k_edgeinit(const float* __restrict__ hA, const float* __restrict__ hB,
                           const float* __restrict__ ea_s, const float* __restrict__ Wc,
                           const int* __restrict__ srcs, const int* __restrict__ dsts,
                           __hip_bfloat16* __restrict__ ebf) {
  int tid = threadIdx.x;
  int lane = tid & 63;
  float w[FEDGE];
#pragma unroll
  for (int k = 0; k < FEDGE; ++k) w[k] = Wc[k * 64 + lane];
  int wave = (blockIdx.x * blockDim.x + tid) >> 6;
  int nwaves = (gridDim.x * blockDim.x) >> 6;
  for (int e = wave; e < N_EDGESC; e += nwaves) {
    int s = srcs[e], d = dsts[e];
    float av = (lane < FEDGE) ? ea_s[(size_t)e * FEDGE + lane] : 0.f;
    float acc = hA[s * 64 + lane] + hB[d * 64 + lane];
#pragma unroll
    for (int k = 0; k < FEDGE; ++k) acc = fmaf(bcast(av, k), w[k], acc);
    acc = fmaxf(acc, 0.f);
    ebf[(size_t)e * 64 + lane] = __float2bfloat16(acc);
  }
}

// ---------------- edge-gated conv, MFMA gate GEMM, dst-sorted run-accumulate ----------------
// htS: [N,128] interleaved -> htS[s*128+c] = ht (message source), htS[s*128+64+c] = htA
__global__ void __launch_bounds__(256) k_conv_mfma(
    const __hip_bfloat16* __restrict__ ebf,
    const float* __restrict__ We2,
    const float* __restrict__ htS, const float* __restrict__ htB,
    const float* __restrict__ normf,
    const int* __restrict__ srcs, const int* __restrict__ dsts,
    float* __restrict__ hacc) {
  const int lane = threadIdx.x & 63;
  const int m  = lane & 15;   // A-row / B-col within 16-tile
  const int kg = lane >> 4;   // k-group

  // B fragments: b[t][s] -> B[k = s*32 + kg*8 + j][c = t*16 + m]
  bf16x8 b[4][2];
#pragma unroll
  for (int t = 0; t < 4; ++t)
#pragma unroll
    for (int s = 0; s < 2; ++s)
#pragma unroll
      for (int j = 0; j < 8; ++j) {
        int k = s * 32 + kg * 8 + j;
        int c = t * 16 + m;
        b[t][s][j] = (__bf16)We2[k * 64 + c];
      }

  int wave = (blockIdx.x * blockDim.x + threadIdx.x) >> 6;
  int nwaves = (gridDim.x * blockDim.x) >> 6;
  const int ntiles = N_EDGESC / 16;
  for (int tile = wave; tile < ntiles; tile += nwaves) {
    int base = tile * 16;
    const __hip_bfloat16* arow = ebf + (size_t)(base + m) * 64 + kg * 8;
    bf16x8 a0 = *reinterpret_cast<const bf16x8*>(arow);
    bf16x8 a1 = *reinterpret_cast<const bf16x8*>(arow + 32);
    f32x4 acc[4];
#pragma unroll
    for (int t = 0; t < 4; ++t) {
      f32x4 z = {0.f, 0.f, 0.f, 0.f};
      acc[t] = __builtin_amdgcn_mfma_f32_16x16x32_bf16(a0, b[t][0], z, 0, 0, 0);
      acc[t] = __builtin_amdgcn_mfma_f32_16x16x32_bf16(a1, b[t][1], acc[t], 0, 0, 0);
    }
    // D mapping: lane holds col c=t*16+m, rows r = kg*4+j (consecutive sorted edges)
    int rbase = base + kg * 4;
    float run[4] = {0.f, 0.f, 0.f, 0.f};
    int dcur = dsts[rbase];
#pragma unroll
    for (int j = 0; j < 4; ++j) {
      int er = rbase + j;
      int s = srcs[er], d = dsts[er];
      float nrm = normf[er];
      if (d != dcur) {
#pragma unroll
        for (int t = 0; t < 4; ++t) {
          atomicAdd(&hacc[dcur * 64 + t * 16 + m], run[t]);
          run[t] = 0.f;
        }
        dcur = d;
      }
#pragma unroll
      for (int t = 0; t < 4; ++t) {
        int c = t * 16 + m;
        float gate = acc[t][j] + htS[s * 128 + 64 + c] + htB[d * 64 + c];
        float sig = 1.0f / (1.0f + __expf(-gate));
        run[t] = fmaf(nrm * htS[s * 128 + c], sig, run[t]);
      }
    }
#pragma unroll
    for (int t = 0; t < 4; ++t)
      atomicAdd(&hacc[dcur * 64 + t * 16 + m], run[t]);
  }
}

// ---------------- h = relu(in), column stats of result ----------------
__global__ void k_relu_stats(const float* __restrict__ in, float* __restrict__ h,
                             float* __restrict__ stats, int nrows) {
  int tid = threadIdx.x;
  float s = 0.f, s2 = 0.f;
  int total = nrows * 64;
  for (int i = blockIdx.x * 256 + tid; i < total; i += gridDim.x * 256) {
    float v = fmaxf(in[i], 0.f);
    h[i] = v;
    s += v; s2 += v * v;
  }
  __shared__ float ls[256], ls2[256];
  ls[tid] = s; ls2[tid] = s2;
  __syncthreads();
  for (int off = 128; off >= 64; off >>= 1) {
    if (tid < off) { ls[tid] += ls[tid + off]; ls2[tid] += ls2[tid + off]; }
    __syncthreads();
  }
  if (tid < 64) {
    atomicAdd(&stats[tid], ls[tid]);
    atomicAdd(&stats[64 + tid], ls2[tid]);
  }
}

// ---------------- global_add_pool (batch is sorted) ----------------
__global__ void k_pool(const float* __restrict__ h, const int* __restrict__ batch,
                       float* __restrict__ g) {
  int lane = threadIdx.x & 63;
  int wave = (blockIdx.x * blockDim.x + threadIdx.x) >> 6;
  int nwaves = (gridDim.x * blockDim.x) >> 6;
  int chunk = (N_NODESC + nwaves - 1) / nwaves;
  int r0 = wave * chunk;
  int r1 = min(r0 + chunk, N_NODESC);
  if (r0 >= r1) return;
  int cur = batch[r0];
  float acc = 0.f;
  for (int r = r0; r < r1; ++r) {
    int b = batch[r];
    if (b != cur) {
      atomicAdd(&g[cur * 64 + lane], acc);
      acc = 0.f;
      cur = b;
    }
    acc += h[r * 64 + lane];
  }
  atomicAdd(&g[cur * 64 + lane], acc);
}

// ---------------- classifier + log_softmax ----------------
__global__ void k_cls(const float* __restrict__ g2, const float* __restrict__ Wc,
                      const float* __restrict__ bc, float* __restrict__ out) {
  int r = blockIdx.x * blockDim.x + threadIdx.x;
  if (r >= N_GRAPHSC) return;
  float z[NCLS];
#pragma unroll
  for (int c = 0; c < NCLS; ++c) z[c] = bc[c];
  for (int k = 0; k < HDIM; ++k) {
    float v = g2[r * HDIM + k];
#pragma unroll
    for (int c = 0; c < NCLS; ++c) z[c] = fmaf(v, Wc[k * NCLS + c], z[c]);
  }
  float m = z[0];
#pragma unroll
  for (int c = 1; c < NCLS; ++c) m = fmaxf(m, z[c]);
  float ssum = 0.f;
#pragma unroll
  for (int c = 0; c < NCLS; ++c) ssum += __expf(z[c] - m);
  float l = __logf(ssum);
#pragma unroll
  for (int c = 0; c < NCLS; ++c) out[r * NCLS + c] = z[c] - m - l;
}

extern "C" void kernel_launch(void* const* d_in, const int* in_sizes, int n_in,
                              void* d_out, int out_size, void* d_ws, size_t ws_size,
                              hipStream_t stream) {
  const float* x         = (const float*)d_in[0];
  const float* edge_attr = (const float*)d_in[1];
  const int*   ei        = (const int*)d_in[2];
  const int*   batch     = (const int*)d_in[3];
  const float* bn_feat_w = (const float*)d_in[4];
  const float* bn_feat_b = (const float*)d_in[5];
  const float* Wn0       = (const float*)d_in[6];
  const float* bn0       = (const float*)d_in[7];
  const float* We0       = (const float*)d_in[8];
  const float* be0       = (const float*)d_in[9];
  const float* bns_w     = (const float*)d_in[10];
  const float* bns_b     = (const float*)d_in[11];
  const float* Wn        = (const float*)d_in[12];
  const float* Wnb       = (const float*)d_in[13];
  const float* We        = (const float*)d_in[14];
  const float* Web       = (const float*)d_in[15];
  const float* bn_fc_w   = (const float*)d_in[16];
  const float* bn_fc_b   = (const float*)d_in[17];
  const float* Wfc       = (const float*)d_in[18];
  const float* bfc       = (const float*)d_in[19];
  const float* bn_hid_w  = (const float*)d_in[20];
  const float* bn_hid_b  = (const float*)d_in[21];
  const float* Wcls      = (const float*)d_in[22];
  const float* bcls      = (const float*)d_in[23];
  float* out = (float*)d_out;
  const int* src = ei;
  const int* dst = ei + N_EDGESC;

  char* p = (char*)d_ws;
  auto carve = [&](size_t bytes) {
    char* q = p;
    p += (bytes + 255) & ~(size_t)255;
    return q;
  };
  __hip_bfloat16* ebf = (__hip_bfloat16*)carve((size_t)N_EDGESC * 64 * 2);
  float* h    = (float*)carve((size_t)N_NODESC * 64 * 4);
  float* hA   = (float*)carve((size_t)N_NODESC * 64 * 4);  // stage0; reused as htS[0:64]
  float* hB   = (float*)carve((size_t)N_NODESC * 64 * 4);  // stage0; reused as htS[64:128]
  float* htB  = (float*)carve((size_t)N_NODESC * 64 * 4);
  float* hacc = (float*)carve((size_t)N_NODESC * 64 * 4);
  float* dinv = (float*)carve((size_t)N_NODESC * 4);
  float* g    = (float*)carve((size_t)N_GRAPHSC * 64 * 4);
  float* g2   = (float*)carve((size_t)N_GRAPHSC * 64 * 4);
  float* stats= (float*)carve(2 * 64 * 4);
  float* Wf   = (float*)carve(64 * 64 * 4);
  float* bf   = (float*)carve(64 * 4);
  uint32* degi   = (uint32*)carve((size_t)50176 * 4);
  uint32* ptr    = (uint32*)carve((size_t)50176 * 4);
  uint32* cursor = (uint32*)carve((size_t)50176 * 4);
  uint32* bsum   = (uint32*)carve(256 * 4);
  int* srcs  = (int*)carve((size_t)N_EDGESC * 4);
  int* dsts  = (int*)carve((size_t)N_EDGESC * 4);
  float* ea_s  = (float*)carve((size_t)N_EDGESC * FEDGE * 4);
  float* normf = (float*)carve((size_t)N_EDGESC * 4);
  float* htS = hA;  // [N,128]: ht interleaved with htA (hA+hB are contiguous)

  // ---- degree, dinv, dst-sorted edge permutation ----
  hipMemsetAsync(degi, 0, 50176 * 4, stream);
  k_deg<<<(N_EDGESC + 255) / 256, 256, 0, stream>>>(dst, degi);
  k_dinv<<<(N_NODESC + 255) / 256, 256, 0, stream>>>(degi, dinv);
  k_scan1<<<SCAN_G, SCAN_B, 0, stream>>>(degi, ptr, bsum);
  k_scan2<<<1, 256, 0, stream>>>(bsum);
  k_scan3<<<SCAN_G, SCAN_B, 0, stream>>>(ptr, bsum);
  hipMemsetAsync(cursor, 0, 50176 * 4, stream);
  k_scatter<<<(N_EDGESC + 255) / 256, 256, 0, stream>>>(src, dst, edge_attr, dinv, ptr, cursor,
                                                        srcs, dsts, ea_s, normf);

  // ---- h0 = BN(x)@Wn0 + bn0 (BN folded) ----
  hipMemsetAsync(stats, 0, 512, stream);
  k_colstats<FNODE><<<256, 256, 0, stream>>>(x, N_NODESC, stats);
  k_foldbn<FNODE, HDIM><<<1, 256, 0, stream>>>(stats, 1.f / N_NODESC, bn_feat_w, bn_feat_b, Wn0, bn0, Wf, bf);
  k_nodemm<FNODE, false, FNODE, 64><<<512, 256, 0, stream>>>(x, N_NODESC, Wf, bf, h);

  // ---- edge features (sorted order) ----
  k_nodemm<HDIM, false, 64, 64><<<512, 256, 0, stream>>>(h, N_NODESC, We0, be0, hA);
  k_nodemm<HDIM, false, 64, 64><<<512, 256, 0, stream>>>(h, N_NODESC, We0 + 64 * 64, nullptr, hB);
  k_edgeinit<<<1024, 256, 0, stream>>>(hA, hB, ea_s, We0 + 128 * 64, srcs, dsts, ebf);

  // ---- h = relu(h0), stats(h) ----
  hipMemsetAsync(stats, 0, 512, stream);
  k_relu_stats<<<256, 256, 0, stream>>>(h, h, stats, N_NODESC);

  for (int i = 0; i < 3; ++i) {
    const float* WeI = We + (size_t)i * 192 * 64;
    k_foldbn<HDIM, HDIM><<<1, 256, 0, stream>>>(stats, 1.f / N_NODESC, bns_w + i * 64, bns_b + i * 64,
                                                Wn + (size_t)i * 64 * 64, Wnb + i * 64, Wf, bf);
    k_nodemm<HDIM, false, 64, 128><<<512, 256, 0, stream>>>(h, N_NODESC, Wf, bf, htS);            // ht
    k_nodemm<HDIM, false, 128, 128><<<512, 256, 0, stream>>>(htS, N_NODESC, WeI, Web + i * 64, htS + 64);  // htA (+Web)
    k_nodemm<HDIM, false, 128, 64><<<512, 256, 0, stream>>>(htS, N_NODESC, WeI + 64 * 64, nullptr, htB);   // htB
    hipMemsetAsync(hacc, 0, (size_t)N_NODESC * 64 * 4, stream);
    k_conv_mfma<<<2048, 256, 0, stream>>>(ebf, WeI + 128 * 64, htS, htB, normf, srcs, dsts, hacc);
    hipMemsetAsync(stats, 0, 512, stream);
    k_relu_stats<<<256, 256, 0, stream>>>(hacc, h, stats, N_NODESC);
  }

  // ---- pool + head ----
  hipMemsetAsync(g, 0, N_GRAPHSC * 64 * 4, stream);
  k_pool<<<64, 256, 0, stream>>>(h, batch, g);
  hipMemsetAsync(stats, 0, 512, stream);
  k_colstats<HDIM><<<32, 256, 0, stream>>>(g, N_GRAPHSC, stats);
  k_foldbn<HDIM, HDIM><<<1, 256, 0, stream>>>(stats, 1.f / N_GRAPHSC, bn_fc_w, bn_fc_b, Wfc, bfc, Wf, bf);
  k_nodemm<HDIM, true, 64, 64><<<128, 256, 0, stream>>>(g, N_GRAPHSC, Wf, bf, g2);
  hipMemsetAsync(stats, 0, 512, stream);
  k_colstats<HDIM><<<32, 256, 0, stream>>>(g2, N_GRAPHSC, stats);
  k_foldbn<HDIM, NCLS><<<1, 256, 0, stream>>>(stats, 1.f / N_GRAPHSC, bn_hid_w, bn_hid_b, Wcls, bcls, Wf, bf);
  k_cls<<<(N_GRAPHSC + 255) / 256, 256, 0, stream>>>(g2, Wf, bf, out);
}

// Round 5
// 1159.123 us; speedup vs baseline: 1.1144x; 1.0474x over previous
//
#include <hip/hip_runtime.h>
#include <hip/hip_bf16.h>

#define N_NODESC 50000
#define N_EDGESC 800000
#define N_GRAPHSC 512
#define HDIM 64
#define FNODE 32
#define FEDGE 8
#define NCLS 10
#define BN_EPS 1e-5f
#define SCAN_B 256
#define SCAN_G 196  // 196*256 = 50176 >= 50000

typedef __bf16 bf16x8 __attribute__((ext_vector_type(8)));
typedef float f32x4 __attribute__((ext_vector_type(4)));
typedef unsigned int uint32;

static __device__ __forceinline__ float bcast(float v, int k) {
  return __uint_as_float(__builtin_amdgcn_readlane(__float_as_uint(v), k));
}
static __device__ __forceinline__ unsigned short f2bu(float f) {
  __hip_bfloat16 b = __float2bfloat16(f);
  return *reinterpret_cast<unsigned short*>(&b);
}
static __device__ __forceinline__ float bu2f(unsigned short u) {
  __hip_bfloat16 b;
  *reinterpret_cast<unsigned short*>(&b) = u;
  return __bfloat162float(b);
}

// ---------------- degree ----------------
__global__ void k_deg(const int* __restrict__ dst, uint32* __restrict__ degi) {
  int e = blockIdx.x * blockDim.x + threadIdx.x;
  if (e < N_EDGESC) atomicAdd(&degi[dst[e]], 1u);
}

__global__ void k_dinv(const uint32* __restrict__ degi, float* __restrict__ dinv) {
  int n = blockIdx.x * blockDim.x + threadIdx.x;
  if (n < N_NODESC) dinv[n] = rsqrtf(fmaxf((float)degi[n], 1.0f));
}

// ---------------- exclusive prefix sum over degi -> ptr ----------------
__global__ void k_scan1(const uint32* __restrict__ degi, uint32* __restrict__ ptr,
                        uint32* __restrict__ bsum) {
  __shared__ uint32 s[SCAN_B];
  int t = threadIdx.x;
  int i = blockIdx.x * SCAN_B + t;
  uint32 v = (i < N_NODESC) ? degi[i] : 0u;
  s[t] = v; __syncthreads();
  for (int off = 1; off < SCAN_B; off <<= 1) {
    uint32 x = (t >= off) ? s[t - off] : 0u; __syncthreads();
    s[t] += x; __syncthreads();
  }
  if (i < N_NODESC) ptr[i] = s[t] - v;  // exclusive local scan
  if (t == SCAN_B - 1) bsum[blockIdx.x] = s[t];
}

__global__ void k_scan2(uint32* __restrict__ bsum) {
  __shared__ uint32 s[256];
  int t = threadIdx.x;
  uint32 v = (t < SCAN_G) ? bsum[t] : 0u;
  s[t] = v; __syncthreads();
  for (int off = 1; off < 256; off <<= 1) {
    uint32 x = (t >= off) ? s[t - off] : 0u; __syncthreads();
    s[t] += x; __syncthreads();
  }
  if (t < SCAN_G) bsum[t] = s[t] - v;  // exclusive
}

__global__ void k_scan3(uint32* __restrict__ ptr, const uint32* __restrict__ bsum) {
  int i = blockIdx.x * SCAN_B + threadIdx.x;
  if (i < N_NODESC) ptr[i] += bsum[blockIdx.x];
}

// ---------------- scatter edges into dst-sorted order (+ea permute, +normf) ----------------
__global__ void k_scatter(const int* __restrict__ src, const int* __restrict__ dst,
                          const float* __restrict__ ea, const float* __restrict__ dinv,
                          const uint32* __restrict__ ptr, uint32* __restrict__ cursor,
                          int* __restrict__ srcs, int* __restrict__ dsts,
                          float* __restrict__ ea_s, float* __restrict__ normf) {
  int e = blockIdx.x * blockDim.x + threadIdx.x;
  if (e < N_EDGESC) {
    int d = dst[e];
    int s = src[e];
    float4 a0 = *reinterpret_cast<const float4*>(ea + (size_t)e * FEDGE);
    float4 a1 = *reinterpret_cast<const float4*>(ea + (size_t)e * FEDGE + 4);
    uint32 r = atomicAdd(&cursor[d], 1u);
    uint32 i = ptr[d] + r;
    srcs[i] = s;
    dsts[i] = d;
    normf[i] = dinv[s] * dinv[d];
    *reinterpret_cast<float4*>(ea_s + (size_t)i * FEDGE) = a0;
    *reinterpret_cast<float4*>(ea_s + (size_t)i * FEDGE + 4) = a1;
  }
}

// ---------------- column stats (sum, sumsq) ----------------
template <int C>
__global__ void k_colstats(const float* __restrict__ in, int nrows, float* __restrict__ stats) {
  const int RPB = 256 / C;
  int tid = threadIdx.x;
  int col = tid % C;
  int rowOff = tid / C;
  float s = 0.f, s2 = 0.f;
  for (int r = blockIdx.x * RPB + rowOff; r < nrows; r += gridDim.x * RPB) {
    float v = in[r * C + col];
    s += v; s2 += v * v;
  }
  __shared__ float ls[256], ls2[256];
  ls[tid] = s; ls2[tid] = s2;
  __syncthreads();
  for (int off = 128; off >= C; off >>= 1) {
    if (tid < off) { ls[tid] += ls[tid + off]; ls2[tid] += ls2[tid + off]; }
    __syncthreads();
  }
  if (tid < C) {
    atomicAdd(&stats[tid], ls[tid]);
    atomicAdd(&stats[C + tid], ls2[tid]);
  }
}

// ---------------- fold BN into weights ----------------
template <int CIN, int COUT>
__global__ void k_foldbn(const float* __restrict__ stats, float invN,
                         const float* __restrict__ bnw, const float* __restrict__ bnb,
                         const float* __restrict__ W, const float* __restrict__ bias,
                         float* __restrict__ Wf, float* __restrict__ bf) {
  __shared__ float a[CIN], sh[CIN];
  int tid = threadIdx.x;
  if (tid < CIN) {
    float m = stats[tid] * invN;
    float v = stats[CIN + tid] * invN - m * m;
    float inv = rsqrtf(v + BN_EPS);
    float aa = bnw[tid] * inv;
    a[tid] = aa;
    sh[tid] = bnb[tid] - m * aa;
  }
  __syncthreads();
  for (int i = tid; i < CIN * COUT; i += 256) {
    int r = i / COUT;
    Wf[i] = a[r] * W[i];
  }
  if (tid < COUT) {
    float acc = bias ? bias[tid] : 0.f;
    for (int r = 0; r < CIN; ++r) acc += sh[r] * W[r * COUT + tid];
    bf[tid] = acc;
  }
}

// ---------------- out[N,64] = in[N,K](ld LDIN) @ W[K,64] + bias (fp32 out) ----------------
template <int K, bool RELU, int LDIN, int LDOUT>
__global__ void k_nodemm(const float* __restrict__ in, int nrows,
                         const float* __restrict__ W, const float* __restrict__ bias,
                         float* __restrict__ out) {
  int tid = threadIdx.x;
  int lane = tid & 63;
  float w[K];
#pragma unroll
  for (int k = 0; k < K; ++k) w[k] = W[k * 64 + lane];
  float bv = bias ? bias[lane] : 0.f;
  int wave = (blockIdx.x * blockDim.x + tid) >> 6;
  int nwaves = (gridDim.x * blockDim.x) >> 6;
  for (int r = wave; r < nrows; r += nwaves) {
    float rv = (lane < K) ? in[(size_t)r * LDIN + lane] : 0.f;
    float acc = bv;
#pragma unroll
    for (int k = 0; k < K; ++k) acc = fmaf(bcast(rv, k), w[k], acc);
    if (RELU) acc = fmaxf(acc, 0.f);
    out[(size_t)r * LDOUT + lane] = acc;
  }
}

// ---------------- bf16-out nodemm: out[N,64] bf16 ----------------
template <int K, int LDIN>
__global__ void k_nodemm_b(const float* __restrict__ in, int nrows,
                           const float* __restrict__ W, const float* __restrict__ bias,
                           unsigned short* __restrict__ out) {
  int tid = threadIdx.x;
  int lane = tid & 63;
  float w[K];
#pragma unroll
  for (int k = 0; k < K; ++k) w[k] = W[k * 64 + lane];
  float bv = bias ? bias[lane] : 0.f;
  int wave = (blockIdx.x * blockDim.x + tid) >> 6;
  int nwaves = (gridDim.x * blockDim.x) >> 6;
  for (int r = wave; r < nrows; r += nwaves) {
    float rv = (lane < K) ? in[(size_t)r * LDIN + lane] : 0.f;
    float acc = bv;
#pragma unroll
    for (int k = 0; k < K; ++k) acc = fmaf(bcast(rv, k), w[k], acc);
    out[(size_t)r * 64 + lane] = f2bu(acc);
  }
}

// ---------------- pack nodemm: computes htA = ht@W + bias, writes {bf16 ht, bf16 htA} ----------------
__global__ void k_nodemm_pack(const float* __restrict__ ht, int nrows,
                              const float* __restrict__ W, const float* __restrict__ bias,
                              uint32* __restrict__ htP) {
  int tid = threadIdx.x;
  int lane = tid & 63;
  float w[64];
#pragma unroll
  for (int k = 0; k < 64; ++k) w[k] = W[k * 64 + lane];
  float bv = bias[lane];
  int wave = (blockIdx.x * blockDim.x + tid) >> 6;
  int nwaves = (gridDim.x * blockDim.x) >> 6;
  for (int r = wave; r < nrows; r += nwaves) {
    float rv = ht[(size_t)r * 64 + lane];  // ht[r][lane]
    float acc = bv;
#pragma unroll
    for (int k = 0; k < 64; ++k) acc = fmaf(bcast(rv, k), w[k], acc);
    htP[(size_t)r * 64 + lane] = ((uint32)f2bu(acc) << 16) | (uint32)f2bu(rv);
  }
}

// ---------------- e = relu(hA[src]+hB[dst]+ea_s@We0c) -> bf16 (sorted order) ----------------
__global__ void k_edgeinit(const unsigned short* __restrict__ hAb,
                           const unsigned short* __restrict__ hBb,
                           const float* __restrict__ ea_s, const float* __restrict__ Wc,
                           const int* __restrict__ srcs, const int* __restrict__ dsts,
                           __hip_bfloat16* __restrict__ ebf) {
  int tid = threadIdx.x;
  int lane = tid & 63;
  float w[FEDGE];
#pragma unroll
  for (int k = 0; k < FEDGE; ++k) w[k] = Wc[k * 64 + lane];
  int wave = (blockIdx.x * blockDim.x + tid) >> 6;
  int nwaves = (gridDim.x * blockDim.x) >> 6;
  for (int e = wave; e < N_EDGESC; e += nwaves) {
    int s = srcs[e], d = dsts[e];
    float av = (lane < FEDGE) ? ea_s[(size_t)e * FEDGE + lane] : 0.f;
    float acc = bu2f(hAb[s * 64 + lane]) + bu2f(hBb[d * 64 + lane]);
#pragma unroll
    for (int k = 0; k < FEDGE; ++k) acc = fmaf(bcast(av, k), w[k], acc);
    acc = fmaxf(acc, 0.f);
    __hip_bfloat16 ob = __float2bfloat16(acc);
    __builtin_nontemporal_store(*reinterpret_cast<unsigned short*>(&ob),
                                reinterpret_cast<unsigned short*>(ebf) + (size_t)e * 64 + lane);
  }
}

// ---------------- edge-gated conv, MFMA gate GEMM, dst-sorted run-accumulate ----------------
// htP[n][c] = {lo: bf16 ht, hi: bf16 htA}; htBb[n][c] = bf16 htB
__global__ void __launch_bounds__(256) k_conv_mfma(
    const __hip_bfloat16* __restrict__ ebf,
    const float* __restrict__ We2,
    const uint32* __restrict__ htP, const unsigned short* __restrict__ htBb,
    const float* __restrict__ normf,
    const int* __restrict__ srcs, const int* __restrict__ dsts,
    float* __restrict__ hacc) {
  const int lane = threadIdx.x & 63;
  const int m  = lane & 15;   // A-row / B-col within 16-tile
  const int kg = lane >> 4;   // k-group

  // B fragments: b[t][s] -> B[k = s*32 + kg*8 + j][c = t*16 + m]
  bf16x8 b[4][2];
#pragma unroll
  for (int t = 0; t < 4; ++t)
#pragma unroll
    for (int s = 0; s < 2; ++s)
#pragma unroll
      for (int j = 0; j < 8; ++j) {
        int k = s * 32 + kg * 8 + j;
        int c = t * 16 + m;
        b[t][s][j] = (__bf16)We2[k * 64 + c];
      }

  int wave = (blockIdx.x * blockDim.x + threadIdx.x) >> 6;
  int nwaves = (gridDim.x * blockDim.x) >> 6;
  const int ntiles = N_EDGESC / 16;
  for (int tile = wave; tile < ntiles; tile += nwaves) {
    int base = tile * 16;
    const bf16x8* arow = reinterpret_cast<const bf16x8*>(ebf + (size_t)(base + m) * 64 + kg * 8);
    bf16x8 a0 = __builtin_nontemporal_load(arow);
    bf16x8 a1 = __builtin_nontemporal_load(arow + 4);
    f32x4 acc[4];
#pragma unroll
    for (int t = 0; t < 4; ++t) {
      f32x4 z = {0.f, 0.f, 0.f, 0.f};
      acc[t] = __builtin_amdgcn_mfma_f32_16x16x32_bf16(a0, b[t][0], z, 0, 0, 0);
      acc[t] = __builtin_amdgcn_mfma_f32_16x16x32_bf16(a1, b[t][1], acc[t], 0, 0, 0);
    }
    // D mapping: lane holds col c=t*16+m, rows r = kg*4+j (consecutive sorted edges)
    int rbase = base + kg * 4;
    float run[4] = {0.f, 0.f, 0.f, 0.f};
    int dcur = dsts[rbase];
#pragma unroll
    for (int j = 0; j < 4; ++j) {
      int er = rbase + j;
      int s = srcs[er], d = dsts[er];
      float nrm = normf[er];
      if (d != dcur) {
#pragma unroll
        for (int t = 0; t < 4; ++t) {
          atomicAdd(&hacc[dcur * 64 + t * 16 + m], run[t]);
          run[t] = 0.f;
        }
        dcur = d;
      }
#pragma unroll
      for (int t = 0; t < 4; ++t) {
        int c = t * 16 + m;
        uint32 pv = htP[(size_t)s * 64 + c];
        float htv  = bu2f((unsigned short)(pv & 0xffffu));
        float htav = bu2f((unsigned short)(pv >> 16));
        float htbv = bu2f(htBb[(size_t)d * 64 + c]);
        float gate = acc[t][j] + htav + htbv;
        float sig = 1.0f / (1.0f + __expf(-gate));
        run[t] = fmaf(nrm * htv, sig, run[t]);
      }
    }
#pragma unroll
    for (int t = 0; t < 4; ++t)
      atomicAdd(&hacc[dcur * 64 + t * 16 + m], run[t]);
  }
}

// ---------------- h = relu(in), column stats of result ----------------
__global__ void k_relu_stats(const float* __restrict__ in, float* __restrict__ h,
                             float* __restrict__ stats, int nrows) {
  int tid = threadIdx.x;
  float s = 0.f, s2 = 0.f;
  int total = nrows * 64;
  for (int i = blockIdx.x * 256 + tid; i < total; i += gridDim.x * 256) {
    float v = fmaxf(in[i], 0.f);
    h[i] = v;
    s += v; s2 += v * v;
  }
  __shared__ float ls[256], ls2[256];
  ls[tid] = s; ls2[tid] = s2;
  __syncthreads();
  for (int off = 128; off >= 64; off >>= 1) {
    if (tid < off) { ls[tid] += ls[tid + off]; ls2[tid] += ls2[tid + off]; }
    __syncthreads();
  }
  if (tid < 64) {
    atomicAdd(&stats[tid], ls[tid]);
    atomicAdd(&stats[64 + tid], ls2[tid]);
  }
}

// ---------------- global_add_pool (batch is sorted) ----------------
__global__ void k_pool(const float* __restrict__ h, const int* __restrict__ batch,
                       float* __restrict__ g) {
  int lane = threadIdx.x & 63;
  int wave = (blockIdx.x * blockDim.x + threadIdx.x) >> 6;
  int nwaves = (gridDim.x * blockDim.x) >> 6;
  int chunk = (N_NODESC + nwaves - 1) / nwaves;
  int r0 = wave * chunk;
  int r1 = min(r0 + chunk, N_NODESC);
  if (r0 >= r1) return;
  int cur = batch[r0];
  float acc = 0.f;
  for (int r = r0; r < r1; ++r) {
    int b = batch[r];
    if (b != cur) {
      atomicAdd(&g[cur * 64 + lane], acc);
      acc = 0.f;
      cur = b;
    }
    acc += h[r * 64 + lane];
  }
  atomicAdd(&g[cur * 64 + lane], acc);
}

// ---------------- classifier + log_softmax ----------------
__global__ void k_cls(const float* __restrict__ g2, const float* __restrict__ Wc,
                      const float* __restrict__ bc, float* __restrict__ out) {
  int r = blockIdx.x * blockDim.x + threadIdx.x;
  if (r >= N_GRAPHSC) return;
  float z[NCLS];
#pragma unroll
  for (int c = 0; c < NCLS; ++c) z[c] = bc[c];
  for (int k = 0; k < HDIM; ++k) {
    float v = g2[r * HDIM + k];
#pragma unroll
    for (int c = 0; c < NCLS; ++c) z[c] = fmaf(v, Wc[k * NCLS + c], z[c]);
  }
  float m = z[0];
#pragma unroll
  for (int c = 1; c < NCLS; ++c) m = fmaxf(m, z[c]);
  float ssum = 0.f;
#pragma unroll
  for (int c = 0; c < NCLS; ++c) ssum += __expf(z[c] - m);
  float l = __logf(ssum);
#pragma unroll
  for (int c = 0; c < NCLS; ++c) out[r * NCLS + c] = z[c] - m - l;
}

extern "C" void kernel_launch(void* const* d_in, const int* in_sizes, int n_in,
                              void* d_out, int out_size, void* d_ws, size_t ws_size,
                              hipStream_t stream) {
  const float* x         = (const float*)d_in[0];
  const float* edge_attr = (const float*)d_in[1];
  const int*   ei        = (const int*)d_in[2];
  const int*   batch     = (const int*)d_in[3];
  const float* bn_feat_w = (const float*)d_in[4];
  const float* bn_feat_b = (const float*)d_in[5];
  const float* Wn0       = (const float*)d_in[6];
  const float* bn0       = (const float*)d_in[7];
  const float* We0       = (const float*)d_in[8];
  const float* be0       = (const float*)d_in[9];
  const float* bns_w     = (const float*)d_in[10];
  const float* bns_b     = (const float*)d_in[11];
  const float* Wn        = (const float*)d_in[12];
  const float* Wnb       = (const float*)d_in[13];
  const float* We        = (const float*)d_in[14];
  const float* Web       = (const float*)d_in[15];
  const float* bn_fc_w   = (const float*)d_in[16];
  const float* bn_fc_b   = (const float*)d_in[17];
  const float* Wfc       = (const float*)d_in[18];
  const float* bfc       = (const float*)d_in[19];
  const float* bn_hid_w  = (const float*)d_in[20];
  const float* bn_hid_b  = (const float*)d_in[21];
  const float* Wcls      = (const float*)d_in[22];
  const float* bcls      = (const float*)d_in[23];
  float* out = (float*)d_out;
  const int* src = ei;
  const int* dst = ei + N_EDGESC;

  char* p = (char*)d_ws;
  auto carve = [&](size_t bytes) {
    char* q = p;
    p += (bytes + 255) & ~(size_t)255;
    return q;
  };
  __hip_bfloat16* ebf = (__hip_bfloat16*)carve((size_t)N_EDGESC * 64 * 2);
  float* h    = (float*)carve((size_t)N_NODESC * 64 * 4);
  float* ht   = (float*)carve((size_t)N_NODESC * 64 * 4);
  float* hacc = (float*)carve((size_t)N_NODESC * 64 * 4);
  uint32* htP = (uint32*)carve((size_t)N_NODESC * 64 * 4);       // {bf16 ht, bf16 htA}
  unsigned short* htBb = (unsigned short*)carve((size_t)N_NODESC * 64 * 2);
  unsigned short* hAb  = (unsigned short*)carve((size_t)N_NODESC * 64 * 2);
  unsigned short* hBb  = (unsigned short*)carve((size_t)N_NODESC * 64 * 2);
  float* dinv = (float*)carve((size_t)N_NODESC * 4);
  float* g    = (float*)carve((size_t)N_GRAPHSC * 64 * 4);
  float* g2   = (float*)carve((size_t)N_GRAPHSC * 64 * 4);
  float* stats= (float*)carve(2 * 64 * 4);
  float* Wf   = (float*)carve(64 * 64 * 4);
  float* bf   = (float*)carve(64 * 4);
  uint32* degi   = (uint32*)carve((size_t)50176 * 4);
  uint32* ptr    = (uint32*)carve((size_t)50176 * 4);
  uint32* cursor = (uint32*)carve((size_t)50176 * 4);
  uint32* bsum   = (uint32*)carve(256 * 4);
  int* srcs  = (int*)carve((size_t)N_EDGESC * 4);
  int* dsts  = (int*)carve((size_t)N_EDGESC * 4);
  float* ea_s  = (float*)carve((size_t)N_EDGESC * FEDGE * 4);
  float* normf = (float*)carve((size_t)N_EDGESC * 4);

  // ---- degree, dinv, dst-sorted edge permutation ----
  hipMemsetAsync(degi, 0, 50176 * 4, stream);
  k_deg<<<(N_EDGESC + 255) / 256, 256, 0, stream>>>(dst, degi);
  k_dinv<<<(N_NODESC + 255) / 256, 256, 0, stream>>>(degi, dinv);
  k_scan1<<<SCAN_G, SCAN_B, 0, stream>>>(degi, ptr, bsum);
  k_scan2<<<1, 256, 0, stream>>>(bsum);
  k_scan3<<<SCAN_G, SCAN_B, 0, stream>>>(ptr, bsum);
  hipMemsetAsync(cursor, 0, 50176 * 4, stream);
  k_scatter<<<(N_EDGESC + 255) / 256, 256, 0, stream>>>(src, dst, edge_attr, dinv, ptr, cursor,
                                                        srcs, dsts, ea_s, normf);

  // ---- h0 = BN(x)@Wn0 + bn0 (BN folded) ----
  hipMemsetAsync(stats, 0, 512, stream);
  k_colstats<FNODE><<<256, 256, 0, stream>>>(x, N_NODESC, stats);
  k_foldbn<FNODE, HDIM><<<1, 256, 0, stream>>>(stats, 1.f / N_NODESC, bn_feat_w, bn_feat_b, Wn0, bn0, Wf, bf);
  k_nodemm<FNODE, false, FNODE, 64><<<512, 256, 0, stream>>>(x, N_NODESC, Wf, bf, h);

  // ---- edge features (sorted order): hA/hB bf16 ----
  k_nodemm_b<HDIM, 64><<<512, 256, 0, stream>>>(h, N_NODESC, We0, be0, hAb);
  k_nodemm_b<HDIM, 64><<<512, 256, 0, stream>>>(h, N_NODESC, We0 + 64 * 64, nullptr, hBb);
  k_edgeinit<<<1024, 256, 0, stream>>>(hAb, hBb, ea_s, We0 + 128 * 64, srcs, dsts, ebf);

  // ---- h = relu(h0), stats(h) ----
  hipMemsetAsync(stats, 0, 512, stream);
  k_relu_stats<<<256, 256, 0, stream>>>(h, h, stats, N_NODESC);

  for (int i = 0; i < 3; ++i) {
    const float* WeI = We + (size_t)i * 192 * 64;
    k_foldbn<HDIM, HDIM><<<1, 256, 0, stream>>>(stats, 1.f / N_NODESC, bns_w + i * 64, bns_b + i * 64,
                                                Wn + (size_t)i * 64 * 64, Wnb + i * 64, Wf, bf);
    k_nodemm<HDIM, false, 64, 64><<<512, 256, 0, stream>>>(h, N_NODESC, Wf, bf, ht);            // ht (fp32)
    k_nodemm_pack<<<512, 256, 0, stream>>>(ht, N_NODESC, WeI, Web + i * 64, htP);               // {ht,htA} bf16x2
    k_nodemm_b<HDIM, 64><<<512, 256, 0, stream>>>(ht, N_NODESC, WeI + 64 * 64, nullptr, htBb);  // htB bf16
    hipMemsetAsync(hacc, 0, (size_t)N_NODESC * 64 * 4, stream);
    k_conv_mfma<<<2048, 256, 0, stream>>>(ebf, WeI + 128 * 64, htP, htBb, normf, srcs, dsts, hacc);
    hipMemsetAsync(stats, 0, 512, stream);
    k_relu_stats<<<256, 256, 0, stream>>>(hacc, h, stats, N_NODESC);
  }

  // ---- pool + head ----
  hipMemsetAsync(g, 0, N_GRAPHSC * 64 * 4, stream);
  k_pool<<<64, 256, 0, stream>>>(h, batch, g);
  hipMemsetAsync(stats, 0, 512, stream);
  k_colstats<HDIM><<<32, 256, 0, stream>>>(g, N_GRAPHSC, stats);
  k_foldbn<HDIM, HDIM><<<1, 256, 0, stream>>>(stats, 1.f / N_GRAPHSC, bn_fc_w, bn_fc_b, Wfc, bfc, Wf, bf);
  k_nodemm<HDIM, true, 64, 64><<<128, 256, 0, stream>>>(g, N_GRAPHSC, Wf, bf, g2);
  hipMemsetAsync(stats, 0, 512, stream);
  k_colstats<HDIM><<<32, 256, 0, stream>>>(g2, N_GRAPHSC, stats);
  k_foldbn<HDIM, NCLS><<<1, 256, 0, stream>>>(stats, 1.f / N_GRAPHSC, bn_hid_w, bn_hid_b, Wcls, bcls, Wf, bf);
  k_cls<<<(N_GRAPHSC + 255) / 256, 256, 0, stream>>>(g2, Wf, bf, out);
}

// Round 6
// 1098.444 us; speedup vs baseline: 1.1760x; 1.0552x over previous
//
#include <hip/hip_runtime.h>
#include <hip/hip_bf16.h>

#define N_NODESC 50000
#define N_EDGESC 800000
#define N_GRAPHSC 512
#define HDIM 64
#define FNODE 32
#define FEDGE 8
#define NCLS 10
#define BN_EPS 1e-5f
#define SCAN_B 256
#define SCAN_G 196  // 196*256 = 50176 >= 50000

typedef __bf16 bf16x8 __attribute__((ext_vector_type(8)));
typedef float f32x4 __attribute__((ext_vector_type(4)));
typedef unsigned int uint32;

static __device__ __forceinline__ float bcast(float v, int k) {
  return __uint_as_float(__builtin_amdgcn_readlane(__float_as_uint(v), k));
}
static __device__ __forceinline__ unsigned short f2bu(float f) {
  __hip_bfloat16 b = __float2bfloat16(f);
  return *reinterpret_cast<unsigned short*>(&b);
}
static __device__ __forceinline__ float bu2f(unsigned short u) {
  __hip_bfloat16 b;
  *reinterpret_cast<unsigned short*>(&b) = u;
  return __bfloat162float(b);
}

// ---------------- degree ----------------
__global__ void k_deg(const int* __restrict__ dst, uint32* __restrict__ degi) {
  int e = blockIdx.x * blockDim.x + threadIdx.x;
  if (e < N_EDGESC) atomicAdd(&degi[dst[e]], 1u);
}

__global__ void k_dinv(const uint32* __restrict__ degi, float* __restrict__ dinv) {
  int n = blockIdx.x * blockDim.x + threadIdx.x;
  if (n < N_NODESC) dinv[n] = rsqrtf(fmaxf((float)degi[n], 1.0f));
}

// ---------------- exclusive prefix sum over degi -> ptr ----------------
__global__ void k_scan1(const uint32* __restrict__ degi, uint32* __restrict__ ptr,
                        uint32* __restrict__ bsum) {
  __shared__ uint32 s[SCAN_B];
  int t = threadIdx.x;
  int i = blockIdx.x * SCAN_B + t;
  uint32 v = (i < N_NODESC) ? degi[i] : 0u;
  s[t] = v; __syncthreads();
  for (int off = 1; off < SCAN_B; off <<= 1) {
    uint32 x = (t >= off) ? s[t - off] : 0u; __syncthreads();
    s[t] += x; __syncthreads();
  }
  if (i < N_NODESC) ptr[i] = s[t] - v;  // exclusive local scan
  if (t == SCAN_B - 1) bsum[blockIdx.x] = s[t];
}

__global__ void k_scan2(uint32* __restrict__ bsum) {
  __shared__ uint32 s[256];
  int t = threadIdx.x;
  uint32 v = (t < SCAN_G) ? bsum[t] : 0u;
  s[t] = v; __syncthreads();
  for (int off = 1; off < 256; off <<= 1) {
    uint32 x = (t >= off) ? s[t - off] : 0u; __syncthreads();
    s[t] += x; __syncthreads();
  }
  if (t < SCAN_G) bsum[t] = s[t] - v;  // exclusive
}

__global__ void k_scan3(uint32* __restrict__ ptr, const uint32* __restrict__ bsum) {
  int i = blockIdx.x * SCAN_B + threadIdx.x;
  if (i < N_NODESC) ptr[i] += bsum[blockIdx.x];
}

// ---------------- scatter edges into dst-sorted order (+ea permute, +normf) ----------------
__global__ void k_scatter(const int* __restrict__ src, const int* __restrict__ dst,
                          const float* __restrict__ ea, const float* __restrict__ dinv,
                          const uint32* __restrict__ ptr, uint32* __restrict__ cursor,
                          int* __restrict__ srcs, int* __restrict__ dsts,
                          float* __restrict__ ea_s, float* __restrict__ normf) {
  int e = blockIdx.x * blockDim.x + threadIdx.x;
  if (e < N_EDGESC) {
    int d = dst[e];
    int s = src[e];
    float4 a0 = *reinterpret_cast<const float4*>(ea + (size_t)e * FEDGE);
    float4 a1 = *reinterpret_cast<const float4*>(ea + (size_t)e * FEDGE + 4);
    uint32 r = atomicAdd(&cursor[d], 1u);
    uint32 i = ptr[d] + r;
    srcs[i] = s;
    dsts[i] = d;
    normf[i] = dinv[s] * dinv[d];
    *reinterpret_cast<float4*>(ea_s + (size_t)i * FEDGE) = a0;
    *reinterpret_cast<float4*>(ea_s + (size_t)i * FEDGE + 4) = a1;
  }
}

// ---------------- column stats (sum, sumsq) ----------------
template <int C>
__global__ void k_colstats(const float* __restrict__ in, int nrows, float* __restrict__ stats) {
  const int RPB = 256 / C;
  int tid = threadIdx.x;
  int col = tid % C;
  int rowOff = tid / C;
  float s = 0.f, s2 = 0.f;
  for (int r = blockIdx.x * RPB + rowOff; r < nrows; r += gridDim.x * RPB) {
    float v = in[r * C + col];
    s += v; s2 += v * v;
  }
  __shared__ float ls[256], ls2[256];
  ls[tid] = s; ls2[tid] = s2;
  __syncthreads();
  for (int off = 128; off >= C; off >>= 1) {
    if (tid < off) { ls[tid] += ls[tid + off]; ls2[tid] += ls2[tid + off]; }
    __syncthreads();
  }
  if (tid < C) {
    atomicAdd(&stats[tid], ls[tid]);
    atomicAdd(&stats[C + tid], ls2[tid]);
  }
}

// ---------------- fold BN into weights ----------------
template <int CIN, int COUT>
__global__ void k_foldbn(const float* __restrict__ stats, float invN,
                         const float* __restrict__ bnw, const float* __restrict__ bnb,
                         const float* __restrict__ W, const float* __restrict__ bias,
                         float* __restrict__ Wf, float* __restrict__ bf) {
  __shared__ float a[CIN], sh[CIN];
  int tid = threadIdx.x;
  if (tid < CIN) {
    float m = stats[tid] * invN;
    float v = stats[CIN + tid] * invN - m * m;
    float inv = rsqrtf(v + BN_EPS);
    float aa = bnw[tid] * inv;
    a[tid] = aa;
    sh[tid] = bnb[tid] - m * aa;
  }
  __syncthreads();
  for (int i = tid; i < CIN * COUT; i += 256) {
    int r = i / COUT;
    Wf[i] = a[r] * W[i];
  }
  if (tid < COUT) {
    float acc = bias ? bias[tid] : 0.f;
    for (int r = 0; r < CIN; ++r) acc += sh[r] * W[r * COUT + tid];
    bf[tid] = acc;
  }
}

// ---------------- out[N,64] = in[N,K](ld LDIN) @ W[K,64] + bias (fp32 out) ----------------
template <int K, bool RELU, int LDIN, int LDOUT>
__global__ void k_nodemm(const float* __restrict__ in, int nrows,
                         const float* __restrict__ W, const float* __restrict__ bias,
                         float* __restrict__ out) {
  int tid = threadIdx.x;
  int lane = tid & 63;
  float w[K];
#pragma unroll
  for (int k = 0; k < K; ++k) w[k] = W[k * 64 + lane];
  float bv = bias ? bias[lane] : 0.f;
  int wave = (blockIdx.x * blockDim.x + tid) >> 6;
  int nwaves = (gridDim.x * blockDim.x) >> 6;
  for (int r = wave; r < nrows; r += nwaves) {
    float rv = (lane < K) ? in[(size_t)r * LDIN + lane] : 0.f;
    float acc = bv;
#pragma unroll
    for (int k = 0; k < K; ++k) acc = fmaf(bcast(rv, k), w[k], acc);
    if (RELU) acc = fmaxf(acc, 0.f);
    out[(size_t)r * LDOUT + lane] = acc;
  }
}

// ---------------- bf16-out nodemm: out[N,64] bf16 ----------------
template <int K, int LDIN>
__global__ void k_nodemm_b(const float* __restrict__ in, int nrows,
                           const float* __restrict__ W, const float* __restrict__ bias,
                           unsigned short* __restrict__ out) {
  int tid = threadIdx.x;
  int lane = tid & 63;
  float w[K];
#pragma unroll
  for (int k = 0; k < K; ++k) w[k] = W[k * 64 + lane];
  float bv = bias ? bias[lane] : 0.f;
  int wave = (blockIdx.x * blockDim.x + tid) >> 6;
  int nwaves = (gridDim.x * blockDim.x) >> 6;
  for (int r = wave; r < nrows; r += nwaves) {
    float rv = (lane < K) ? in[(size_t)r * LDIN + lane] : 0.f;
    float acc = bv;
#pragma unroll
    for (int k = 0; k < K; ++k) acc = fmaf(bcast(rv, k), w[k], acc);
    out[(size_t)r * 64 + lane] = f2bu(acc);
  }
}

// ---------------- pack nodemm: computes htA = ht@W + bias, writes {bf16 ht, bf16 htA} ----------------
__global__ void k_nodemm_pack(const float* __restrict__ ht, int nrows,
                              const float* __restrict__ W, const float* __restrict__ bias,
                              uint32* __restrict__ htP) {
  int tid = threadIdx.x;
  int lane = tid & 63;
  float w[64];
#pragma unroll
  for (int k = 0; k < 64; ++k) w[k] = W[k * 64 + lane];
  float bv = bias[lane];
  int wave = (blockIdx.x * blockDim.x + tid) >> 6;
  int nwaves = (gridDim.x * blockDim.x) >> 6;
  for (int r = wave; r < nrows; r += nwaves) {
    float rv = ht[(size_t)r * 64 + lane];  // ht[r][lane]
    float acc = bv;
#pragma unroll
    for (int k = 0; k < 64; ++k) acc = fmaf(bcast(rv, k), w[k], acc);
    htP[(size_t)r * 64 + lane] = ((uint32)f2bu(acc) << 16) | (uint32)f2bu(rv);
  }
}

// ---------------- e = relu(hA[src]+hB[dst]+ea_s@We0c) -> bf16 (2-edge batched loads) ----------------
__global__ void k_edgeinit(const unsigned short* __restrict__ hAb,
                           const unsigned short* __restrict__ hBb,
                           const float* __restrict__ ea_s, const float* __restrict__ Wc,
                           const int* __restrict__ srcs, const int* __restrict__ dsts,
                           __hip_bfloat16* __restrict__ ebf) {
  int tid = threadIdx.x;
  int lane = tid & 63;
  float w[FEDGE];
#pragma unroll
  for (int k = 0; k < FEDGE; ++k) w[k] = Wc[k * 64 + lane];
  int wave = (blockIdx.x * blockDim.x + tid) >> 6;
  int nwaves = (gridDim.x * blockDim.x) >> 6;
  for (int e = 2 * wave; e < N_EDGESC; e += 2 * nwaves) {
    // phase 1: batch all loads for both edges
    int s0 = srcs[e], d0 = dsts[e];
    int s1 = srcs[e + 1], d1 = dsts[e + 1];
    float av0 = (lane < FEDGE) ? ea_s[(size_t)e * FEDGE + lane] : 0.f;
    float av1 = (lane < FEDGE) ? ea_s[(size_t)(e + 1) * FEDGE + lane] : 0.f;
    unsigned short a0 = hAb[s0 * 64 + lane];
    unsigned short b0 = hBb[d0 * 64 + lane];
    unsigned short a1 = hAb[s1 * 64 + lane];
    unsigned short b1 = hBb[d1 * 64 + lane];
    // phase 2: compute + store
    float acc0 = bu2f(a0) + bu2f(b0);
    float acc1 = bu2f(a1) + bu2f(b1);
#pragma unroll
    for (int k = 0; k < FEDGE; ++k) {
      acc0 = fmaf(bcast(av0, k), w[k], acc0);
      acc1 = fmaf(bcast(av1, k), w[k], acc1);
    }
    acc0 = fmaxf(acc0, 0.f);
    acc1 = fmaxf(acc1, 0.f);
    __builtin_nontemporal_store(f2bu(acc0),
        reinterpret_cast<unsigned short*>(ebf) + (size_t)e * 64 + lane);
    __builtin_nontemporal_store(f2bu(acc1),
        reinterpret_cast<unsigned short*>(ebf) + (size_t)(e + 1) * 64 + lane);
  }
}

// ---------------- edge-gated conv: phased loads -> MFMA -> VALU -> flush ----------------
// htP[n][c] = {lo: bf16 ht, hi: bf16 htA}; htBb[n][c] = bf16 htB
__global__ void __launch_bounds__(256) k_conv_mfma(
    const __hip_bfloat16* __restrict__ ebf,
    const float* __restrict__ We2,
    const uint32* __restrict__ htP, const unsigned short* __restrict__ htBb,
    const float* __restrict__ normf,
    const int* __restrict__ srcs, const int* __restrict__ dsts,
    float* __restrict__ hacc) {
  const int lane = threadIdx.x & 63;
  const int m  = lane & 15;   // A-row / B-col within 16-tile
  const int kg = lane >> 4;   // k-group

  // B fragments: b[t][s] -> B[k = s*32 + kg*8 + j][c = t*16 + m]
  bf16x8 b[4][2];
#pragma unroll
  for (int t = 0; t < 4; ++t)
#pragma unroll
    for (int s = 0; s < 2; ++s)
#pragma unroll
      for (int j = 0; j < 8; ++j) {
        int k = s * 32 + kg * 8 + j;
        int c = t * 16 + m;
        b[t][s][j] = (__bf16)We2[k * 64 + c];
      }

  int wave = (blockIdx.x * blockDim.x + threadIdx.x) >> 6;
  int nwaves = (gridDim.x * blockDim.x) >> 6;
  const int ntiles = N_EDGESC / 16;
  for (int tile = wave; tile < ntiles; tile += nwaves) {
    int base = tile * 16;
    // ---- phase 1: issue ALL loads (pure, no stores/branches between) ----
    const bf16x8* arow = reinterpret_cast<const bf16x8*>(ebf + (size_t)(base + m) * 64 + kg * 8);
    bf16x8 a0 = __builtin_nontemporal_load(arow);
    bf16x8 a1 = __builtin_nontemporal_load(arow + 4);
    int rbase = base + kg * 4;
    int se[4], de[4];
    float ne[4];
#pragma unroll
    for (int j = 0; j < 4; ++j) {
      se[j] = srcs[rbase + j];
      de[j] = dsts[rbase + j];
      ne[j] = normf[rbase + j];
    }
    uint32 pv[4][4];
    unsigned short hv[4][4];
#pragma unroll
    for (int j = 0; j < 4; ++j) {
#pragma unroll
      for (int t = 0; t < 4; ++t) {
        int c = t * 16 + m;
        pv[j][t] = htP[(size_t)se[j] * 64 + c];
        hv[j][t] = htBb[(size_t)de[j] * 64 + c];
      }
    }
    // ---- phase 2: MFMA ----
    f32x4 acc[4];
#pragma unroll
    for (int t = 0; t < 4; ++t) {
      f32x4 z = {0.f, 0.f, 0.f, 0.f};
      acc[t] = __builtin_amdgcn_mfma_f32_16x16x32_bf16(a0, b[t][0], z, 0, 0, 0);
      acc[t] = __builtin_amdgcn_mfma_f32_16x16x32_bf16(a1, b[t][1], acc[t], 0, 0, 0);
    }
    // ---- phase 3: pure VALU msg computation ----
    float msg[4][4];
#pragma unroll
    for (int j = 0; j < 4; ++j) {
#pragma unroll
      for (int t = 0; t < 4; ++t) {
        float gate = acc[t][j] + bu2f((unsigned short)(pv[j][t] >> 16)) + bu2f(hv[j][t]);
        float sig = 1.0f / (1.0f + __expf(-gate));
        msg[j][t] = ne[j] * bu2f((unsigned short)(pv[j][t] & 0xffffu)) * sig;
      }
    }
    // ---- phase 4: run-accumulate flush (atomics only here) ----
    float run[4] = {0.f, 0.f, 0.f, 0.f};
    int dcur = de[0];
#pragma unroll
    for (int j = 0; j < 4; ++j) {
      if (de[j] != dcur) {
#pragma unroll
        for (int t = 0; t < 4; ++t) {
          atomicAdd(&hacc[dcur * 64 + t * 16 + m], run[t]);
          run[t] = 0.f;
        }
        dcur = de[j];
      }
#pragma unroll
      for (int t = 0; t < 4; ++t) run[t] += msg[j][t];
    }
#pragma unroll
    for (int t = 0; t < 4; ++t)
      atomicAdd(&hacc[dcur * 64 + t * 16 + m], run[t]);
  }
}

// ---------------- h = relu(in), column stats of result ----------------
__global__ void k_relu_stats(const float* __restrict__ in, float* __restrict__ h,
                             float* __restrict__ stats, int nrows) {
  int tid = threadIdx.x;
  float s = 0.f, s2 = 0.f;
  int total = nrows * 64;
  for (int i = blockIdx.x * 256 + tid; i < total; i += gridDim.x * 256) {
    float v = fmaxf(in[i], 0.f);
    h[i] = v;
    s += v; s2 += v * v;
  }
  __shared__ float ls[256], ls2[256];
  ls[tid] = s; ls2[tid] = s2;
  __syncthreads();
  for (int off = 128; off >= 64; off >>= 1) {
    if (tid < off) { ls[tid] += ls[tid + off]; ls2[tid] += ls2[tid + off]; }
    __syncthreads();
  }
  if (tid < 64) {
    atomicAdd(&stats[tid], ls[tid]);
    atomicAdd(&stats[64 + tid], ls2[tid]);
  }
}

// ---------------- global_add_pool (batch is sorted) ----------------
__global__ void k_pool(const float* __restrict__ h, const int* __restrict__ batch,
                       float* __restrict__ g) {
  int lane = threadIdx.x & 63;
  int wave = (blockIdx.x * blockDim.x + threadIdx.x) >> 6;
  int nwaves = (gridDim.x * blockDim.x) >> 6;
  int chunk = (N_NODESC + nwaves - 1) / nwaves;
  int r0 = wave * chunk;
  int r1 = min(r0 + chunk, N_NODESC);
  if (r0 >= r1) return;
  int cur = batch[r0];
  float acc = 0.f;
  for (int r = r0; r < r1; ++r) {
    int b = batch[r];
    if (b != cur) {
      atomicAdd(&g[cur * 64 + lane], acc);
      acc = 0.f;
      cur = b;
    }
    acc += h[r * 64 + lane];
  }
  atomicAdd(&g[cur * 64 + lane], acc);
}

// ---------------- classifier + log_softmax ----------------
__global__ void k_cls(const float* __restrict__ g2, const float* __restrict__ Wc,
                      const float* __restrict__ bc, float* __restrict__ out) {
  int r = blockIdx.x * blockDim.x + threadIdx.x;
  if (r >= N_GRAPHSC) return;
  float z[NCLS];
#pragma unroll
  for (int c = 0; c < NCLS; ++c) z[c] = bc[c];
  for (int k = 0; k < HDIM; ++k) {
    float v = g2[r * HDIM + k];
#pragma unroll
    for (int c = 0; c < NCLS; ++c) z[c] = fmaf(v, Wc[k * NCLS + c], z[c]);
  }
  float m = z[0];
#pragma unroll
  for (int c = 1; c < NCLS; ++c) m = fmaxf(m, z[c]);
  float ssum = 0.f;
#pragma unroll
  for (int c = 0; c < NCLS; ++c) ssum += __expf(z[c] - m);
  float l = __logf(ssum);
#pragma unroll
  for (int c = 0; c < NCLS; ++c) out[r * NCLS + c] = z[c] - m - l;
}

extern "C" void kernel_launch(void* const* d_in, const int* in_sizes, int n_in,
                              void* d_out, int out_size, void* d_ws, size_t ws_size,
                              hipStream_t stream) {
  const float* x         = (const float*)d_in[0];
  const float* edge_attr = (const float*)d_in[1];
  const int*   ei        = (const int*)d_in[2];
  const int*   batch     = (const int*)d_in[3];
  const float* bn_feat_w = (const float*)d_in[4];
  const float* bn_feat_b = (const float*)d_in[5];
  const float* Wn0       = (const float*)d_in[6];
  const float* bn0       = (const float*)d_in[7];
  const float* We0       = (const float*)d_in[8];
  const float* be0       = (const float*)d_in[9];
  const float* bns_w     = (const float*)d_in[10];
  const float* bns_b     = (const float*)d_in[11];
  const float* Wn        = (const float*)d_in[12];
  const float* Wnb       = (const float*)d_in[13];
  const float* We        = (const float*)d_in[14];
  const float* Web       = (const float*)d_in[15];
  const float* bn_fc_w   = (const float*)d_in[16];
  const float* bn_fc_b   = (const float*)d_in[17];
  const float* Wfc       = (const float*)d_in[18];
  const float* bfc       = (const float*)d_in[19];
  const float* bn_hid_w  = (const float*)d_in[20];
  const float* bn_hid_b  = (const float*)d_in[21];
  const float* Wcls      = (const float*)d_in[22];
  const float* bcls      = (const float*)d_in[23];
  float* out = (float*)d_out;
  const int* src = ei;
  const int* dst = ei + N_EDGESC;

  char* p = (char*)d_ws;
  auto carve = [&](size_t bytes) {
    char* q = p;
    p += (bytes + 255) & ~(size_t)255;
    return q;
  };
  __hip_bfloat16* ebf = (__hip_bfloat16*)carve((size_t)N_EDGESC * 64 * 2);
  float* h    = (float*)carve((size_t)N_NODESC * 64 * 4);
  float* ht   = (float*)carve((size_t)N_NODESC * 64 * 4);
  float* hacc = (float*)carve((size_t)N_NODESC * 64 * 4);
  uint32* htP = (uint32*)carve((size_t)N_NODESC * 64 * 4);       // {bf16 ht, bf16 htA}
  unsigned short* htBb = (unsigned short*)carve((size_t)N_NODESC * 64 * 2);
  unsigned short* hAb  = (unsigned short*)carve((size_t)N_NODESC * 64 * 2);
  unsigned short* hBb  = (unsigned short*)carve((size_t)N_NODESC * 64 * 2);
  float* dinv = (float*)carve((size_t)N_NODESC * 4);
  float* g    = (float*)carve((size_t)N_GRAPHSC * 64 * 4);
  float* g2   = (float*)carve((size_t)N_GRAPHSC * 64 * 4);
  float* stats= (float*)carve(2 * 64 * 4);
  float* Wf   = (float*)carve(64 * 64 * 4);
  float* bf   = (float*)carve(64 * 4);
  uint32* degi   = (uint32*)carve((size_t)50176 * 4);
  uint32* ptr    = (uint32*)carve((size_t)50176 * 4);
  uint32* cursor = (uint32*)carve((size_t)50176 * 4);
  uint32* bsum   = (uint32*)carve(256 * 4);
  int* srcs  = (int*)carve((size_t)N_EDGESC * 4);
  int* dsts  = (int*)carve((size_t)N_EDGESC * 4);
  float* ea_s  = (float*)carve((size_t)N_EDGESC * FEDGE * 4);
  float* normf = (float*)carve((size_t)N_EDGESC * 4);

  // ---- degree, dinv, dst-sorted edge permutation ----
  hipMemsetAsync(degi, 0, 50176 * 4, stream);
  k_deg<<<(N_EDGESC + 255) / 256, 256, 0, stream>>>(dst, degi);
  k_dinv<<<(N_NODESC + 255) / 256, 256, 0, stream>>>(degi, dinv);
  k_scan1<<<SCAN_G, SCAN_B, 0, stream>>>(degi, ptr, bsum);
  k_scan2<<<1, 256, 0, stream>>>(bsum);
  k_scan3<<<SCAN_G, SCAN_B, 0, stream>>>(ptr, bsum);
  hipMemsetAsync(cursor, 0, 50176 * 4, stream);
  k_scatter<<<(N_EDGESC + 255) / 256, 256, 0, stream>>>(src, dst, edge_attr, dinv, ptr, cursor,
                                                        srcs, dsts, ea_s, normf);

  // ---- h0 = BN(x)@Wn0 + bn0 (BN folded) ----
  hipMemsetAsync(stats, 0, 512, stream);
  k_colstats<FNODE><<<256, 256, 0, stream>>>(x, N_NODESC, stats);
  k_foldbn<FNODE, HDIM><<<1, 256, 0, stream>>>(stats, 1.f / N_NODESC, bn_feat_w, bn_feat_b, Wn0, bn0, Wf, bf);
  k_nodemm<FNODE, false, FNODE, 64><<<512, 256, 0, stream>>>(x, N_NODESC, Wf, bf, h);

  // ---- edge features (sorted order): hA/hB bf16 ----
  k_nodemm_b<HDIM, 64><<<512, 256, 0, stream>>>(h, N_NODESC, We0, be0, hAb);
  k_nodemm_b<HDIM, 64><<<512, 256, 0, stream>>>(h, N_NODESC, We0 + 64 * 64, nullptr, hBb);
  k_edgeinit<<<1024, 256, 0, stream>>>(hAb, hBb, ea_s, We0 + 128 * 64, srcs, dsts, ebf);

  // ---- h = relu(h0), stats(h) ----
  hipMemsetAsync(stats, 0, 512, stream);
  k_relu_stats<<<256, 256, 0, stream>>>(h, h, stats, N_NODESC);

  for (int i = 0; i < 3; ++i) {
    const float* WeI = We + (size_t)i * 192 * 64;
    k_foldbn<HDIM, HDIM><<<1, 256, 0, stream>>>(stats, 1.f / N_NODESC, bns_w + i * 64, bns_b + i * 64,
                                                Wn + (size_t)i * 64 * 64, Wnb + i * 64, Wf, bf);
    k_nodemm<HDIM, false, 64, 64><<<512, 256, 0, stream>>>(h, N_NODESC, Wf, bf, ht);            // ht (fp32)
    k_nodemm_pack<<<512, 256, 0, stream>>>(ht, N_NODESC, WeI, Web + i * 64, htP);               // {ht,htA} bf16x2
    k_nodemm_b<HDIM, 64><<<512, 256, 0, stream>>>(ht, N_NODESC, WeI + 64 * 64, nullptr, htBb);  // htB bf16
    hipMemsetAsync(hacc, 0, (size_t)N_NODESC * 64 * 4, stream);
    k_conv_mfma<<<2048, 256, 0, stream>>>(ebf, WeI + 128 * 64, htP, htBb, normf, srcs, dsts, hacc);
    hipMemsetAsync(stats, 0, 512, stream);
    k_relu_stats<<<256, 256, 0, stream>>>(hacc, h, stats, N_NODESC);
  }

  // ---- pool + head ----
  hipMemsetAsync(g, 0, N_GRAPHSC * 64 * 4, stream);
  k_pool<<<64, 256, 0, stream>>>(h, batch, g);
  hipMemsetAsync(stats, 0, 512, stream);
  k_colstats<HDIM><<<32, 256, 0, stream>>>(g, N_GRAPHSC, stats);
  k_foldbn<HDIM, HDIM><<<1, 256, 0, stream>>>(stats, 1.f / N_GRAPHSC, bn_fc_w, bn_fc_b, Wfc, bfc, Wf, bf);
  k_nodemm<HDIM, true, 64, 64><<<128, 256, 0, stream>>>(g, N_GRAPHSC, Wf, bf, g2);
  hipMemsetAsync(stats, 0, 512, stream);
  k_colstats<HDIM><<<32, 256, 0, stream>>>(g2, N_GRAPHSC, stats);
  k_foldbn<HDIM, NCLS><<<1, 256, 0, stream>>>(stats, 1.f / N_GRAPHSC, bn_hid_w, bn_hid_b, Wcls, bcls, Wf, bf);
  k_cls<<<(N_GRAPHSC + 255) / 256, 256, 0, stream>>>(g2, Wf, bf, out);
}

// Round 7
// 1023.851 us; speedup vs baseline: 1.2616x; 1.0729x over previous
//
#include <hip/hip_runtime.h>
#include <hip/hip_bf16.h>

#define N_NODESC 50000
#define N_EDGESC 800000
#define N_GRAPHSC 512
#define HDIM 64
#define FNODE 32
#define FEDGE 8
#define NCLS 10
#define BN_EPS 1e-5f
#define SCAN_B 256
#define SCAN_G 196  // 196*256 = 50176 >= 50000

typedef __bf16 bf16x8 __attribute__((ext_vector_type(8)));
typedef float f32x4 __attribute__((ext_vector_type(4)));
typedef unsigned int uint32;

static __device__ __forceinline__ float bcast(float v, int k) {
  return __uint_as_float(__builtin_amdgcn_readlane(__float_as_uint(v), k));
}
static __device__ __forceinline__ unsigned short f2bu(float f) {
  __hip_bfloat16 b = __float2bfloat16(f);
  return *reinterpret_cast<unsigned short*>(&b);
}
static __device__ __forceinline__ float bu2f(unsigned short u) {
  __hip_bfloat16 b;
  *reinterpret_cast<unsigned short*>(&b) = u;
  return __bfloat162float(b);
}

// ---------------- degree ----------------
__global__ void k_deg(const int* __restrict__ dst, uint32* __restrict__ degi) {
  int e = blockIdx.x * blockDim.x + threadIdx.x;
  if (e < N_EDGESC) atomicAdd(&degi[dst[e]], 1u);
}

__global__ void k_dinv(const uint32* __restrict__ degi, float* __restrict__ dinv) {
  int n = blockIdx.x * blockDim.x + threadIdx.x;
  if (n < N_NODESC) dinv[n] = rsqrtf(fmaxf((float)degi[n], 1.0f));
}

// ---------------- exclusive prefix sum over degi -> ptr ----------------
__global__ void k_scan1(const uint32* __restrict__ degi, uint32* __restrict__ ptr,
                        uint32* __restrict__ bsum) {
  __shared__ uint32 s[SCAN_B];
  int t = threadIdx.x;
  int i = blockIdx.x * SCAN_B + t;
  uint32 v = (i < N_NODESC) ? degi[i] : 0u;
  s[t] = v; __syncthreads();
  for (int off = 1; off < SCAN_B; off <<= 1) {
    uint32 x = (t >= off) ? s[t - off] : 0u; __syncthreads();
    s[t] += x; __syncthreads();
  }
  if (i < N_NODESC) ptr[i] = s[t] - v;  // exclusive local scan
  if (t == SCAN_B - 1) bsum[blockIdx.x] = s[t];
}

__global__ void k_scan2(uint32* __restrict__ bsum) {
  __shared__ uint32 s[256];
  int t = threadIdx.x;
  uint32 v = (t < SCAN_G) ? bsum[t] : 0u;
  s[t] = v; __syncthreads();
  for (int off = 1; off < 256; off <<= 1) {
    uint32 x = (t >= off) ? s[t - off] : 0u; __syncthreads();
    s[t] += x; __syncthreads();
  }
  if (t < SCAN_G) bsum[t] = s[t] - v;  // exclusive
}

__global__ void k_scan3(uint32* __restrict__ ptr, const uint32* __restrict__ bsum) {
  int i = blockIdx.x * SCAN_B + threadIdx.x;
  if (i < N_NODESC) ptr[i] += bsum[blockIdx.x];
}

// ---------------- scatter edges into dst-sorted order (+ea permute, +normf) ----------------
__global__ void k_scatter(const int* __restrict__ src, const int* __restrict__ dst,
                          const float* __restrict__ ea, const float* __restrict__ dinv,
                          const uint32* __restrict__ ptr, uint32* __restrict__ cursor,
                          int* __restrict__ srcs, int* __restrict__ dsts,
                          float* __restrict__ ea_s, float* __restrict__ normf) {
  int e = blockIdx.x * blockDim.x + threadIdx.x;
  if (e < N_EDGESC) {
    int d = dst[e];
    int s = src[e];
    float4 a0 = *reinterpret_cast<const float4*>(ea + (size_t)e * FEDGE);
    float4 a1 = *reinterpret_cast<const float4*>(ea + (size_t)e * FEDGE + 4);
    uint32 r = atomicAdd(&cursor[d], 1u);
    uint32 i = ptr[d] + r;
    srcs[i] = s;
    dsts[i] = d;
    normf[i] = dinv[s] * dinv[d];
    *reinterpret_cast<float4*>(ea_s + (size_t)i * FEDGE) = a0;
    *reinterpret_cast<float4*>(ea_s + (size_t)i * FEDGE + 4) = a1;
  }
}

// ---------------- column stats (sum, sumsq) ----------------
template <int C>
__global__ void k_colstats(const float* __restrict__ in, int nrows, float* __restrict__ stats) {
  const int RPB = 256 / C;
  int tid = threadIdx.x;
  int col = tid % C;
  int rowOff = tid / C;
  float s = 0.f, s2 = 0.f;
  for (int r = blockIdx.x * RPB + rowOff; r < nrows; r += gridDim.x * RPB) {
    float v = in[r * C + col];
    s += v; s2 += v * v;
  }
  __shared__ float ls[256], ls2[256];
  ls[tid] = s; ls2[tid] = s2;
  __syncthreads();
  for (int off = 128; off >= C; off >>= 1) {
    if (tid < off) { ls[tid] += ls[tid + off]; ls2[tid] += ls2[tid + off]; }
    __syncthreads();
  }
  if (tid < C) {
    atomicAdd(&stats[tid], ls[tid]);
    atomicAdd(&stats[C + tid], ls2[tid]);
  }
}

// ---------------- fold BN into weights ----------------
template <int CIN, int COUT>
__global__ void k_foldbn(const float* __restrict__ stats, float invN,
                         const float* __restrict__ bnw, const float* __restrict__ bnb,
                         const float* __restrict__ W, const float* __restrict__ bias,
                         float* __restrict__ Wf, float* __restrict__ bf) {
  __shared__ float a[CIN], sh[CIN];
  int tid = threadIdx.x;
  if (tid < CIN) {
    float m = stats[tid] * invN;
    float v = stats[CIN + tid] * invN - m * m;
    float inv = rsqrtf(v + BN_EPS);
    float aa = bnw[tid] * inv;
    a[tid] = aa;
    sh[tid] = bnb[tid] - m * aa;
  }
  __syncthreads();
  for (int i = tid; i < CIN * COUT; i += 256) {
    int r = i / COUT;
    Wf[i] = a[r] * W[i];
  }
  if (tid < COUT) {
    float acc = bias ? bias[tid] : 0.f;
    for (int r = 0; r < CIN; ++r) acc += sh[r] * W[r * COUT + tid];
    bf[tid] = acc;
  }
}

// ---------------- out[N,64] = in[N,K](ld LDIN) @ W[K,64] + bias (fp32 out) ----------------
template <int K, bool RELU, int LDIN, int LDOUT>
__global__ void k_nodemm(const float* __restrict__ in, int nrows,
                         const float* __restrict__ W, const float* __restrict__ bias,
                         float* __restrict__ out) {
  int tid = threadIdx.x;
  int lane = tid & 63;
  float w[K];
#pragma unroll
  for (int k = 0; k < K; ++k) w[k] = W[k * 64 + lane];
  float bv = bias ? bias[lane] : 0.f;
  int wave = (blockIdx.x * blockDim.x + tid) >> 6;
  int nwaves = (gridDim.x * blockDim.x) >> 6;
  for (int r = wave; r < nrows; r += nwaves) {
    float rv = (lane < K) ? in[(size_t)r * LDIN + lane] : 0.f;
    float acc = bv;
#pragma unroll
    for (int k = 0; k < K; ++k) acc = fmaf(bcast(rv, k), w[k], acc);
    if (RELU) acc = fmaxf(acc, 0.f);
    out[(size_t)r * LDOUT + lane] = acc;
  }
}

// ---------------- bf16-out nodemm: out[N,64] bf16 ----------------
template <int K, int LDIN>
__global__ void k_nodemm_b(const float* __restrict__ in, int nrows,
                           const float* __restrict__ W, const float* __restrict__ bias,
                           unsigned short* __restrict__ out) {
  int tid = threadIdx.x;
  int lane = tid & 63;
  float w[K];
#pragma unroll
  for (int k = 0; k < K; ++k) w[k] = W[k * 64 + lane];
  float bv = bias ? bias[lane] : 0.f;
  int wave = (blockIdx.x * blockDim.x + tid) >> 6;
  int nwaves = (gridDim.x * blockDim.x) >> 6;
  for (int r = wave; r < nrows; r += nwaves) {
    float rv = (lane < K) ? in[(size_t)r * LDIN + lane] : 0.f;
    float acc = bv;
#pragma unroll
    for (int k = 0; k < K; ++k) acc = fmaf(bcast(rv, k), w[k], acc);
    out[(size_t)r * 64 + lane] = f2bu(acc);
  }
}

// ---------------- pack nodemm: computes htA = ht@W + bias, writes {bf16 ht, bf16 htA} ----------------
__global__ void k_nodemm_pack(const float* __restrict__ ht, int nrows,
                              const float* __restrict__ W, const float* __restrict__ bias,
                              uint32* __restrict__ htP) {
  int tid = threadIdx.x;
  int lane = tid & 63;
  float w[64];
#pragma unroll
  for (int k = 0; k < 64; ++k) w[k] = W[k * 64 + lane];
  float bv = bias[lane];
  int wave = (blockIdx.x * blockDim.x + tid) >> 6;
  int nwaves = (gridDim.x * blockDim.x) >> 6;
  for (int r = wave; r < nrows; r += nwaves) {
    float rv = ht[(size_t)r * 64 + lane];  // ht[r][lane]
    float acc = bv;
#pragma unroll
    for (int k = 0; k < 64; ++k) acc = fmaf(bcast(rv, k), w[k], acc);
    htP[(size_t)r * 64 + lane] = ((uint32)f2bu(acc) << 16) | (uint32)f2bu(rv);
  }
}

// ---------------- e = relu(hA[src]+hB[dst]+ea_s@We0c) -> bf16 (chunked contiguous) ----------------
__global__ void k_edgeinit(const unsigned short* __restrict__ hAb,
                           const unsigned short* __restrict__ hBb,
                           const float* __restrict__ ea_s, const float* __restrict__ Wc,
                           const int* __restrict__ srcs, const int* __restrict__ dsts,
                           __hip_bfloat16* __restrict__ ebf) {
  int tid = threadIdx.x;
  int lane = tid & 63;
  float w[FEDGE];
#pragma unroll
  for (int k = 0; k < FEDGE; ++k) w[k] = Wc[k * 64 + lane];
  int wave = (blockIdx.x * blockDim.x + tid) >> 6;
  int nwaves = (gridDim.x * blockDim.x) >> 6;
  const int npairs = N_EDGESC / 2;
  int per = (npairs + nwaves - 1) / nwaves;
  int p0 = wave * per;
  int p1 = min(p0 + per, npairs);
  for (int pr = p0; pr < p1; ++pr) {
    int e = 2 * pr;
    int s0 = srcs[e], d0 = dsts[e];
    int s1 = srcs[e + 1], d1 = dsts[e + 1];
    float av0 = (lane < FEDGE) ? ea_s[(size_t)e * FEDGE + lane] : 0.f;
    float av1 = (lane < FEDGE) ? ea_s[(size_t)(e + 1) * FEDGE + lane] : 0.f;
    unsigned short a0 = hAb[s0 * 64 + lane];
    unsigned short b0 = hBb[d0 * 64 + lane];
    unsigned short a1 = hAb[s1 * 64 + lane];
    unsigned short b1 = hBb[d1 * 64 + lane];
    float acc0 = bu2f(a0) + bu2f(b0);
    float acc1 = bu2f(a1) + bu2f(b1);
#pragma unroll
    for (int k = 0; k < FEDGE; ++k) {
      acc0 = fmaf(bcast(av0, k), w[k], acc0);
      acc1 = fmaf(bcast(av1, k), w[k], acc1);
    }
    acc0 = fmaxf(acc0, 0.f);
    acc1 = fmaxf(acc1, 0.f);
    __builtin_nontemporal_store(f2bu(acc0),
        reinterpret_cast<unsigned short*>(ebf) + (size_t)e * 64 + lane);
    __builtin_nontemporal_store(f2bu(acc1),
        reinterpret_cast<unsigned short*>(ebf) + (size_t)(e + 1) * 64 + lane);
  }
}

// ---------------- edge-gated conv: chunked tiles, cross-tile run-accumulate ----------------
// htP[n][c] = {lo: bf16 ht, hi: bf16 htA}; htBb[n][c] = bf16 htB
__global__ void __launch_bounds__(256) k_conv_mfma(
    const __hip_bfloat16* __restrict__ ebf,
    const float* __restrict__ We2,
    const uint32* __restrict__ htP, const unsigned short* __restrict__ htBb,
    const float* __restrict__ normf,
    const int* __restrict__ srcs, const int* __restrict__ dsts,
    float* __restrict__ hacc) {
  const int lane = threadIdx.x & 63;
  const int m  = lane & 15;   // A-row / B-col within 16-tile
  const int kg = lane >> 4;   // k-group

  // B fragments: b[t][s] -> B[k = s*32 + kg*8 + j][c = t*16 + m]
  bf16x8 b[4][2];
#pragma unroll
  for (int t = 0; t < 4; ++t)
#pragma unroll
    for (int s = 0; s < 2; ++s)
#pragma unroll
      for (int j = 0; j < 8; ++j) {
        int k = s * 32 + kg * 8 + j;
        int c = t * 16 + m;
        b[t][s][j] = (__bf16)We2[k * 64 + c];
      }

  int wave = (blockIdx.x * blockDim.x + threadIdx.x) >> 6;
  int nwaves = (gridDim.x * blockDim.x) >> 6;
  const int ntiles = N_EDGESC / 16;
  int per = (ntiles + nwaves - 1) / nwaves;
  int t0 = wave * per;
  int t1 = min(t0 + per, ntiles);
  if (t0 >= t1) return;

  float run[4] = {0.f, 0.f, 0.f, 0.f};
  int dcur = dsts[t0 * 16 + kg * 4];

  for (int tile = t0; tile < t1; ++tile) {
    int base = tile * 16;
    // ---- phase 1: issue ALL loads ----
    const bf16x8* arow = reinterpret_cast<const bf16x8*>(ebf + (size_t)(base + m) * 64 + kg * 8);
    bf16x8 a0 = __builtin_nontemporal_load(arow);
    bf16x8 a1 = __builtin_nontemporal_load(arow + 4);
    int rbase = base + kg * 4;
    int4 sev = *reinterpret_cast<const int4*>(srcs + rbase);
    int4 dev = *reinterpret_cast<const int4*>(dsts + rbase);
    float4 nev = *reinterpret_cast<const float4*>(normf + rbase);
    int se[4] = {sev.x, sev.y, sev.z, sev.w};
    int de[4] = {dev.x, dev.y, dev.z, dev.w};
    float ne[4] = {nev.x, nev.y, nev.z, nev.w};
    uint32 pv[4][4];
    unsigned short hv[4][4];
#pragma unroll
    for (int j = 0; j < 4; ++j) {
#pragma unroll
      for (int t = 0; t < 4; ++t) {
        int c = t * 16 + m;
        pv[j][t] = htP[(size_t)se[j] * 64 + c];
        hv[j][t] = htBb[(size_t)de[j] * 64 + c];
      }
    }
    // ---- phase 2: MFMA ----
    f32x4 acc[4];
#pragma unroll
    for (int t = 0; t < 4; ++t) {
      f32x4 z = {0.f, 0.f, 0.f, 0.f};
      acc[t] = __builtin_amdgcn_mfma_f32_16x16x32_bf16(a0, b[t][0], z, 0, 0, 0);
      acc[t] = __builtin_amdgcn_mfma_f32_16x16x32_bf16(a1, b[t][1], acc[t], 0, 0, 0);
    }
    // ---- phase 3: pure VALU msg computation ----
    float msg[4][4];
#pragma unroll
    for (int j = 0; j < 4; ++j) {
#pragma unroll
      for (int t = 0; t < 4; ++t) {
        float gate = acc[t][j] + bu2f((unsigned short)(pv[j][t] >> 16)) + bu2f(hv[j][t]);
        float sig = 1.0f / (1.0f + __expf(-gate));
        msg[j][t] = ne[j] * bu2f((unsigned short)(pv[j][t] & 0xffffu)) * sig;
      }
    }
    // ---- phase 4: run-accumulate, flush on dst change (carried across tiles) ----
#pragma unroll
    for (int j = 0; j < 4; ++j) {
      if (de[j] != dcur) {
#pragma unroll
        for (int t = 0; t < 4; ++t) {
          atomicAdd(&hacc[dcur * 64 + t * 16 + m], run[t]);
          run[t] = 0.f;
        }
        dcur = de[j];
      }
#pragma unroll
      for (int t = 0; t < 4; ++t) run[t] += msg[j][t];
    }
  }
#pragma unroll
  for (int t = 0; t < 4; ++t)
    atomicAdd(&hacc[dcur * 64 + t * 16 + m], run[t]);
}

// ---------------- h = relu(in), column stats of result ----------------
__global__ void k_relu_stats(const float* __restrict__ in, float* __restrict__ h,
                             float* __restrict__ stats, int nrows) {
  int tid = threadIdx.x;
  float s = 0.f, s2 = 0.f;
  int total = nrows * 64;
  for (int i = blockIdx.x * 256 + tid; i < total; i += gridDim.x * 256) {
    float v = fmaxf(in[i], 0.f);
    h[i] = v;
    s += v; s2 += v * v;
  }
  __shared__ float ls[256], ls2[256];
  ls[tid] = s; ls2[tid] = s2;
  __syncthreads();
  for (int off = 128; off >= 64; off >>= 1) {
    if (tid < off) { ls[tid] += ls[tid + off]; ls2[tid] += ls2[tid + off]; }
    __syncthreads();
  }
  if (tid < 64) {
    atomicAdd(&stats[tid], ls[tid]);
    atomicAdd(&stats[64 + tid], ls2[tid]);
  }
}

// ---------------- global_add_pool (batch is sorted) ----------------
__global__ void k_pool(const float* __restrict__ h, const int* __restrict__ batch,
                       float* __restrict__ g) {
  int lane = threadIdx.x & 63;
  int wave = (blockIdx.x * blockDim.x + threadIdx.x) >> 6;
  int nwaves = (gridDim.x * blockDim.x) >> 6;
  int chunk = (N_NODESC + nwaves - 1) / nwaves;
  int r0 = wave * chunk;
  int r1 = min(r0 + chunk, N_NODESC);
  if (r0 >= r1) return;
  int cur = batch[r0];
  float acc = 0.f;
  for (int r = r0; r < r1; ++r) {
    int b = batch[r];
    if (b != cur) {
      atomicAdd(&g[cur * 64 + lane], acc);
      acc = 0.f;
      cur = b;
    }
    acc += h[r * 64 + lane];
  }
  atomicAdd(&g[cur * 64 + lane], acc);
}

// ---------------- classifier + log_softmax ----------------
__global__ void k_cls(const float* __restrict__ g2, const float* __restrict__ Wc,
                      const float* __restrict__ bc, float* __restrict__ out) {
  int r = blockIdx.x * blockDim.x + threadIdx.x;
  if (r >= N_GRAPHSC) return;
  float z[NCLS];
#pragma unroll
  for (int c = 0; c < NCLS; ++c) z[c] = bc[c];
  for (int k = 0; k < HDIM; ++k) {
    float v = g2[r * HDIM + k];
#pragma unroll
    for (int c = 0; c < NCLS; ++c) z[c] = fmaf(v, Wc[k * NCLS + c], z[c]);
  }
  float m = z[0];
#pragma unroll
  for (int c = 1; c < NCLS; ++c) m = fmaxf(m, z[c]);
  float ssum = 0.f;
#pragma unroll
  for (int c = 0; c < NCLS; ++c) ssum += __expf(z[c] - m);
  float l = __logf(ssum);
#pragma unroll
  for (int c = 0; c < NCLS; ++c) out[r * NCLS + c] = z[c] - m - l;
}

extern "C" void kernel_launch(void* const* d_in, const int* in_sizes, int n_in,
                              void* d_out, int out_size, void* d_ws, size_t ws_size,
                              hipStream_t stream) {
  const float* x         = (const float*)d_in[0];
  const float* edge_attr = (const float*)d_in[1];
  const int*   ei        = (const int*)d_in[2];
  const int*   batch     = (const int*)d_in[3];
  const float* bn_feat_w = (const float*)d_in[4];
  const float* bn_feat_b = (const float*)d_in[5];
  const float* Wn0       = (const float*)d_in[6];
  const float* bn0       = (const float*)d_in[7];
  const float* We0       = (const float*)d_in[8];
  const float* be0       = (const float*)d_in[9];
  const float* bns_w     = (const float*)d_in[10];
  const float* bns_b     = (const float*)d_in[11];
  const float* Wn        = (const float*)d_in[12];
  const float* Wnb       = (const float*)d_in[13];
  const float* We        = (const float*)d_in[14];
  const float* Web       = (const float*)d_in[15];
  const float* bn_fc_w   = (const float*)d_in[16];
  const float* bn_fc_b   = (const float*)d_in[17];
  const float* Wfc       = (const float*)d_in[18];
  const float* bfc       = (const float*)d_in[19];
  const float* bn_hid_w  = (const float*)d_in[20];
  const float* bn_hid_b  = (const float*)d_in[21];
  const float* Wcls      = (const float*)d_in[22];
  const float* bcls      = (const float*)d_in[23];
  float* out = (float*)d_out;
  const int* src = ei;
  const int* dst = ei + N_EDGESC;

  char* p = (char*)d_ws;
  auto carve = [&](size_t bytes) {
    char* q = p;
    p += (bytes + 255) & ~(size_t)255;
    return q;
  };
  __hip_bfloat16* ebf = (__hip_bfloat16*)carve((size_t)N_EDGESC * 64 * 2);
  float* h    = (float*)carve((size_t)N_NODESC * 64 * 4);
  float* ht   = (float*)carve((size_t)N_NODESC * 64 * 4);
  float* hacc = (float*)carve((size_t)N_NODESC * 64 * 4);
  uint32* htP = (uint32*)carve((size_t)N_NODESC * 64 * 4);       // {bf16 ht, bf16 htA}
  unsigned short* htBb = (unsigned short*)carve((size_t)N_NODESC * 64 * 2);
  unsigned short* hAb  = (unsigned short*)carve((size_t)N_NODESC * 64 * 2);
  unsigned short* hBb  = (unsigned short*)carve((size_t)N_NODESC * 64 * 2);
  float* dinv = (float*)carve((size_t)N_NODESC * 4);
  float* g    = (float*)carve((size_t)N_GRAPHSC * 64 * 4);
  float* g2   = (float*)carve((size_t)N_GRAPHSC * 64 * 4);
  float* stats= (float*)carve(2 * 64 * 4);
  float* Wf   = (float*)carve(64 * 64 * 4);
  float* bf   = (float*)carve(64 * 4);
  uint32* degi   = (uint32*)carve((size_t)50176 * 4);
  uint32* ptr    = (uint32*)carve((size_t)50176 * 4);
  uint32* cursor = (uint32*)carve((size_t)50176 * 4);
  uint32* bsum   = (uint32*)carve(256 * 4);
  int* srcs  = (int*)carve((size_t)N_EDGESC * 4);
  int* dsts  = (int*)carve((size_t)N_EDGESC * 4);
  float* ea_s  = (float*)carve((size_t)N_EDGESC * FEDGE * 4);
  float* normf = (float*)carve((size_t)N_EDGESC * 4);

  // ---- degree, dinv, dst-sorted edge permutation ----
  hipMemsetAsync(degi, 0, 50176 * 4, stream);
  k_deg<<<(N_EDGESC + 255) / 256, 256, 0, stream>>>(dst, degi);
  k_dinv<<<(N_NODESC + 255) / 256, 256, 0, stream>>>(degi, dinv);
  k_scan1<<<SCAN_G, SCAN_B, 0, stream>>>(degi, ptr, bsum);
  k_scan2<<<1, 256, 0, stream>>>(bsum);
  k_scan3<<<SCAN_G, SCAN_B, 0, stream>>>(ptr, bsum);
  hipMemsetAsync(cursor, 0, 50176 * 4, stream);
  k_scatter<<<(N_EDGESC + 255) / 256, 256, 0, stream>>>(src, dst, edge_attr, dinv, ptr, cursor,
                                                        srcs, dsts, ea_s, normf);

  // ---- h0 = BN(x)@Wn0 + bn0 (BN folded) ----
  hipMemsetAsync(stats, 0, 512, stream);
  k_colstats<FNODE><<<256, 256, 0, stream>>>(x, N_NODESC, stats);
  k_foldbn<FNODE, HDIM><<<1, 256, 0, stream>>>(stats, 1.f / N_NODESC, bn_feat_w, bn_feat_b, Wn0, bn0, Wf, bf);
  k_nodemm<FNODE, false, FNODE, 64><<<512, 256, 0, stream>>>(x, N_NODESC, Wf, bf, h);

  // ---- edge features (sorted order): hA/hB bf16 ----
  k_nodemm_b<HDIM, 64><<<512, 256, 0, stream>>>(h, N_NODESC, We0, be0, hAb);
  k_nodemm_b<HDIM, 64><<<512, 256, 0, stream>>>(h, N_NODESC, We0 + 64 * 64, nullptr, hBb);
  k_edgeinit<<<1024, 256, 0, stream>>>(hAb, hBb, ea_s, We0 + 128 * 64, srcs, dsts, ebf);

  // ---- h = relu(h0), stats(h) ----
  hipMemsetAsync(stats, 0, 512, stream);
  k_relu_stats<<<256, 256, 0, stream>>>(h, h, stats, N_NODESC);

  for (int i = 0; i < 3; ++i) {
    const float* WeI = We + (size_t)i * 192 * 64;
    k_foldbn<HDIM, HDIM><<<1, 256, 0, stream>>>(stats, 1.f / N_NODESC, bns_w + i * 64, bns_b + i * 64,
                                                Wn + (size_t)i * 64 * 64, Wnb + i * 64, Wf, bf);
    k_nodemm<HDIM, false, 64, 64><<<512, 256, 0, stream>>>(h, N_NODESC, Wf, bf, ht);            // ht (fp32)
    k_nodemm_pack<<<512, 256, 0, stream>>>(ht, N_NODESC, WeI, Web + i * 64, htP);               // {ht,htA} bf16x2
    k_nodemm_b<HDIM, 64><<<512, 256, 0, stream>>>(ht, N_NODESC, WeI + 64 * 64, nullptr, htBb);  // htB bf16
    hipMemsetAsync(hacc, 0, (size_t)N_NODESC * 64 * 4, stream);
    k_conv_mfma<<<2048, 256, 0, stream>>>(ebf, WeI + 128 * 64, htP, htBb, normf, srcs, dsts, hacc);
    hipMemsetAsync(stats, 0, 512, stream);
    k_relu_stats<<<256, 256, 0, stream>>>(hacc, h, stats, N_NODESC);
  }

  // ---- pool + head ----
  hipMemsetAsync(g, 0, N_GRAPHSC * 64 * 4, stream);
  k_pool<<<64, 256, 0, stream>>>(h, batch, g);
  hipMemsetAsync(stats, 0, 512, stream);
  k_colstats<HDIM><<<32, 256, 0, stream>>>(g, N_GRAPHSC, stats);
  k_foldbn<HDIM, HDIM><<<1, 256, 0, stream>>>(stats, 1.f / N_GRAPHSC, bn_fc_w, bn_fc_b, Wfc, bfc, Wf, bf);
  k_nodemm<HDIM, true, 64, 64><<<128, 256, 0, stream>>>(g, N_GRAPHSC, Wf, bf, g2);
  hipMemsetAsync(stats, 0, 512, stream);
  k_colstats<HDIM><<<32, 256, 0, stream>>>(g2, N_GRAPHSC, stats);
  k_foldbn<HDIM, NCLS><<<1, 256, 0, stream>>>(stats, 1.f / N_GRAPHSC, bn_hid_w, bn_hid_b, Wcls, bcls, Wf, bf);
  k_cls<<<(N_GRAPHSC + 255) / 256, 256, 0, stream>>>(g2, Wf, bf, out);
}

// Round 8
// 982.834 us; speedup vs baseline: 1.3143x; 1.0417x over previous
//
#include <hip/hip_runtime.h>
#include <hip/hip_bf16.h>

#define N_NODESC 50000
#define N_EDGESC 800000
#define N_GRAPHSC 512
#define HDIM 64
#define FNODE 32
#define FEDGE 8
#define NCLS 10
#define BN_EPS 1e-5f
#define SCAN_B 256
#define SCAN_G 196  // 196*256 = 50176 >= 50000

typedef __bf16 bf16x8 __attribute__((ext_vector_type(8)));
typedef float f32x4 __attribute__((ext_vector_type(4)));
typedef unsigned int uint32;

static __device__ __forceinline__ float bcast(float v, int k) {
  return __uint_as_float(__builtin_amdgcn_readlane(__float_as_uint(v), k));
}
static __device__ __forceinline__ unsigned short f2bu(float f) {
  __hip_bfloat16 b = __float2bfloat16(f);
  return *reinterpret_cast<unsigned short*>(&b);
}
static __device__ __forceinline__ float bu2f(unsigned short u) {
  __hip_bfloat16 b;
  *reinterpret_cast<unsigned short*>(&b) = u;
  return __bfloat162float(b);
}

// ---------------- degree ----------------
__global__ void k_deg(const int* __restrict__ dst, uint32* __restrict__ degi) {
  int e = blockIdx.x * blockDim.x + threadIdx.x;
  if (e < N_EDGESC) atomicAdd(&degi[dst[e]], 1u);
}

__global__ void k_dinv(const uint32* __restrict__ degi, float* __restrict__ dinv) {
  int n = blockIdx.x * blockDim.x + threadIdx.x;
  if (n < N_NODESC) dinv[n] = rsqrtf(fmaxf((float)degi[n], 1.0f));
}

// ---------------- exclusive prefix sum over degi -> ptr ----------------
__global__ void k_scan1(const uint32* __restrict__ degi, uint32* __restrict__ ptr,
                        uint32* __restrict__ bsum) {
  __shared__ uint32 s[SCAN_B];
  int t = threadIdx.x;
  int i = blockIdx.x * SCAN_B + t;
  uint32 v = (i < N_NODESC) ? degi[i] : 0u;
  s[t] = v; __syncthreads();
  for (int off = 1; off < SCAN_B; off <<= 1) {
    uint32 x = (t >= off) ? s[t - off] : 0u; __syncthreads();
    s[t] += x; __syncthreads();
  }
  if (i < N_NODESC) ptr[i] = s[t] - v;  // exclusive local scan
  if (t == SCAN_B - 1) bsum[blockIdx.x] = s[t];
}

__global__ void k_scan2(uint32* __restrict__ bsum) {
  __shared__ uint32 s[256];
  int t = threadIdx.x;
  uint32 v = (t < SCAN_G) ? bsum[t] : 0u;
  s[t] = v; __syncthreads();
  for (int off = 1; off < 256; off <<= 1) {
    uint32 x = (t >= off) ? s[t - off] : 0u; __syncthreads();
    s[t] += x; __syncthreads();
  }
  if (t < SCAN_G) bsum[t] = s[t] - v;  // exclusive
}

__global__ void k_scan3(uint32* __restrict__ ptr, const uint32* __restrict__ bsum) {
  int i = blockIdx.x * SCAN_B + threadIdx.x;
  if (i < N_NODESC) ptr[i] += bsum[blockIdx.x];
}

// ---------------- scatter edges into dst-sorted order (+ea permute, +normf) ----------------
__global__ void k_scatter(const int* __restrict__ src, const int* __restrict__ dst,
                          const float* __restrict__ ea, const float* __restrict__ dinv,
                          const uint32* __restrict__ ptr, uint32* __restrict__ cursor,
                          int* __restrict__ srcs, int* __restrict__ dsts,
                          float* __restrict__ ea_s, float* __restrict__ normf) {
  int e = blockIdx.x * blockDim.x + threadIdx.x;
  if (e < N_EDGESC) {
    int d = dst[e];
    int s = src[e];
    float4 a0 = *reinterpret_cast<const float4*>(ea + (size_t)e * FEDGE);
    float4 a1 = *reinterpret_cast<const float4*>(ea + (size_t)e * FEDGE + 4);
    uint32 r = atomicAdd(&cursor[d], 1u);
    uint32 i = ptr[d] + r;
    srcs[i] = s;
    dsts[i] = d;
    normf[i] = dinv[s] * dinv[d];
    *reinterpret_cast<float4*>(ea_s + (size_t)i * FEDGE) = a0;
    *reinterpret_cast<float4*>(ea_s + (size_t)i * FEDGE + 4) = a1;
  }
}

// ---------------- column stats (sum, sumsq) ----------------
template <int C>
__global__ void k_colstats(const float* __restrict__ in, int nrows, float* __restrict__ stats) {
  const int RPB = 256 / C;
  int tid = threadIdx.x;
  int col = tid % C;
  int rowOff = tid / C;
  float s = 0.f, s2 = 0.f;
  for (int r = blockIdx.x * RPB + rowOff; r < nrows; r += gridDim.x * RPB) {
    float v = in[r * C + col];
    s += v; s2 += v * v;
  }
  __shared__ float ls[256], ls2[256];
  ls[tid] = s; ls2[tid] = s2;
  __syncthreads();
  for (int off = 128; off >= C; off >>= 1) {
    if (tid < off) { ls[tid] += ls[tid + off]; ls2[tid] += ls2[tid + off]; }
    __syncthreads();
  }
  if (tid < C) {
    atomicAdd(&stats[tid], ls[tid]);
    atomicAdd(&stats[C + tid], ls2[tid]);
  }
}

// ---------------- fold BN into weights ----------------
template <int CIN, int COUT>
__global__ void k_foldbn(const float* __restrict__ stats, float invN,
                         const float* __restrict__ bnw, const float* __restrict__ bnb,
                         const float* __restrict__ W, const float* __restrict__ bias,
                         float* __restrict__ Wf, float* __restrict__ bf) {
  __shared__ float a[CIN], sh[CIN];
  int tid = threadIdx.x;
  if (tid < CIN) {
    float m = stats[tid] * invN;
    float v = stats[CIN + tid] * invN - m * m;
    float inv = rsqrtf(v + BN_EPS);
    float aa = bnw[tid] * inv;
    a[tid] = aa;
    sh[tid] = bnb[tid] - m * aa;
  }
  __syncthreads();
  for (int i = tid; i < CIN * COUT; i += 256) {
    int r = i / COUT;
    Wf[i] = a[r] * W[i];
  }
  if (tid < COUT) {
    float acc = bias ? bias[tid] : 0.f;
    for (int r = 0; r < CIN; ++r) acc += sh[r] * W[r * COUT + tid];
    bf[tid] = acc;
  }
}

// ---------------- out[N,64] = in[N,K](ld LDIN) @ W[K,64] + bias (fp32 out) ----------------
template <int K, bool RELU, int LDIN, int LDOUT>
__global__ void k_nodemm(const float* __restrict__ in, int nrows,
                         const float* __restrict__ W, const float* __restrict__ bias,
                         float* __restrict__ out) {
  int tid = threadIdx.x;
  int lane = tid & 63;
  float w[K];
#pragma unroll
  for (int k = 0; k < K; ++k) w[k] = W[k * 64 + lane];
  float bv = bias ? bias[lane] : 0.f;
  int wave = (blockIdx.x * blockDim.x + tid) >> 6;
  int nwaves = (gridDim.x * blockDim.x) >> 6;
  for (int r = wave; r < nrows; r += nwaves) {
    float rv = (lane < K) ? in[(size_t)r * LDIN + lane] : 0.f;
    float acc = bv;
#pragma unroll
    for (int k = 0; k < K; ++k) acc = fmaf(bcast(rv, k), w[k], acc);
    if (RELU) acc = fmaxf(acc, 0.f);
    out[(size_t)r * LDOUT + lane] = acc;
  }
}

// ---------------- bf16-out nodemm: out[N,64] bf16 (standard layout) ----------------
template <int K, int LDIN>
__global__ void k_nodemm_b(const float* __restrict__ in, int nrows,
                           const float* __restrict__ W, const float* __restrict__ bias,
                           unsigned short* __restrict__ out) {
  int tid = threadIdx.x;
  int lane = tid & 63;
  float w[K];
#pragma unroll
  for (int k = 0; k < K; ++k) w[k] = W[k * 64 + lane];
  float bv = bias ? bias[lane] : 0.f;
  int wave = (blockIdx.x * blockDim.x + tid) >> 6;
  int nwaves = (gridDim.x * blockDim.x) >> 6;
  for (int r = wave; r < nrows; r += nwaves) {
    float rv = (lane < K) ? in[(size_t)r * LDIN + lane] : 0.f;
    float acc = bv;
#pragma unroll
    for (int k = 0; k < K; ++k) acc = fmaf(bcast(rv, k), w[k], acc);
    out[(size_t)r * 64 + lane] = f2bu(acc);
  }
}

// ---------------- fused per-conv node prep: ht, htA, htB in one pass ----------------
// htP/htBb stored COLUMN-PERMUTED: storage index c' = (c&15)*4 + (c>>4)
// so conv's per-lane 4 columns {t*16+m} are contiguous dwords [m*4, m*4+4).
__global__ void __launch_bounds__(256, 2) k_node3(
    const float* __restrict__ h, int nrows,
    const float* __restrict__ Wf, const float* __restrict__ bfv,
    const float* __restrict__ WA, const float* __restrict__ Wab,
    const float* __restrict__ WB,
    uint32* __restrict__ htP, unsigned short* __restrict__ htBb) {
  int tid = threadIdx.x;
  int lane = tid & 63;
  float w1[64], w2[64], w3[64];
#pragma unroll
  for (int k = 0; k < 64; ++k) w1[k] = Wf[k * 64 + lane];
#pragma unroll
  for (int k = 0; k < 64; ++k) w2[k] = WA[k * 64 + lane];
#pragma unroll
  for (int k = 0; k < 64; ++k) w3[k] = WB[k * 64 + lane];
  float b1 = bfv[lane];
  float b2 = Wab[lane];
  int cperm = (lane & 15) * 4 + (lane >> 4);
  int wave = (blockIdx.x * blockDim.x + tid) >> 6;
  int nwaves = (gridDim.x * blockDim.x) >> 6;
  for (int r = wave; r < nrows; r += nwaves) {
    float hv = h[(size_t)r * 64 + lane];
    float t1 = b1;
#pragma unroll
    for (int k = 0; k < 64; ++k) t1 = fmaf(bcast(hv, k), w1[k], t1);  // ht
    float t2 = b2;
    float t3 = 0.f;
#pragma unroll
    for (int k = 0; k < 64; ++k) {
      float tb = bcast(t1, k);
      t2 = fmaf(tb, w2[k], t2);  // htA
      t3 = fmaf(tb, w3[k], t3);  // htB
    }
    htP[(size_t)r * 64 + cperm] = ((uint32)f2bu(t2) << 16) | (uint32)f2bu(t1);
    htBb[(size_t)r * 64 + cperm] = f2bu(t3);
  }
}

// ---------------- e = relu(hA[src]+hB[dst]+ea_s@We0c) -> bf16 (chunked contiguous) ----------------
__global__ void k_edgeinit(const unsigned short* __restrict__ hAb,
                           const unsigned short* __restrict__ hBb,
                           const float* __restrict__ ea_s, const float* __restrict__ Wc,
                           const int* __restrict__ srcs, const int* __restrict__ dsts,
                           __hip_bfloat16* __restrict__ ebf) {
  int tid = threadIdx.x;
  int lane = tid & 63;
  float w[FEDGE];
#pragma unroll
  for (int k = 0; k < FEDGE; ++k) w[k] = Wc[k * 64 + lane];
  int wave = (blockIdx.x * blockDim.x + tid) >> 6;
  int nwaves = (gridDim.x * blockDim.x) >> 6;
  const int npairs = N_EDGESC / 2;
  int per = (npairs + nwaves - 1) / nwaves;
  int p0 = wave * per;
  int p1 = min(p0 + per, npairs);
  for (int pr = p0; pr < p1; ++pr) {
    int e = 2 * pr;
    int s0 = srcs[e], d0 = dsts[e];
    int s1 = srcs[e + 1], d1 = dsts[e + 1];
    float av0 = (lane < FEDGE) ? ea_s[(size_t)e * FEDGE + lane] : 0.f;
    float av1 = (lane < FEDGE) ? ea_s[(size_t)(e + 1) * FEDGE + lane] : 0.f;
    unsigned short a0 = hAb[s0 * 64 + lane];
    unsigned short b0 = hBb[d0 * 64 + lane];
    unsigned short a1 = hAb[s1 * 64 + lane];
    unsigned short b1 = hBb[d1 * 64 + lane];
    float acc0 = bu2f(a0) + bu2f(b0);
    float acc1 = bu2f(a1) + bu2f(b1);
#pragma unroll
    for (int k = 0; k < FEDGE; ++k) {
      acc0 = fmaf(bcast(av0, k), w[k], acc0);
      acc1 = fmaf(bcast(av1, k), w[k], acc1);
    }
    acc0 = fmaxf(acc0, 0.f);
    acc1 = fmaxf(acc1, 0.f);
    __builtin_nontemporal_store(f2bu(acc0),
        reinterpret_cast<unsigned short*>(ebf) + (size_t)e * 64 + lane);
    __builtin_nontemporal_store(f2bu(acc1),
        reinterpret_cast<unsigned short*>(ebf) + (size_t)(e + 1) * 64 + lane);
  }
}

// ---------------- edge-gated conv: chunked tiles, vectorized permuted gathers ----------------
__global__ void __launch_bounds__(256) k_conv_mfma(
    const __hip_bfloat16* __restrict__ ebf,
    const float* __restrict__ We2,
    const uint32* __restrict__ htP, const unsigned short* __restrict__ htBb,
    const float* __restrict__ normf,
    const int* __restrict__ srcs, const int* __restrict__ dsts,
    float* __restrict__ hacc) {
  const int lane = threadIdx.x & 63;
  const int m  = lane & 15;   // A-row / B-col within 16-tile
  const int kg = lane >> 4;   // k-group

  // B fragments: b[t][s] -> B[k = s*32 + kg*8 + j][c = t*16 + m]
  bf16x8 b[4][2];
#pragma unroll
  for (int t = 0; t < 4; ++t)
#pragma unroll
    for (int s = 0; s < 2; ++s)
#pragma unroll
      for (int j = 0; j < 8; ++j) {
        int k = s * 32 + kg * 8 + j;
        int c = t * 16 + m;
        b[t][s][j] = (__bf16)We2[k * 64 + c];
      }

  int wave = (blockIdx.x * blockDim.x + threadIdx.x) >> 6;
  int nwaves = (gridDim.x * blockDim.x) >> 6;
  const int ntiles = N_EDGESC / 16;
  int per = (ntiles + nwaves - 1) / nwaves;
  int t0 = wave * per;
  int t1 = min(t0 + per, ntiles);
  if (t0 >= t1) return;

  float run[4] = {0.f, 0.f, 0.f, 0.f};
  int dcur = dsts[t0 * 16 + kg * 4];

  for (int tile = t0; tile < t1; ++tile) {
    int base = tile * 16;
    // ---- phase 1: issue ALL loads ----
    const bf16x8* arow = reinterpret_cast<const bf16x8*>(ebf + (size_t)(base + m) * 64 + kg * 8);
    bf16x8 a0 = __builtin_nontemporal_load(arow);
    bf16x8 a1 = __builtin_nontemporal_load(arow + 4);
    int rbase = base + kg * 4;
    int4 sev = *reinterpret_cast<const int4*>(srcs + rbase);
    int4 dev = *reinterpret_cast<const int4*>(dsts + rbase);
    float4 nev = *reinterpret_cast<const float4*>(normf + rbase);
    int se[4] = {sev.x, sev.y, sev.z, sev.w};
    int de[4] = {dev.x, dev.y, dev.z, dev.w};
    float ne[4] = {nev.x, nev.y, nev.z, nev.w};
    uint4 pv4[4];
    uint2 hv2[4];
#pragma unroll
    for (int j = 0; j < 4; ++j) {
      pv4[j] = *reinterpret_cast<const uint4*>(htP + (size_t)se[j] * 64 + m * 4);
      hv2[j] = *reinterpret_cast<const uint2*>(htBb + (size_t)de[j] * 64 + m * 4);
    }
    // ---- phase 2: MFMA ----
    f32x4 acc[4];
#pragma unroll
    for (int t = 0; t < 4; ++t) {
      f32x4 z = {0.f, 0.f, 0.f, 0.f};
      acc[t] = __builtin_amdgcn_mfma_f32_16x16x32_bf16(a0, b[t][0], z, 0, 0, 0);
      acc[t] = __builtin_amdgcn_mfma_f32_16x16x32_bf16(a1, b[t][1], acc[t], 0, 0, 0);
    }
    // ---- phase 3+4: msg + run-accumulate, flush on dst change (carried across tiles) ----
#pragma unroll
    for (int j = 0; j < 4; ++j) {
      if (de[j] != dcur) {
#pragma unroll
        for (int t = 0; t < 4; ++t) {
          atomicAdd(&hacc[dcur * 64 + t * 16 + m], run[t]);
          run[t] = 0.f;
        }
        dcur = de[j];
      }
      uint32 pd[4] = {pv4[j].x, pv4[j].y, pv4[j].z, pv4[j].w};
      uint32 hd[2] = {hv2[j].x, hv2[j].y};
#pragma unroll
      for (int t = 0; t < 4; ++t) {
        unsigned short hbu = (unsigned short)((hd[t >> 1] >> ((t & 1) * 16)) & 0xffffu);
        float gate = acc[t][j] + bu2f((unsigned short)(pd[t] >> 16)) + bu2f(hbu);
        float sig = 1.0f / (1.0f + __expf(-gate));
        run[t] = fmaf(ne[j] * bu2f((unsigned short)(pd[t] & 0xffffu)), sig, run[t]);
      }
    }
  }
#pragma unroll
  for (int t = 0; t < 4; ++t)
    atomicAdd(&hacc[dcur * 64 + t * 16 + m], run[t]);
}

// ---------------- h = relu(in), column stats of result ----------------
__global__ void k_relu_stats(const float* __restrict__ in, float* __restrict__ h,
                             float* __restrict__ stats, int nrows) {
  int tid = threadIdx.x;
  float s = 0.f, s2 = 0.f;
  int total = nrows * 64;
  for (int i = blockIdx.x * 256 + tid; i < total; i += gridDim.x * 256) {
    float v = fmaxf(in[i], 0.f);
    h[i] = v;
    s += v; s2 += v * v;
  }
  __shared__ float ls[256], ls2[256];
  ls[tid] = s; ls2[tid] = s2;
  __syncthreads();
  for (int off = 128; off >= 64; off >>= 1) {
    if (tid < off) { ls[tid] += ls[tid + off]; ls2[tid] += ls2[tid + off]; }
    __syncthreads();
  }
  if (tid < 64) {
    atomicAdd(&stats[tid], ls[tid]);
    atomicAdd(&stats[64 + tid], ls2[tid]);
  }
}

// ---------------- global_add_pool (batch is sorted) ----------------
__global__ void k_pool(const float* __restrict__ h, const int* __restrict__ batch,
                       float* __restrict__ g) {
  int lane = threadIdx.x & 63;
  int wave = (blockIdx.x * blockDim.x + threadIdx.x) >> 6;
  int nwaves = (gridDim.x * blockDim.x) >> 6;
  int chunk = (N_NODESC + nwaves - 1) / nwaves;
  int r0 = wave * chunk;
  int r1 = min(r0 + chunk, N_NODESC);
  if (r0 >= r1) return;
  int cur = batch[r0];
  float acc = 0.f;
  for (int r = r0; r < r1; ++r) {
    int b = batch[r];
    if (b != cur) {
      atomicAdd(&g[cur * 64 + lane], acc);
      acc = 0.f;
      cur = b;
    }
    acc += h[r * 64 + lane];
  }
  atomicAdd(&g[cur * 64 + lane], acc);
}

// ---------------- classifier + log_softmax ----------------
__global__ void k_cls(const float* __restrict__ g2, const float* __restrict__ Wc,
                      const float* __restrict__ bc, float* __restrict__ out) {
  int r = blockIdx.x * blockDim.x + threadIdx.x;
  if (r >= N_GRAPHSC) return;
  float z[NCLS];
#pragma unroll
  for (int c = 0; c < NCLS; ++c) z[c] = bc[c];
  for (int k = 0; k < HDIM; ++k) {
    float v = g2[r * HDIM + k];
#pragma unroll
    for (int c = 0; c < NCLS; ++c) z[c] = fmaf(v, Wc[k * NCLS + c], z[c]);
  }
  float m = z[0];
#pragma unroll
  for (int c = 1; c < NCLS; ++c) m = fmaxf(m, z[c]);
  float ssum = 0.f;
#pragma unroll
  for (int c = 0; c < NCLS; ++c) ssum += __expf(z[c] - m);
  float l = __logf(ssum);
#pragma unroll
  for (int c = 0; c < NCLS; ++c) out[r * NCLS + c] = z[c] - m - l;
}

extern "C" void kernel_launch(void* const* d_in, const int* in_sizes, int n_in,
                              void* d_out, int out_size, void* d_ws, size_t ws_size,
                              hipStream_t stream) {
  const float* x         = (const float*)d_in[0];
  const float* edge_attr = (const float*)d_in[1];
  const int*   ei        = (const int*)d_in[2];
  const int*   batch     = (const int*)d_in[3];
  const float* bn_feat_w = (const float*)d_in[4];
  const float* bn_feat_b = (const float*)d_in[5];
  const float* Wn0       = (const float*)d_in[6];
  const float* bn0       = (const float*)d_in[7];
  const float* We0       = (const float*)d_in[8];
  const float* be0       = (const float*)d_in[9];
  const float* bns_w     = (const float*)d_in[10];
  const float* bns_b     = (const float*)d_in[11];
  const float* Wn        = (const float*)d_in[12];
  const float* Wnb       = (const float*)d_in[13];
  const float* We        = (const float*)d_in[14];
  const float* Web       = (const float*)d_in[15];
  const float* bn_fc_w   = (const float*)d_in[16];
  const float* bn_fc_b   = (const float*)d_in[17];
  const float* Wfc       = (const float*)d_in[18];
  const float* bfc       = (const float*)d_in[19];
  const float* bn_hid_w  = (const float*)d_in[20];
  const float* bn_hid_b  = (const float*)d_in[21];
  const float* Wcls      = (const float*)d_in[22];
  const float* bcls      = (const float*)d_in[23];
  float* out = (float*)d_out;
  const int* src = ei;
  const int* dst = ei + N_EDGESC;

  char* p = (char*)d_ws;
  auto carve = [&](size_t bytes) {
    char* q = p;
    p += (bytes + 255) & ~(size_t)255;
    return q;
  };
  __hip_bfloat16* ebf = (__hip_bfloat16*)carve((size_t)N_EDGESC * 64 * 2);
  float* h    = (float*)carve((size_t)N_NODESC * 64 * 4);
  float* hacc = (float*)carve((size_t)N_NODESC * 64 * 4);
  uint32* htP = (uint32*)carve((size_t)N_NODESC * 64 * 4);       // {bf16 ht, bf16 htA}, col-permuted
  unsigned short* htBb = (unsigned short*)carve((size_t)N_NODESC * 64 * 2);  // col-permuted
  unsigned short* hAb  = (unsigned short*)carve((size_t)N_NODESC * 64 * 2);
  unsigned short* hBb  = (unsigned short*)carve((size_t)N_NODESC * 64 * 2);
  float* dinv = (float*)carve((size_t)N_NODESC * 4);
  float* g    = (float*)carve((size_t)N_GRAPHSC * 64 * 4);
  float* g2   = (float*)carve((size_t)N_GRAPHSC * 64 * 4);
  float* stats= (float*)carve(2 * 64 * 4);
  float* Wf   = (float*)carve(64 * 64 * 4);
  float* bf   = (float*)carve(64 * 4);
  uint32* degi   = (uint32*)carve((size_t)50176 * 4);
  uint32* ptr    = (uint32*)carve((size_t)50176 * 4);
  uint32* cursor = (uint32*)carve((size_t)50176 * 4);
  uint32* bsum   = (uint32*)carve(256 * 4);
  int* srcs  = (int*)carve((size_t)N_EDGESC * 4);
  int* dsts  = (int*)carve((size_t)N_EDGESC * 4);
  float* ea_s  = (float*)carve((size_t)N_EDGESC * FEDGE * 4);
  float* normf = (float*)carve((size_t)N_EDGESC * 4);

  // ---- degree, dinv, dst-sorted edge permutation ----
  hipMemsetAsync(degi, 0, 50176 * 4, stream);
  k_deg<<<(N_EDGESC + 255) / 256, 256, 0, stream>>>(dst, degi);
  k_dinv<<<(N_NODESC + 255) / 256, 256, 0, stream>>>(degi, dinv);
  k_scan1<<<SCAN_G, SCAN_B, 0, stream>>>(degi, ptr, bsum);
  k_scan2<<<1, 256, 0, stream>>>(bsum);
  k_scan3<<<SCAN_G, SCAN_B, 0, stream>>>(ptr, bsum);
  hipMemsetAsync(cursor, 0, 50176 * 4, stream);
  k_scatter<<<(N_EDGESC + 255) / 256, 256, 0, stream>>>(src, dst, edge_attr, dinv, ptr, cursor,
                                                        srcs, dsts, ea_s, normf);

  // ---- h0 = BN(x)@Wn0 + bn0 (BN folded) ----
  hipMemsetAsync(stats, 0, 512, stream);
  k_colstats<FNODE><<<256, 256, 0, stream>>>(x, N_NODESC, stats);
  k_foldbn<FNODE, HDIM><<<1, 256, 0, stream>>>(stats, 1.f / N_NODESC, bn_feat_w, bn_feat_b, Wn0, bn0, Wf, bf);
  k_nodemm<FNODE, false, FNODE, 64><<<512, 256, 0, stream>>>(x, N_NODESC, Wf, bf, h);

  // ---- edge features (sorted order): hA/hB bf16 ----
  k_nodemm_b<HDIM, 64><<<512, 256, 0, stream>>>(h, N_NODESC, We0, be0, hAb);
  k_nodemm_b<HDIM, 64><<<512, 256, 0, stream>>>(h, N_NODESC, We0 + 64 * 64, nullptr, hBb);
  k_edgeinit<<<1024, 256, 0, stream>>>(hAb, hBb, ea_s, We0 + 128 * 64, srcs, dsts, ebf);

  // ---- h = relu(h0), stats(h) ----
  hipMemsetAsync(stats, 0, 512, stream);
  k_relu_stats<<<256, 256, 0, stream>>>(h, h, stats, N_NODESC);

  for (int i = 0; i < 3; ++i) {
    const float* WeI = We + (size_t)i * 192 * 64;
    k_foldbn<HDIM, HDIM><<<1, 256, 0, stream>>>(stats, 1.f / N_NODESC, bns_w + i * 64, bns_b + i * 64,
                                                Wn + (size_t)i * 64 * 64, Wnb + i * 64, Wf, bf);
    k_node3<<<512, 256, 0, stream>>>(h, N_NODESC, Wf, bf, WeI, Web + i * 64, WeI + 64 * 64, htP, htBb);
    hipMemsetAsync(hacc, 0, (size_t)N_NODESC * 64 * 4, stream);
    k_conv_mfma<<<2048, 256, 0, stream>>>(ebf, WeI + 128 * 64, htP, htBb, normf, srcs, dsts, hacc);
    hipMemsetAsync(stats, 0, 512, stream);
    k_relu_stats<<<256, 256, 0, stream>>>(hacc, h, stats, N_NODESC);
  }

  // ---- pool + head ----
  hipMemsetAsync(g, 0, N_GRAPHSC * 64 * 4, stream);
  k_pool<<<64, 256, 0, stream>>>(h, batch, g);
  hipMemsetAsync(stats, 0, 512, stream);
  k_colstats<HDIM><<<32, 256, 0, stream>>>(g, N_GRAPHSC, stats);
  k_foldbn<HDIM, HDIM><<<1, 256, 0, stream>>>(stats, 1.f / N_GRAPHSC, bn_fc_w, bn_fc_b, Wfc, bfc, Wf, bf);
  k_nodemm<HDIM, true, 64, 64><<<128, 256, 0, stream>>>(g, N_GRAPHSC, Wf, bf, g2);
  hipMemsetAsync(stats, 0, 512, stream);
  k_colstats<HDIM><<<32, 256, 0, stream>>>(g2, N_GRAPHSC, stats);
  k_foldbn<HDIM, NCLS><<<1, 256, 0, stream>>>(stats, 1.f / N_GRAPHSC, bn_hid_w, bn_hid_b, Wcls, bcls, Wf, bf);
  k_cls<<<(N_GRAPHSC + 255) / 256, 256, 0, stream>>>(g2, Wf, bf, out);
}

// Round 9
// 973.372 us; speedup vs baseline: 1.3271x; 1.0097x over previous
//
#include <hip/hip_runtime.h>
#include <hip/hip_bf16.h>

#define N_NODESC 50000
#define N_EDGESC 800000
#define N_GRAPHSC 512
#define HDIM 64
#define FNODE 32
#define FEDGE 8
#define NCLS 10
#define BN_EPS 1e-5f
#define SCAN_B 256
#define SCAN_G 196  // 196*256 = 50176 >= 50000

typedef __bf16 bf16x8 __attribute__((ext_vector_type(8)));
typedef float f32x4 __attribute__((ext_vector_type(4)));
typedef unsigned int uint32;

static __device__ __forceinline__ float bcast(float v, int k) {
  return __uint_as_float(__builtin_amdgcn_readlane(__float_as_uint(v), k));
}
static __device__ __forceinline__ unsigned short f2bu(float f) {
  __hip_bfloat16 b = __float2bfloat16(f);
  return *reinterpret_cast<unsigned short*>(&b);
}
static __device__ __forceinline__ float bu2f(unsigned short u) {
  __hip_bfloat16 b;
  *reinterpret_cast<unsigned short*>(&b) = u;
  return __bfloat162float(b);
}

// ---------------- degree ----------------
__global__ void k_deg(const int* __restrict__ dst, uint32* __restrict__ degi) {
  int e = blockIdx.x * blockDim.x + threadIdx.x;
  if (e < N_EDGESC) atomicAdd(&degi[dst[e]], 1u);
}

__global__ void k_dinv(const uint32* __restrict__ degi, float* __restrict__ dinv) {
  int n = blockIdx.x * blockDim.x + threadIdx.x;
  if (n < N_NODESC) dinv[n] = rsqrtf(fmaxf((float)degi[n], 1.0f));
}

// ---------------- exclusive prefix sum over degi -> ptr ----------------
__global__ void k_scan1(const uint32* __restrict__ degi, uint32* __restrict__ ptr,
                        uint32* __restrict__ bsum) {
  __shared__ uint32 s[SCAN_B];
  int t = threadIdx.x;
  int i = blockIdx.x * SCAN_B + t;
  uint32 v = (i < N_NODESC) ? degi[i] : 0u;
  s[t] = v; __syncthreads();
  for (int off = 1; off < SCAN_B; off <<= 1) {
    uint32 x = (t >= off) ? s[t - off] : 0u; __syncthreads();
    s[t] += x; __syncthreads();
  }
  if (i < N_NODESC) ptr[i] = s[t] - v;  // exclusive local scan
  if (t == SCAN_B - 1) bsum[blockIdx.x] = s[t];
}

__global__ void k_scan2(uint32* __restrict__ bsum) {
  __shared__ uint32 s[256];
  int t = threadIdx.x;
  uint32 v = (t < SCAN_G) ? bsum[t] : 0u;
  s[t] = v; __syncthreads();
  for (int off = 1; off < 256; off <<= 1) {
    uint32 x = (t >= off) ? s[t - off] : 0u; __syncthreads();
    s[t] += x; __syncthreads();
  }
  if (t < SCAN_G) bsum[t] = s[t] - v;  // exclusive
}

__global__ void k_scan3(uint32* __restrict__ ptr, const uint32* __restrict__ bsum) {
  int i = blockIdx.x * SCAN_B + threadIdx.x;
  if (i < N_NODESC) ptr[i] += bsum[blockIdx.x];
}

// ---------------- scatter edges into dst-sorted order (+ea permute, +normf) ----------------
__global__ void k_scatter(const int* __restrict__ src, const int* __restrict__ dst,
                          const float* __restrict__ ea, const float* __restrict__ dinv,
                          const uint32* __restrict__ ptr, uint32* __restrict__ cursor,
                          int* __restrict__ srcs, int* __restrict__ dsts,
                          float* __restrict__ ea_s, float* __restrict__ normf) {
  int e = blockIdx.x * blockDim.x + threadIdx.x;
  if (e < N_EDGESC) {
    int d = dst[e];
    int s = src[e];
    float4 a0 = *reinterpret_cast<const float4*>(ea + (size_t)e * FEDGE);
    float4 a1 = *reinterpret_cast<const float4*>(ea + (size_t)e * FEDGE + 4);
    uint32 r = atomicAdd(&cursor[d], 1u);
    uint32 i = ptr[d] + r;
    srcs[i] = s;
    dsts[i] = d;
    normf[i] = dinv[s] * dinv[d];
    *reinterpret_cast<float4*>(ea_s + (size_t)i * FEDGE) = a0;
    *reinterpret_cast<float4*>(ea_s + (size_t)i * FEDGE + 4) = a1;
  }
}

// ---------------- column stats (sum, sumsq) ----------------
template <int C>
__global__ void k_colstats(const float* __restrict__ in, int nrows, float* __restrict__ stats) {
  const int RPB = 256 / C;
  int tid = threadIdx.x;
  int col = tid % C;
  int rowOff = tid / C;
  float s = 0.f, s2 = 0.f;
  for (int r = blockIdx.x * RPB + rowOff; r < nrows; r += gridDim.x * RPB) {
    float v = in[r * C + col];
    s += v; s2 += v * v;
  }
  __shared__ float ls[256], ls2[256];
  ls[tid] = s; ls2[tid] = s2;
  __syncthreads();
  for (int off = 128; off >= C; off >>= 1) {
    if (tid < off) { ls[tid] += ls[tid + off]; ls2[tid] += ls2[tid + off]; }
    __syncthreads();
  }
  if (tid < C) {
    atomicAdd(&stats[tid], ls[tid]);
    atomicAdd(&stats[C + tid], ls2[tid]);
  }
}

// ---------------- fold BN into weights ----------------
template <int CIN, int COUT>
__global__ void k_foldbn(const float* __restrict__ stats, float invN,
                         const float* __restrict__ bnw, const float* __restrict__ bnb,
                         const float* __restrict__ W, const float* __restrict__ bias,
                         float* __restrict__ Wf, float* __restrict__ bf) {
  __shared__ float a[CIN], sh[CIN];
  int tid = threadIdx.x;
  if (tid < CIN) {
    float m = stats[tid] * invN;
    float v = stats[CIN + tid] * invN - m * m;
    float inv = rsqrtf(v + BN_EPS);
    float aa = bnw[tid] * inv;
    a[tid] = aa;
    sh[tid] = bnb[tid] - m * aa;
  }
  __syncthreads();
  for (int i = tid; i < CIN * COUT; i += 256) {
    int r = i / COUT;
    Wf[i] = a[r] * W[i];
  }
  if (tid < COUT) {
    float acc = bias ? bias[tid] : 0.f;
    for (int r = 0; r < CIN; ++r) acc += sh[r] * W[r * COUT + tid];
    bf[tid] = acc;
  }
}

// ---------------- out[N,64] = in[N,K](ld LDIN) @ W[K,64] + bias (fp32 out) ----------------
template <int K, bool RELU, int LDIN, int LDOUT>
__global__ void k_nodemm(const float* __restrict__ in, int nrows,
                         const float* __restrict__ W, const float* __restrict__ bias,
                         float* __restrict__ out) {
  int tid = threadIdx.x;
  int lane = tid & 63;
  float w[K];
#pragma unroll
  for (int k = 0; k < K; ++k) w[k] = W[k * 64 + lane];
  float bv = bias ? bias[lane] : 0.f;
  int wave = (blockIdx.x * blockDim.x + tid) >> 6;
  int nwaves = (gridDim.x * blockDim.x) >> 6;
  for (int r = wave; r < nrows; r += nwaves) {
    float rv = (lane < K) ? in[(size_t)r * LDIN + lane] : 0.f;
    float acc = bv;
#pragma unroll
    for (int k = 0; k < K; ++k) acc = fmaf(bcast(rv, k), w[k], acc);
    if (RELU) acc = fmaxf(acc, 0.f);
    out[(size_t)r * LDOUT + lane] = acc;
  }
}

// ---------------- bf16-out nodemm: out[N,64] bf16 (standard layout) ----------------
template <int K, int LDIN>
__global__ void k_nodemm_b(const float* __restrict__ in, int nrows,
                           const float* __restrict__ W, const float* __restrict__ bias,
                           unsigned short* __restrict__ out) {
  int tid = threadIdx.x;
  int lane = tid & 63;
  float w[K];
#pragma unroll
  for (int k = 0; k < K; ++k) w[k] = W[k * 64 + lane];
  float bv = bias ? bias[lane] : 0.f;
  int wave = (blockIdx.x * blockDim.x + tid) >> 6;
  int nwaves = (gridDim.x * blockDim.x) >> 6;
  for (int r = wave; r < nrows; r += nwaves) {
    float rv = (lane < K) ? in[(size_t)r * LDIN + lane] : 0.f;
    float acc = bv;
#pragma unroll
    for (int k = 0; k < K; ++k) acc = fmaf(bcast(rv, k), w[k], acc);
    out[(size_t)r * 64 + lane] = f2bu(acc);
  }
}

// ---------------- fused per-conv node prep: ht, htA, htB in one pass ----------------
// htP/htBb stored COLUMN-PERMUTED: storage index c' = (c&15)*4 + (c>>4)
__global__ void __launch_bounds__(256, 2) k_node3(
    const float* __restrict__ h, int nrows,
    const float* __restrict__ Wf, const float* __restrict__ bfv,
    const float* __restrict__ WA, const float* __restrict__ Wab,
    const float* __restrict__ WB,
    uint32* __restrict__ htP, unsigned short* __restrict__ htBb) {
  int tid = threadIdx.x;
  int lane = tid & 63;
  float w1[64], w2[64], w3[64];
#pragma unroll
  for (int k = 0; k < 64; ++k) w1[k] = Wf[k * 64 + lane];
#pragma unroll
  for (int k = 0; k < 64; ++k) w2[k] = WA[k * 64 + lane];
#pragma unroll
  for (int k = 0; k < 64; ++k) w3[k] = WB[k * 64 + lane];
  float b1 = bfv[lane];
  float b2 = Wab[lane];
  int cperm = (lane & 15) * 4 + (lane >> 4);
  int wave = (blockIdx.x * blockDim.x + tid) >> 6;
  int nwaves = (gridDim.x * blockDim.x) >> 6;
  for (int r = wave; r < nrows; r += nwaves) {
    float hv = h[(size_t)r * 64 + lane];
    float t1 = b1;
#pragma unroll
    for (int k = 0; k < 64; ++k) t1 = fmaf(bcast(hv, k), w1[k], t1);  // ht
    float t2 = b2;
    float t3 = 0.f;
#pragma unroll
    for (int k = 0; k < 64; ++k) {
      float tb = bcast(t1, k);
      t2 = fmaf(tb, w2[k], t2);  // htA
      t3 = fmaf(tb, w3[k], t3);  // htB
    }
    htP[(size_t)r * 64 + cperm] = ((uint32)f2bu(t2) << 16) | (uint32)f2bu(t1);
    htBb[(size_t)r * 64 + cperm] = f2bu(t3);
  }
}

// ---------------- e = relu(hA[src]+hB[dst]+ea_s@We0c) -> bf16 (chunked contiguous) ----------------
__global__ void k_edgeinit(const unsigned short* __restrict__ hAb,
                           const unsigned short* __restrict__ hBb,
                           const float* __restrict__ ea_s, const float* __restrict__ Wc,
                           const int* __restrict__ srcs, const int* __restrict__ dsts,
                           __hip_bfloat16* __restrict__ ebf) {
  int tid = threadIdx.x;
  int lane = tid & 63;
  float w[FEDGE];
#pragma unroll
  for (int k = 0; k < FEDGE; ++k) w[k] = Wc[k * 64 + lane];
  int wave = (blockIdx.x * blockDim.x + tid) >> 6;
  int nwaves = (gridDim.x * blockDim.x) >> 6;
  const int npairs = N_EDGESC / 2;
  int per = (npairs + nwaves - 1) / nwaves;
  int p0 = wave * per;
  int p1 = min(p0 + per, npairs);
  for (int pr = p0; pr < p1; ++pr) {
    int e = 2 * pr;
    int s0 = srcs[e], d0 = dsts[e];
    int s1 = srcs[e + 1], d1 = dsts[e + 1];
    float av0 = (lane < FEDGE) ? ea_s[(size_t)e * FEDGE + lane] : 0.f;
    float av1 = (lane < FEDGE) ? ea_s[(size_t)(e + 1) * FEDGE + lane] : 0.f;
    unsigned short a0 = hAb[s0 * 64 + lane];
    unsigned short b0 = hBb[d0 * 64 + lane];
    unsigned short a1 = hAb[s1 * 64 + lane];
    unsigned short b1 = hBb[d1 * 64 + lane];
    float acc0 = bu2f(a0) + bu2f(b0);
    float acc1 = bu2f(a1) + bu2f(b1);
#pragma unroll
    for (int k = 0; k < FEDGE; ++k) {
      acc0 = fmaf(bcast(av0, k), w[k], acc0);
      acc1 = fmaf(bcast(av1, k), w[k], acc1);
    }
    acc0 = fmaxf(acc0, 0.f);
    acc1 = fmaxf(acc1, 0.f);
    __builtin_nontemporal_store(f2bu(acc0),
        reinterpret_cast<unsigned short*>(ebf) + (size_t)e * 64 + lane);
    __builtin_nontemporal_store(f2bu(acc1),
        reinterpret_cast<unsigned short*>(ebf) + (size_t)(e + 1) * 64 + lane);
  }
}

// ---------------- edge-gated conv: 2-deep software-pipelined tiles ----------------
struct TileIdx { int4 se; int4 de; float4 ne; };
struct TileG {
  bf16x8 a0, a1;
  uint4 pv[4];
  uint2 hv[4];
};

__global__ void __launch_bounds__(256, 1) k_conv_mfma(
    const __hip_bfloat16* __restrict__ ebf,
    const float* __restrict__ We2,
    const uint32* __restrict__ htP, const unsigned short* __restrict__ htBb,
    const float* __restrict__ normf,
    const int* __restrict__ srcs, const int* __restrict__ dsts,
    float* __restrict__ hacc) {
  const int lane = threadIdx.x & 63;
  const int m  = lane & 15;   // A-row / B-col within 16-tile
  const int kg = lane >> 4;   // k-group

  // B fragments: b[t][s] -> B[k = s*32 + kg*8 + j][c = t*16 + m]
  bf16x8 b[4][2];
#pragma unroll
  for (int t = 0; t < 4; ++t)
#pragma unroll
    for (int s = 0; s < 2; ++s)
#pragma unroll
      for (int j = 0; j < 8; ++j) {
        int k = s * 32 + kg * 8 + j;
        int c = t * 16 + m;
        b[t][s][j] = (__bf16)We2[k * 64 + c];
      }

  int wave = (blockIdx.x * blockDim.x + threadIdx.x) >> 6;
  int nwaves = (gridDim.x * blockDim.x) >> 6;
  const int ntiles = N_EDGESC / 16;
  int per = (ntiles + nwaves - 1) / nwaves;
  int t0 = wave * per;
  int t1 = min(t0 + per, ntiles);
  if (t0 >= t1) return;

  float run[4] = {0.f, 0.f, 0.f, 0.f};
  int dcur = -1;

  auto loadIdx = [&](int tile) {
    TileIdx ix;
    int rbase = tile * 16 + kg * 4;
    ix.se = *reinterpret_cast<const int4*>(srcs + rbase);
    ix.de = *reinterpret_cast<const int4*>(dsts + rbase);
    ix.ne = *reinterpret_cast<const float4*>(normf + rbase);
    return ix;
  };
  auto loadG = [&](int tile, const TileIdx& ix) {
    TileG gd;
    const bf16x8* arow = reinterpret_cast<const bf16x8*>(ebf + (size_t)(tile * 16 + m) * 64 + kg * 8);
    gd.a0 = __builtin_nontemporal_load(arow);
    gd.a1 = __builtin_nontemporal_load(arow + 4);
    int se[4] = {ix.se.x, ix.se.y, ix.se.z, ix.se.w};
    int de[4] = {ix.de.x, ix.de.y, ix.de.z, ix.de.w};
#pragma unroll
    for (int j = 0; j < 4; ++j) {
      gd.pv[j] = *reinterpret_cast<const uint4*>(htP + (size_t)se[j] * 64 + m * 4);
      gd.hv[j] = *reinterpret_cast<const uint2*>(htBb + (size_t)de[j] * 64 + m * 4);
    }
    return gd;
  };
  auto computeT = [&](const TileG& gd, const TileIdx& ix) {
    f32x4 acc[4];
#pragma unroll
    for (int t = 0; t < 4; ++t) {
      f32x4 z = {0.f, 0.f, 0.f, 0.f};
      acc[t] = __builtin_amdgcn_mfma_f32_16x16x32_bf16(gd.a0, b[t][0], z, 0, 0, 0);
      acc[t] = __builtin_amdgcn_mfma_f32_16x16x32_bf16(gd.a1, b[t][1], acc[t], 0, 0, 0);
    }
    int de[4] = {ix.de.x, ix.de.y, ix.de.z, ix.de.w};
    float ne[4] = {ix.ne.x, ix.ne.y, ix.ne.z, ix.ne.w};
#pragma unroll
    for (int j = 0; j < 4; ++j) {
      if (de[j] != dcur) {
#pragma unroll
        for (int t = 0; t < 4; ++t) {
          if (dcur >= 0) atomicAdd(&hacc[dcur * 64 + t * 16 + m], run[t]);
          run[t] = 0.f;
        }
        dcur = de[j];
      }
      uint32 pd[4] = {gd.pv[j].x, gd.pv[j].y, gd.pv[j].z, gd.pv[j].w};
      uint32 hd[2] = {gd.hv[j].x, gd.hv[j].y};
#pragma unroll
      for (int t = 0; t < 4; ++t) {
        unsigned short hbu = (unsigned short)((hd[t >> 1] >> ((t & 1) * 16)) & 0xffffu);
        float gate = acc[t][j] + bu2f((unsigned short)(pd[t] >> 16)) + bu2f(hbu);
        float sig = 1.0f / (1.0f + __expf(-gate));
        run[t] = fmaf(ne[j] * bu2f((unsigned short)(pd[t] & 0xffffu)), sig, run[t]);
      }
    }
  };

  // ---- software pipeline: idx 2 ahead, gathers 1 ahead ----
  TileIdx i0 = loadIdx(t0);
  TileIdx i1 = (t0 + 1 < t1) ? loadIdx(t0 + 1) : i0;
  TileG g0 = loadG(t0, i0);
  TileG g1;
  for (int tile = t0; tile < t1; tile += 2) {
    bool has1 = (tile + 1 < t1);
    if (has1) g1 = loadG(tile + 1, i1);
    TileIdx i2 = (tile + 2 < t1) ? loadIdx(tile + 2) : i0;
    computeT(g0, i0);
    if (!has1) break;
    TileIdx i3 = (tile + 3 < t1) ? loadIdx(tile + 3) : i1;
    if (tile + 2 < t1) g0 = loadG(tile + 2, i2);
    computeT(g1, i1);
    i0 = i2; i1 = i3;
  }
#pragma unroll
  for (int t = 0; t < 4; ++t)
    atomicAdd(&hacc[dcur * 64 + t * 16 + m], run[t]);
}

// ---------------- h = relu(in), column stats of result ----------------
__global__ void k_relu_stats(const float* __restrict__ in, float* __restrict__ h,
                             float* __restrict__ stats, int nrows) {
  int tid = threadIdx.x;
  float s = 0.f, s2 = 0.f;
  int total = nrows * 64;
  for (int i = blockIdx.x * 256 + tid; i < total; i += gridDim.x * 256) {
    float v = fmaxf(in[i], 0.f);
    h[i] = v;
    s += v; s2 += v * v;
  }
  __shared__ float ls[256], ls2[256];
  ls[tid] = s; ls2[tid] = s2;
  __syncthreads();
  for (int off = 128; off >= 64; off >>= 1) {
    if (tid < off) { ls[tid] += ls[tid + off]; ls2[tid] += ls2[tid + off]; }
    __syncthreads();
  }
  if (tid < 64) {
    atomicAdd(&stats[tid], ls[tid]);
    atomicAdd(&stats[64 + tid], ls2[tid]);
  }
}

// ---------------- global_add_pool (batch is sorted) ----------------
__global__ void k_pool(const float* __restrict__ h, const int* __restrict__ batch,
                       float* __restrict__ g) {
  int lane = threadIdx.x & 63;
  int wave = (blockIdx.x * blockDim.x + threadIdx.x) >> 6;
  int nwaves = (gridDim.x * blockDim.x) >> 6;
  int chunk = (N_NODESC + nwaves - 1) / nwaves;
  int r0 = wave * chunk;
  int r1 = min(r0 + chunk, N_NODESC);
  if (r0 >= r1) return;
  int cur = batch[r0];
  float acc = 0.f;
  for (int r = r0; r < r1; ++r) {
    int b = batch[r];
    if (b != cur) {
      atomicAdd(&g[cur * 64 + lane], acc);
      acc = 0.f;
      cur = b;
    }
    acc += h[r * 64 + lane];
  }
  atomicAdd(&g[cur * 64 + lane], acc);
}

// ---------------- classifier + log_softmax ----------------
__global__ void k_cls(const float* __restrict__ g2, const float* __restrict__ Wc,
                      const float* __restrict__ bc, float* __restrict__ out) {
  int r = blockIdx.x * blockDim.x + threadIdx.x;
  if (r >= N_GRAPHSC) return;
  float z[NCLS];
#pragma unroll
  for (int c = 0; c < NCLS; ++c) z[c] = bc[c];
  for (int k = 0; k < HDIM; ++k) {
    float v = g2[r * HDIM + k];
#pragma unroll
    for (int c = 0; c < NCLS; ++c) z[c] = fmaf(v, Wc[k * NCLS + c], z[c]);
  }
  float m = z[0];
#pragma unroll
  for (int c = 1; c < NCLS; ++c) m = fmaxf(m, z[c]);
  float ssum = 0.f;
#pragma unroll
  for (int c = 0; c < NCLS; ++c) ssum += __expf(z[c] - m);
  float l = __logf(ssum);
#pragma unroll
  for (int c = 0; c < NCLS; ++c) out[r * NCLS + c] = z[c] - m - l;
}

extern "C" void kernel_launch(void* const* d_in, const int* in_sizes, int n_in,
                              void* d_out, int out_size, void* d_ws, size_t ws_size,
                              hipStream_t stream) {
  const float* x         = (const float*)d_in[0];
  const float* edge_attr = (const float*)d_in[1];
  const int*   ei        = (const int*)d_in[2];
  const int*   batch     = (const int*)d_in[3];
  const float* bn_feat_w = (const float*)d_in[4];
  const float* bn_feat_b = (const float*)d_in[5];
  const float* Wn0       = (const float*)d_in[6];
  const float* bn0       = (const float*)d_in[7];
  const float* We0       = (const float*)d_in[8];
  const float* be0       = (const float*)d_in[9];
  const float* bns_w     = (const float*)d_in[10];
  const float* bns_b     = (const float*)d_in[11];
  const float* Wn        = (const float*)d_in[12];
  const float* Wnb       = (const float*)d_in[13];
  const float* We        = (const float*)d_in[14];
  const float* Web       = (const float*)d_in[15];
  const float* bn_fc_w   = (const float*)d_in[16];
  const float* bn_fc_b   = (const float*)d_in[17];
  const float* Wfc       = (const float*)d_in[18];
  const float* bfc       = (const float*)d_in[19];
  const float* bn_hid_w  = (const float*)d_in[20];
  const float* bn_hid_b  = (const float*)d_in[21];
  const float* Wcls      = (const float*)d_in[22];
  const float* bcls      = (const float*)d_in[23];
  float* out = (float*)d_out;
  const int* src = ei;
  const int* dst = ei + N_EDGESC;

  char* p = (char*)d_ws;
  auto carve = [&](size_t bytes) {
    char* q = p;
    p += (bytes + 255) & ~(size_t)255;
    return q;
  };
  __hip_bfloat16* ebf = (__hip_bfloat16*)carve((size_t)N_EDGESC * 64 * 2);
  float* h    = (float*)carve((size_t)N_NODESC * 64 * 4);
  float* hacc = (float*)carve((size_t)N_NODESC * 64 * 4);
  uint32* htP = (uint32*)carve((size_t)N_NODESC * 64 * 4);       // {bf16 ht, bf16 htA}, col-permuted
  unsigned short* htBb = (unsigned short*)carve((size_t)N_NODESC * 64 * 2);  // col-permuted
  unsigned short* hAb  = (unsigned short*)carve((size_t)N_NODESC * 64 * 2);
  unsigned short* hBb  = (unsigned short*)carve((size_t)N_NODESC * 64 * 2);
  float* dinv = (float*)carve((size_t)N_NODESC * 4);
  float* g    = (float*)carve((size_t)N_GRAPHSC * 64 * 4);
  float* g2   = (float*)carve((size_t)N_GRAPHSC * 64 * 4);
  float* stats= (float*)carve(2 * 64 * 4);
  float* Wf   = (float*)carve(64 * 64 * 4);
  float* bf   = (float*)carve(64 * 4);
  uint32* degi   = (uint32*)carve((size_t)50176 * 4);
  uint32* ptr    = (uint32*)carve((size_t)50176 * 4);
  uint32* cursor = (uint32*)carve((size_t)50176 * 4);
  uint32* bsum   = (uint32*)carve(256 * 4);
  int* srcs  = (int*)carve((size_t)N_EDGESC * 4);
  int* dsts  = (int*)carve((size_t)N_EDGESC * 4);
  float* ea_s  = (float*)carve((size_t)N_EDGESC * FEDGE * 4);
  float* normf = (float*)carve((size_t)N_EDGESC * 4);

  // ---- degree, dinv, dst-sorted edge permutation ----
  hipMemsetAsync(degi, 0, 50176 * 4, stream);
  k_deg<<<(N_EDGESC + 255) / 256, 256, 0, stream>>>(dst, degi);
  k_dinv<<<(N_NODESC + 255) / 256, 256, 0, stream>>>(degi, dinv);
  k_scan1<<<SCAN_G, SCAN_B, 0, stream>>>(degi, ptr, bsum);
  k_scan2<<<1, 256, 0, stream>>>(bsum);
  k_scan3<<<SCAN_G, SCAN_B, 0, stream>>>(ptr, bsum);
  hipMemsetAsync(cursor, 0, 50176 * 4, stream);
  k_scatter<<<(N_EDGESC + 255) / 256, 256, 0, stream>>>(src, dst, edge_attr, dinv, ptr, cursor,
                                                        srcs, dsts, ea_s, normf);

  // ---- h0 = BN(x)@Wn0 + bn0 (BN folded) ----
  hipMemsetAsync(stats, 0, 512, stream);
  k_colstats<FNODE><<<256, 256, 0, stream>>>(x, N_NODESC, stats);
  k_foldbn<FNODE, HDIM><<<1, 256, 0, stream>>>(stats, 1.f / N_NODESC, bn_feat_w, bn_feat_b, Wn0, bn0, Wf, bf);
  k_nodemm<FNODE, false, FNODE, 64><<<512, 256, 0, stream>>>(x, N_NODESC, Wf, bf, h);

  // ---- edge features (sorted order): hA/hB bf16 ----
  k_nodemm_b<HDIM, 64><<<512, 256, 0, stream>>>(h, N_NODESC, We0, be0, hAb);
  k_nodemm_b<HDIM, 64><<<512, 256, 0, stream>>>(h, N_NODESC, We0 + 64 * 64, nullptr, hBb);
  k_edgeinit<<<1024, 256, 0, stream>>>(hAb, hBb, ea_s, We0 + 128 * 64, srcs, dsts, ebf);

  // ---- h = relu(h0), stats(h) ----
  hipMemsetAsync(stats, 0, 512, stream);
  k_relu_stats<<<256, 256, 0, stream>>>(h, h, stats, N_NODESC);

  for (int i = 0; i < 3; ++i) {
    const float* WeI = We + (size_t)i * 192 * 64;
    k_foldbn<HDIM, HDIM><<<1, 256, 0, stream>>>(stats, 1.f / N_NODESC, bns_w + i * 64, bns_b + i * 64,
                                                Wn + (size_t)i * 64 * 64, Wnb + i * 64, Wf, bf);
    k_node3<<<512, 256, 0, stream>>>(h, N_NODESC, Wf, bf, WeI, Web + i * 64, WeI + 64 * 64, htP, htBb);
    hipMemsetAsync(hacc, 0, (size_t)N_NODESC * 64 * 4, stream);
    k_conv_mfma<<<1024, 256, 0, stream>>>(ebf, WeI + 128 * 64, htP, htBb, normf, srcs, dsts, hacc);
    hipMemsetAsync(stats, 0, 512, stream);
    k_relu_stats<<<256, 256, 0, stream>>>(hacc, h, stats, N_NODESC);
  }

  // ---- pool + head ----
  hipMemsetAsync(g, 0, N_GRAPHSC * 64 * 4, stream);
  k_pool<<<64, 256, 0, stream>>>(h, batch, g);
  hipMemsetAsync(stats, 0, 512, stream);
  k_colstats<HDIM><<<32, 256, 0, stream>>>(g, N_GRAPHSC, stats);
  k_foldbn<HDIM, HDIM><<<1, 256, 0, stream>>>(stats, 1.f / N_GRAPHSC, bn_fc_w, bn_fc_b, Wfc, bfc, Wf, bf);
  k_nodemm<HDIM, true, 64, 64><<<128, 256, 0, stream>>>(g, N_GRAPHSC, Wf, bf, g2);
  hipMemsetAsync(stats, 0, 512, stream);
  k_colstats<HDIM><<<32, 256, 0, stream>>>(g2, N_GRAPHSC, stats);
  k_foldbn<HDIM, NCLS><<<1, 256, 0, stream>>>(stats, 1.f / N_GRAPHSC, bn_hid_w, bn_hid_b, Wcls, bcls, Wf, bf);
  k_cls<<<(N_GRAPHSC + 255) / 256, 256, 0, stream>>>(g2, Wf, bf, out);
}

// Round 10
// 873.152 us; speedup vs baseline: 1.4794x; 1.1148x over previous
//
#include <hip/hip_runtime.h>
#include <hip/hip_bf16.h>

#define N_NODESC 50000
#define N_EDGESC 800000
#define N_GRAPHSC 512
#define HDIM 64
#define FNODE 32
#define FEDGE 8
#define NCLS 10
#define BN_EPS 1e-5f
#define SCAN_B 256
#define SCAN_G 196  // 196*256 = 50176 >= 50000
#define NPW 8       // nodes per wave in conv

typedef __bf16 bf16x8 __attribute__((ext_vector_type(8)));
typedef float f32x4 __attribute__((ext_vector_type(4)));
typedef unsigned int uint32;

static __device__ __forceinline__ float bcast(float v, int k) {
  return __uint_as_float(__builtin_amdgcn_readlane(__float_as_uint(v), k));
}
static __device__ __forceinline__ unsigned short f2bu(float f) {
  __hip_bfloat16 b = __float2bfloat16(f);
  return *reinterpret_cast<unsigned short*>(&b);
}
static __device__ __forceinline__ float bu2f(unsigned short u) {
  __hip_bfloat16 b;
  *reinterpret_cast<unsigned short*>(&b) = u;
  return __bfloat162float(b);
}

// ---------------- degree ----------------
__global__ void k_deg(const int* __restrict__ dst, uint32* __restrict__ degi) {
  int e = blockIdx.x * blockDim.x + threadIdx.x;
  if (e < N_EDGESC) atomicAdd(&degi[dst[e]], 1u);
}

__global__ void k_dinv(const uint32* __restrict__ degi, float* __restrict__ dinv) {
  int n = blockIdx.x * blockDim.x + threadIdx.x;
  if (n < N_NODESC) dinv[n] = rsqrtf(fmaxf((float)degi[n], 1.0f));
}

// ---------------- exclusive prefix sum over degi -> ptr ----------------
__global__ void k_scan1(const uint32* __restrict__ degi, uint32* __restrict__ ptr,
                        uint32* __restrict__ bsum) {
  __shared__ uint32 s[SCAN_B];
  int t = threadIdx.x;
  int i = blockIdx.x * SCAN_B + t;
  uint32 v = (i < N_NODESC) ? degi[i] : 0u;
  s[t] = v; __syncthreads();
  for (int off = 1; off < SCAN_B; off <<= 1) {
    uint32 x = (t >= off) ? s[t - off] : 0u; __syncthreads();
    s[t] += x; __syncthreads();
  }
  if (i < N_NODESC) ptr[i] = s[t] - v;  // exclusive local scan
  if (t == SCAN_B - 1) bsum[blockIdx.x] = s[t];
}

__global__ void k_scan2(uint32* __restrict__ bsum) {
  __shared__ uint32 s[256];
  int t = threadIdx.x;
  uint32 v = (t < SCAN_G) ? bsum[t] : 0u;
  s[t] = v; __syncthreads();
  for (int off = 1; off < 256; off <<= 1) {
    uint32 x = (t >= off) ? s[t - off] : 0u; __syncthreads();
    s[t] += x; __syncthreads();
  }
  if (t < SCAN_G) bsum[t] = s[t] - v;  // exclusive
}

__global__ void k_scan3(uint32* __restrict__ ptr, const uint32* __restrict__ bsum) {
  int i = blockIdx.x * SCAN_B + threadIdx.x;
  if (i < N_NODESC) ptr[i] += bsum[blockIdx.x];
  if (blockIdx.x == 0 && threadIdx.x == 0) ptr[N_NODESC] = N_EDGESC;  // CSR sentinel
}

// ---------------- scatter edges into dst-sorted order (+ea permute, +normf) ----------------
__global__ void k_scatter(const int* __restrict__ src, const int* __restrict__ dst,
                          const float* __restrict__ ea, const float* __restrict__ dinv,
                          const uint32* __restrict__ ptr, uint32* __restrict__ cursor,
                          int* __restrict__ srcs, int* __restrict__ dsts,
                          float* __restrict__ ea_s, float* __restrict__ normf) {
  int e = blockIdx.x * blockDim.x + threadIdx.x;
  if (e < N_EDGESC) {
    int d = dst[e];
    int s = src[e];
    float4 a0 = *reinterpret_cast<const float4*>(ea + (size_t)e * FEDGE);
    float4 a1 = *reinterpret_cast<const float4*>(ea + (size_t)e * FEDGE + 4);
    uint32 r = atomicAdd(&cursor[d], 1u);
    uint32 i = ptr[d] + r;
    srcs[i] = s;
    dsts[i] = d;
    normf[i] = dinv[s] * dinv[d];
    *reinterpret_cast<float4*>(ea_s + (size_t)i * FEDGE) = a0;
    *reinterpret_cast<float4*>(ea_s + (size_t)i * FEDGE + 4) = a1;
  }
}

// ---------------- column stats (sum, sumsq) ----------------
template <int C>
__global__ void k_colstats(const float* __restrict__ in, int nrows, float* __restrict__ stats) {
  const int RPB = 256 / C;
  int tid = threadIdx.x;
  int col = tid % C;
  int rowOff = tid / C;
  float s = 0.f, s2 = 0.f;
  for (int r = blockIdx.x * RPB + rowOff; r < nrows; r += gridDim.x * RPB) {
    float v = in[r * C + col];
    s += v; s2 += v * v;
  }
  __shared__ float ls[256], ls2[256];
  ls[tid] = s; ls2[tid] = s2;
  __syncthreads();
  for (int off = 128; off >= C; off >>= 1) {
    if (tid < off) { ls[tid] += ls[tid + off]; ls2[tid] += ls2[tid + off]; }
    __syncthreads();
  }
  if (tid < C) {
    atomicAdd(&stats[tid], ls[tid]);
    atomicAdd(&stats[C + tid], ls2[tid]);
  }
}

// ---------------- fold BN into weights (stage0 & head) ----------------
template <int CIN, int COUT>
__global__ void k_foldbn(const float* __restrict__ stats, float invN,
                         const float* __restrict__ bnw, const float* __restrict__ bnb,
                         const float* __restrict__ W, const float* __restrict__ bias,
                         float* __restrict__ Wf, float* __restrict__ bf) {
  __shared__ float a[CIN], sh[CIN];
  int tid = threadIdx.x;
  if (tid < CIN) {
    float m = stats[tid] * invN;
    float v = stats[CIN + tid] * invN - m * m;
    float inv = rsqrtf(v + BN_EPS);
    float aa = bnw[tid] * inv;
    a[tid] = aa;
    sh[tid] = bnb[tid] - m * aa;
  }
  __syncthreads();
  for (int i = tid; i < CIN * COUT; i += 256) {
    int r = i / COUT;
    Wf[i] = a[r] * W[i];
  }
  if (tid < COUT) {
    float acc = bias ? bias[tid] : 0.f;
    for (int r = 0; r < CIN; ++r) acc += sh[r] * W[r * COUT + tid];
    bf[tid] = acc;
  }
}

// ---------------- out[N,64] = in[N,K] @ W[K,64] + bias (fp32 out) ----------------
template <int K, bool RELU, int LDIN, int LDOUT>
__global__ void k_nodemm(const float* __restrict__ in, int nrows,
                         const float* __restrict__ W, const float* __restrict__ bias,
                         float* __restrict__ out) {
  int tid = threadIdx.x;
  int lane = tid & 63;
  float w[K];
#pragma unroll
  for (int k = 0; k < K; ++k) w[k] = W[k * 64 + lane];
  float bv = bias ? bias[lane] : 0.f;
  int wave = (blockIdx.x * blockDim.x + tid) >> 6;
  int nwaves = (gridDim.x * blockDim.x) >> 6;
  for (int r = wave; r < nrows; r += nwaves) {
    float rv = (lane < K) ? in[(size_t)r * LDIN + lane] : 0.f;
    float acc = bv;
#pragma unroll
    for (int k = 0; k < K; ++k) acc = fmaf(bcast(rv, k), w[k], acc);
    if (RELU) acc = fmaxf(acc, 0.f);
    out[(size_t)r * LDOUT + lane] = acc;
  }
}

// ---------------- fused hA + hB (bf16 out) ----------------
__global__ void k_nodemm_b2(const float* __restrict__ h, int nrows,
                            const float* __restrict__ WA, const float* __restrict__ bA,
                            const float* __restrict__ WB,
                            unsigned short* __restrict__ hAb,
                            unsigned short* __restrict__ hBb) {
  int tid = threadIdx.x;
  int lane = tid & 63;
  float wA[64], wB[64];
#pragma unroll
  for (int k = 0; k < 64; ++k) wA[k] = WA[k * 64 + lane];
#pragma unroll
  for (int k = 0; k < 64; ++k) wB[k] = WB[k * 64 + lane];
  float bv = bA[lane];
  int wave = (blockIdx.x * blockDim.x + tid) >> 6;
  int nwaves = (gridDim.x * blockDim.x) >> 6;
  for (int r = wave; r < nrows; r += nwaves) {
    float rv = h[(size_t)r * 64 + lane];
    float aA = bv, aB = 0.f;
#pragma unroll
    for (int k = 0; k < 64; ++k) {
      float tb = bcast(rv, k);
      aA = fmaf(tb, wA[k], aA);
      aB = fmaf(tb, wB[k], aB);
    }
    hAb[(size_t)r * 64 + lane] = f2bu(aA);
    hBb[(size_t)r * 64 + lane] = f2bu(aB);
  }
}

// ---------------- fused per-conv node prep (inline BN fold): ht, htA, htB ----------------
// htP col-PERMUTED (c' = (c&15)*4 + (c>>4)); htBb LINEAR.
__global__ void __launch_bounds__(256, 2) k_node3(
    const float* __restrict__ h, int nrows,
    const float* __restrict__ stats, float invN,
    const float* __restrict__ bnw, const float* __restrict__ bnb,
    const float* __restrict__ Wn_i, const float* __restrict__ Wnb_i,
    const float* __restrict__ WA, const float* __restrict__ Wab,
    const float* __restrict__ WB,
    uint32* __restrict__ htP, unsigned short* __restrict__ htBb) {
  __shared__ float a_s[64], sh_s[64];
  int tid = threadIdx.x;
  int lane = tid & 63;
  if (tid < 64) {
    float m = stats[tid] * invN;
    float v = stats[64 + tid] * invN - m * m;
    float inv = rsqrtf(v + BN_EPS);
    float aa = bnw[tid] * inv;
    a_s[tid] = aa;
    sh_s[tid] = bnb[tid] - m * aa;
  }
  __syncthreads();
  float w1[64], w2[64], w3[64];
  float b1 = Wnb_i[lane];
#pragma unroll
  for (int k = 0; k < 64; ++k) {
    float raw = Wn_i[k * 64 + lane];
    w1[k] = a_s[k] * raw;
    b1 = fmaf(sh_s[k], raw, b1);
  }
#pragma unroll
  for (int k = 0; k < 64; ++k) w2[k] = WA[k * 64 + lane];
#pragma unroll
  for (int k = 0; k < 64; ++k) w3[k] = WB[k * 64 + lane];
  float b2 = Wab[lane];
  int cperm = (lane & 15) * 4 + (lane >> 4);
  int wave = (blockIdx.x * blockDim.x + tid) >> 6;
  int nwaves = (gridDim.x * blockDim.x) >> 6;
  for (int r = wave; r < nrows; r += nwaves) {
    float hv = h[(size_t)r * 64 + lane];
    float t1 = b1;
#pragma unroll
    for (int k = 0; k < 64; ++k) t1 = fmaf(bcast(hv, k), w1[k], t1);  // ht
    float t2 = b2;
    float t3 = 0.f;
#pragma unroll
    for (int k = 0; k < 64; ++k) {
      float tb = bcast(t1, k);
      t2 = fmaf(tb, w2[k], t2);  // htA (+Web)
      t3 = fmaf(tb, w3[k], t3);  // htB
    }
    htP[(size_t)r * 64 + cperm] = ((uint32)f2bu(t2) << 16) | (uint32)f2bu(t1);
    htBb[(size_t)r * 64 + lane] = f2bu(t3);
  }
}

// ---------------- e = relu(hA[src]+hB[dst]+ea_s@We0c) -> bf16 ----------------
__global__ void k_edgeinit(const unsigned short* __restrict__ hAb,
                           const unsigned short* __restrict__ hBb,
                           const float* __restrict__ ea_s, const float* __restrict__ Wc,
                           const int* __restrict__ srcs, const int* __restrict__ dsts,
                           __hip_bfloat16* __restrict__ ebf) {
  int tid = threadIdx.x;
  int lane = tid & 63;
  float w[FEDGE];
#pragma unroll
  for (int k = 0; k < FEDGE; ++k) w[k] = Wc[k * 64 + lane];
  int wave = (blockIdx.x * blockDim.x + tid) >> 6;
  int nwaves = (gridDim.x * blockDim.x) >> 6;
  const int npairs = N_EDGESC / 2;
  int per = (npairs + nwaves - 1) / nwaves;
  int p0 = wave * per;
  int p1 = min(p0 + per, npairs);
  for (int pr = p0; pr < p1; ++pr) {
    int e = 2 * pr;
    int s0 = srcs[e], d0 = dsts[e];
    int s1 = srcs[e + 1], d1 = dsts[e + 1];
    float av0 = (lane < FEDGE) ? ea_s[(size_t)e * FEDGE + lane] : 0.f;
    float av1 = (lane < FEDGE) ? ea_s[(size_t)(e + 1) * FEDGE + lane] : 0.f;
    unsigned short a0 = hAb[s0 * 64 + lane];
    unsigned short b0 = hBb[d0 * 64 + lane];
    unsigned short a1 = hAb[s1 * 64 + lane];
    unsigned short b1 = hBb[d1 * 64 + lane];
    float acc0 = bu2f(a0) + bu2f(b0);
    float acc1 = bu2f(a1) + bu2f(b1);
#pragma unroll
    for (int k = 0; k < FEDGE; ++k) {
      acc0 = fmaf(bcast(av0, k), w[k], acc0);
      acc1 = fmaf(bcast(av1, k), w[k], acc1);
    }
    acc0 = fmaxf(acc0, 0.f);
    acc1 = fmaxf(acc1, 0.f);
    __builtin_nontemporal_store(f2bu(acc0),
        reinterpret_cast<unsigned short*>(ebf) + (size_t)e * 64 + lane);
    __builtin_nontemporal_store(f2bu(acc1),
        reinterpret_cast<unsigned short*>(ebf) + (size_t)(e + 1) * 64 + lane);
  }
}

// ---------------- edge-gated conv: CSR node-ownership, LDS accumulate, plain stores ----------------
// Inner loop has NO global stores -> vmcnt counts loads only -> cross-iteration overlap.
__global__ void __launch_bounds__(256, 4) k_conv_mfma(
    const __hip_bfloat16* __restrict__ ebf,
    const float* __restrict__ We2,
    const uint32* __restrict__ htP, const unsigned short* __restrict__ htBb,
    const float* __restrict__ normf,
    const int* __restrict__ srcs, const int* __restrict__ dsts,
    const uint32* __restrict__ ptr,
    float* __restrict__ hacc) {
  __shared__ float lds_acc[4][NPW * 65];
  __shared__ float lds_htB[4][NPW * 65];
  const int tid = threadIdx.x;
  const int lane = tid & 63;
  const int w = tid >> 6;
  const int m = lane & 15;
  const int kg = lane >> 4;

  int wave = blockIdx.x * 4 + w;
  int n0 = wave * NPW;
  if (n0 >= N_NODESC) return;

  // B fragments: b[t][s] -> B[k = s*32 + kg*8 + j][c = t*16 + m]
  bf16x8 b[4][2];
#pragma unroll
  for (int t = 0; t < 4; ++t)
#pragma unroll
    for (int s = 0; s < 2; ++s)
#pragma unroll
      for (int j = 0; j < 8; ++j) {
        int k = s * 32 + kg * 8 + j;
        int c = t * 16 + m;
        b[t][s][j] = (__bf16)We2[k * 64 + c];
      }

  float* acc_l = lds_acc[w];
  float* htB_l = lds_htB[w];
#pragma unroll
  for (int r = 0; r < NPW; ++r) {
    acc_l[r * 65 + lane] = 0.f;
    htB_l[r * 65 + lane] = bu2f(htBb[(size_t)(n0 + r) * 64 + lane]);
  }

  int e0 = (int)ptr[n0];
  int eend = (int)ptr[n0 + NPW];
  int tb0 = e0 & ~15;

  float run[4] = {0.f, 0.f, 0.f, 0.f};
  int dcur = -1, rcur = 0;

  for (int tb = tb0; tb < eend; tb += 16) {
    // ---- loads (only VMEM in loop) ----
    const bf16x8* arow = reinterpret_cast<const bf16x8*>(ebf + (size_t)(tb + m) * 64 + kg * 8);
    bf16x8 a0 = __builtin_nontemporal_load(arow);
    bf16x8 a1 = __builtin_nontemporal_load(arow + 4);
    int rb = tb + kg * 4;
    int4 sev = *reinterpret_cast<const int4*>(srcs + rb);
    int4 dev = *reinterpret_cast<const int4*>(dsts + rb);
    float4 nev = *reinterpret_cast<const float4*>(normf + rb);
    int se[4] = {sev.x, sev.y, sev.z, sev.w};
    int de[4] = {dev.x, dev.y, dev.z, dev.w};
    float ne[4] = {nev.x, nev.y, nev.z, nev.w};
    uint4 pv[4];
#pragma unroll
    for (int j = 0; j < 4; ++j)
      pv[j] = *reinterpret_cast<const uint4*>(htP + (size_t)se[j] * 64 + m * 4);

    // ---- MFMA ----
    f32x4 acc[4];
#pragma unroll
    for (int t = 0; t < 4; ++t) {
      f32x4 z = {0.f, 0.f, 0.f, 0.f};
      acc[t] = __builtin_amdgcn_mfma_f32_16x16x32_bf16(a0, b[t][0], z, 0, 0, 0);
      acc[t] = __builtin_amdgcn_mfma_f32_16x16x32_bf16(a1, b[t][1], acc[t], 0, 0, 0);
    }

    // ---- msg + LDS run-accumulate (DS ops only; kg-uniform branches) ----
#pragma unroll
    for (int j = 0; j < 4; ++j) {
      int eidx = rb + j;
      bool valid = (eidx >= e0) && (eidx < eend);
      if (valid) {
        if (de[j] != dcur) {
          if (dcur >= 0) {
#pragma unroll
            for (int t = 0; t < 4; ++t) {
              atomicAdd(&acc_l[rcur * 65 + t * 16 + m], run[t]);
              run[t] = 0.f;
            }
          }
          dcur = de[j];
          rcur = dcur - n0;
        }
        uint32 pd[4] = {pv[j].x, pv[j].y, pv[j].z, pv[j].w};
#pragma unroll
        for (int t = 0; t < 4; ++t) {
          int c = t * 16 + m;
          float gate = acc[t][j] + bu2f((unsigned short)(pd[t] >> 16)) + htB_l[rcur * 65 + c];
          float sig = 1.0f / (1.0f + __expf(-gate));
          run[t] = fmaf(ne[j] * bu2f((unsigned short)(pd[t] & 0xffffu)), sig, run[t]);
        }
      }
    }
  }
  if (dcur >= 0) {
#pragma unroll
    for (int t = 0; t < 4; ++t)
      atomicAdd(&acc_l[rcur * 65 + t * 16 + m], run[t]);
  }
  // ---- epilogue: plain coalesced stores (wave owns its nodes exclusively) ----
#pragma unroll
  for (int r = 0; r < NPW; ++r)
    hacc[(size_t)(n0 + r) * 64 + lane] = acc_l[r * 65 + lane];
}

// ---------------- h = relu(in), column stats of result ----------------
__global__ void k_relu_stats(const float* __restrict__ in, float* __restrict__ h,
                             float* __restrict__ stats, int nrows) {
  int tid = threadIdx.x;
  float s = 0.f, s2 = 0.f;
  int total = nrows * 64;
  for (int i = blockIdx.x * 256 + tid; i < total; i += gridDim.x * 256) {
    float v = fmaxf(in[i], 0.f);
    h[i] = v;
    s += v; s2 += v * v;
  }
  __shared__ float ls[256], ls2[256];
  ls[tid] = s; ls2[tid] = s2;
  __syncthreads();
  for (int off = 128; off >= 64; off >>= 1) {
    if (tid < off) { ls[tid] += ls[tid + off]; ls2[tid] += ls2[tid + off]; }
    __syncthreads();
  }
  if (tid < 64) {
    atomicAdd(&stats[tid], ls[tid]);
    atomicAdd(&stats[64 + tid], ls2[tid]);
  }
}

// ---------------- global_add_pool (batch is sorted) ----------------
__global__ void k_pool(const float* __restrict__ h, const int* __restrict__ batch,
                       float* __restrict__ g) {
  int lane = threadIdx.x & 63;
  int wave = (blockIdx.x * blockDim.x + threadIdx.x) >> 6;
  int nwaves = (gridDim.x * blockDim.x) >> 6;
  int chunk = (N_NODESC + nwaves - 1) / nwaves;
  int r0 = wave * chunk;
  int r1 = min(r0 + chunk, N_NODESC);
  if (r0 >= r1) return;
  int cur = batch[r0];
  float acc = 0.f;
  for (int r = r0; r < r1; ++r) {
    int b = batch[r];
    if (b != cur) {
      atomicAdd(&g[cur * 64 + lane], acc);
      acc = 0.f;
      cur = b;
    }
    acc += h[r * 64 + lane];
  }
  atomicAdd(&g[cur * 64 + lane], acc);
}

// ---------------- classifier + log_softmax ----------------
__global__ void k_cls(const float* __restrict__ g2, const float* __restrict__ Wc,
                      const float* __restrict__ bc, float* __restrict__ out) {
  int r = blockIdx.x * blockDim.x + threadIdx.x;
  if (r >= N_GRAPHSC) return;
  float z[NCLS];
#pragma unroll
  for (int c = 0; c < NCLS; ++c) z[c] = bc[c];
  for (int k = 0; k < HDIM; ++k) {
    float v = g2[r * HDIM + k];
#pragma unroll
    for (int c = 0; c < NCLS; ++c) z[c] = fmaf(v, Wc[k * NCLS + c], z[c]);
  }
  float m = z[0];
#pragma unroll
  for (int c = 1; c < NCLS; ++c) m = fmaxf(m, z[c]);
  float ssum = 0.f;
#pragma unroll
  for (int c = 0; c < NCLS; ++c) ssum += __expf(z[c] - m);
  float l = __logf(ssum);
#pragma unroll
  for (int c = 0; c < NCLS; ++c) out[r * NCLS + c] = z[c] - m - l;
}

extern "C" void kernel_launch(void* const* d_in, const int* in_sizes, int n_in,
                              void* d_out, int out_size, void* d_ws, size_t ws_size,
                              hipStream_t stream) {
  const float* x         = (const float*)d_in[0];
  const float* edge_attr = (const float*)d_in[1];
  const int*   ei        = (const int*)d_in[2];
  const int*   batch     = (const int*)d_in[3];
  const float* bn_feat_w = (const float*)d_in[4];
  const float* bn_feat_b = (const float*)d_in[5];
  const float* Wn0       = (const float*)d_in[6];
  const float* bn0       = (const float*)d_in[7];
  const float* We0       = (const float*)d_in[8];
  const float* be0       = (const float*)d_in[9];
  const float* bns_w     = (const float*)d_in[10];
  const float* bns_b     = (const float*)d_in[11];
  const float* Wn        = (const float*)d_in[12];
  const float* Wnb       = (const float*)d_in[13];
  const float* We        = (const float*)d_in[14];
  const float* Web       = (const float*)d_in[15];
  const float* bn_fc_w   = (const float*)d_in[16];
  const float* bn_fc_b   = (const float*)d_in[17];
  const float* Wfc       = (const float*)d_in[18];
  const float* bfc       = (const float*)d_in[19];
  const float* bn_hid_w  = (const float*)d_in[20];
  const float* bn_hid_b  = (const float*)d_in[21];
  const float* Wcls      = (const float*)d_in[22];
  const float* bcls      = (const float*)d_in[23];
  float* out = (float*)d_out;
  const int* src = ei;
  const int* dst = ei + N_EDGESC;

  char* p = (char*)d_ws;
  auto carve = [&](size_t bytes) {
    char* q = p;
    p += (bytes + 255) & ~(size_t)255;
    return q;
  };
  __hip_bfloat16* ebf = (__hip_bfloat16*)carve((size_t)N_EDGESC * 64 * 2);
  float* h    = (float*)carve((size_t)N_NODESC * 64 * 4);
  float* hacc = (float*)carve((size_t)N_NODESC * 64 * 4);
  uint32* htP = (uint32*)carve((size_t)N_NODESC * 64 * 4);       // {bf16 ht, bf16 htA}, col-permuted
  unsigned short* htBb = (unsigned short*)carve((size_t)N_NODESC * 64 * 2);  // linear
  unsigned short* hAb  = (unsigned short*)carve((size_t)N_NODESC * 64 * 2);
  unsigned short* hBb  = (unsigned short*)carve((size_t)N_NODESC * 64 * 2);
  float* dinv = (float*)carve((size_t)N_NODESC * 4);
  float* g    = (float*)carve((size_t)N_GRAPHSC * 64 * 4);
  float* g2   = (float*)carve((size_t)N_GRAPHSC * 64 * 4);
  float* stats= (float*)carve(2 * 64 * 4);
  float* Wf   = (float*)carve(64 * 64 * 4);
  float* bf   = (float*)carve(64 * 4);
  uint32* degi   = (uint32*)carve((size_t)50176 * 4);
  uint32* ptr    = (uint32*)carve((size_t)50176 * 4);
  uint32* cursor = (uint32*)carve((size_t)50176 * 4);
  uint32* bsum   = (uint32*)carve(256 * 4);
  int* srcs  = (int*)carve((size_t)N_EDGESC * 4);
  int* dsts  = (int*)carve((size_t)N_EDGESC * 4);
  float* ea_s  = (float*)carve((size_t)N_EDGESC * FEDGE * 4);
  float* normf = (float*)carve((size_t)N_EDGESC * 4);

  // ---- degree, dinv, dst-sorted edge permutation (CSR) ----
  hipMemsetAsync(degi, 0, 50176 * 4, stream);
  k_deg<<<(N_EDGESC + 255) / 256, 256, 0, stream>>>(dst, degi);
  k_dinv<<<(N_NODESC + 255) / 256, 256, 0, stream>>>(degi, dinv);
  k_scan1<<<SCAN_G, SCAN_B, 0, stream>>>(degi, ptr, bsum);
  k_scan2<<<1, 256, 0, stream>>>(bsum);
  k_scan3<<<SCAN_G, SCAN_B, 0, stream>>>(ptr, bsum);
  hipMemsetAsync(cursor, 0, 50176 * 4, stream);
  k_scatter<<<(N_EDGESC + 255) / 256, 256, 0, stream>>>(src, dst, edge_attr, dinv, ptr, cursor,
                                                        srcs, dsts, ea_s, normf);

  // ---- h0 = BN(x)@Wn0 + bn0 (BN folded) ----
  hipMemsetAsync(stats, 0, 512, stream);
  k_colstats<FNODE><<<256, 256, 0, stream>>>(x, N_NODESC, stats);
  k_foldbn<FNODE, HDIM><<<1, 256, 0, stream>>>(stats, 1.f / N_NODESC, bn_feat_w, bn_feat_b, Wn0, bn0, Wf, bf);
  k_nodemm<FNODE, false, FNODE, 64><<<512, 256, 0, stream>>>(x, N_NODESC, Wf, bf, h);

  // ---- edge features (sorted order): fused hA/hB bf16 ----
  k_nodemm_b2<<<512, 256, 0, stream>>>(h, N_NODESC, We0, be0, We0 + 64 * 64, hAb, hBb);
  k_edgeinit<<<1024, 256, 0, stream>>>(hAb, hBb, ea_s, We0 + 128 * 64, srcs, dsts, ebf);

  // ---- h = relu(h0), stats(h) ----
  hipMemsetAsync(stats, 0, 512, stream);
  k_relu_stats<<<256, 256, 0, stream>>>(h, h, stats, N_NODESC);

  const int convBlocks = (N_NODESC / NPW + 3) / 4;  // 6250 waves / 4 per block
  for (int i = 0; i < 3; ++i) {
    const float* WeI = We + (size_t)i * 192 * 64;
    k_node3<<<512, 256, 0, stream>>>(h, N_NODESC, stats, 1.f / N_NODESC,
                                     bns_w + i * 64, bns_b + i * 64,
                                     Wn + (size_t)i * 64 * 64, Wnb + i * 64,
                                     WeI, Web + i * 64, WeI + 64 * 64, htP, htBb);
    k_conv_mfma<<<convBlocks, 256, 0, stream>>>(ebf, WeI + 128 * 64, htP, htBb, normf,
                                                srcs, dsts, ptr, hacc);
    hipMemsetAsync(stats, 0, 512, stream);
    k_relu_stats<<<256, 256, 0, stream>>>(hacc, h, stats, N_NODESC);
  }

  // ---- pool + head ----
  hipMemsetAsync(g, 0, N_GRAPHSC * 64 * 4, stream);
  k_pool<<<64, 256, 0, stream>>>(h, batch, g);
  hipMemsetAsync(stats, 0, 512, stream);
  k_colstats<HDIM><<<32, 256, 0, stream>>>(g, N_GRAPHSC, stats);
  k_foldbn<HDIM, HDIM><<<1, 256, 0, stream>>>(stats, 1.f / N_GRAPHSC, bn_fc_w, bn_fc_b, Wfc, bfc, Wf, bf);
  k_nodemm<HDIM, true, 64, 64><<<128, 256, 0, stream>>>(g, N_GRAPHSC, Wf, bf, g2);
  hipMemsetAsync(stats, 0, 512, stream);
  k_colstats<HDIM><<<32, 256, 0, stream>>>(g2, N_GRAPHSC, stats);
  k_foldbn<HDIM, NCLS><<<1, 256, 0, stream>>>(stats, 1.f / N_GRAPHSC, bn_hid_w, bn_hid_b, Wcls, bcls, Wf, bf);
  k_cls<<<(N_GRAPHSC + 255) / 256, 256, 0, stream>>>(g2, Wf, bf, out);
}

// Round 11
// 793.237 us; speedup vs baseline: 1.6284x; 1.1007x over previous
//
#include <hip/hip_runtime.h>
#include <hip/hip_bf16.h>

#define N_NODESC 50000
#define N_EDGESC 800000
#define N_GRAPHSC 512
#define HDIM 64
#define FNODE 32
#define FEDGE 8
#define NCLS 10
#define BN_EPS 1e-5f
#define SCAN_B 256
#define SCAN_G 196  // 196*256 = 50176 >= 50000
#define NPW 8       // nodes per wave in conv

typedef __bf16 bf16x8 __attribute__((ext_vector_type(8)));
typedef float f32x4 __attribute__((ext_vector_type(4)));
typedef unsigned int uint32;

static __device__ __forceinline__ float bcast(float v, int k) {
  return __uint_as_float(__builtin_amdgcn_readlane(__float_as_uint(v), k));
}
static __device__ __forceinline__ unsigned short f2bu(float f) {
  __hip_bfloat16 b = __float2bfloat16(f);
  return *reinterpret_cast<unsigned short*>(&b);
}
static __device__ __forceinline__ float bu2f(unsigned short u) {
  __hip_bfloat16 b;
  *reinterpret_cast<unsigned short*>(&b) = u;
  return __bfloat162float(b);
}

// ---------------- degree ----------------
__global__ void k_deg(const int* __restrict__ dst, uint32* __restrict__ degi) {
  int e = blockIdx.x * blockDim.x + threadIdx.x;
  if (e < N_EDGESC) atomicAdd(&degi[dst[e]], 1u);
}

__global__ void k_dinv(const uint32* __restrict__ degi, float* __restrict__ dinv) {
  int n = blockIdx.x * blockDim.x + threadIdx.x;
  if (n < N_NODESC) dinv[n] = rsqrtf(fmaxf((float)degi[n], 1.0f));
}

// ---------------- exclusive prefix sum over degi -> ptr ----------------
__global__ void k_scan1(const uint32* __restrict__ degi, uint32* __restrict__ ptr,
                        uint32* __restrict__ bsum) {
  __shared__ uint32 s[SCAN_B];
  int t = threadIdx.x;
  int i = blockIdx.x * SCAN_B + t;
  uint32 v = (i < N_NODESC) ? degi[i] : 0u;
  s[t] = v; __syncthreads();
  for (int off = 1; off < SCAN_B; off <<= 1) {
    uint32 x = (t >= off) ? s[t - off] : 0u; __syncthreads();
    s[t] += x; __syncthreads();
  }
  if (i < N_NODESC) ptr[i] = s[t] - v;  // exclusive local scan
  if (t == SCAN_B - 1) bsum[blockIdx.x] = s[t];
}

__global__ void k_scan2(uint32* __restrict__ bsum) {
  __shared__ uint32 s[256];
  int t = threadIdx.x;
  uint32 v = (t < SCAN_G) ? bsum[t] : 0u;
  s[t] = v; __syncthreads();
  for (int off = 1; off < 256; off <<= 1) {
    uint32 x = (t >= off) ? s[t - off] : 0u; __syncthreads();
    s[t] += x; __syncthreads();
  }
  if (t < SCAN_G) bsum[t] = s[t] - v;  // exclusive
}

__global__ void k_scan3(uint32* __restrict__ ptr, const uint32* __restrict__ bsum) {
  int i = blockIdx.x * SCAN_B + threadIdx.x;
  if (i < N_NODESC) ptr[i] += bsum[blockIdx.x];
  if (blockIdx.x == 0 && threadIdx.x == 0) ptr[N_NODESC] = N_EDGESC;  // CSR sentinel
}

// ---------------- scatter edges into dst-sorted order (+ea permute, +normf) ----------------
__global__ void k_scatter(const int* __restrict__ src, const int* __restrict__ dst,
                          const float* __restrict__ ea, const float* __restrict__ dinv,
                          const uint32* __restrict__ ptr, uint32* __restrict__ cursor,
                          int* __restrict__ srcs, int* __restrict__ dsts,
                          float* __restrict__ ea_s, float* __restrict__ normf) {
  int e = blockIdx.x * blockDim.x + threadIdx.x;
  if (e < N_EDGESC) {
    int d = dst[e];
    int s = src[e];
    float4 a0 = *reinterpret_cast<const float4*>(ea + (size_t)e * FEDGE);
    float4 a1 = *reinterpret_cast<const float4*>(ea + (size_t)e * FEDGE + 4);
    uint32 r = atomicAdd(&cursor[d], 1u);
    uint32 i = ptr[d] + r;
    srcs[i] = s;
    dsts[i] = d;
    normf[i] = dinv[s] * dinv[d];
    *reinterpret_cast<float4*>(ea_s + (size_t)i * FEDGE) = a0;
    *reinterpret_cast<float4*>(ea_s + (size_t)i * FEDGE + 4) = a1;
  }
}

// ---------------- column stats (sum, sumsq) into a slot ----------------
template <int C>
__global__ void k_colstats(const float* __restrict__ in, int nrows, float* __restrict__ stats) {
  const int RPB = 256 / C;
  int tid = threadIdx.x;
  int col = tid % C;
  int rowOff = tid / C;
  float s = 0.f, s2 = 0.f;
  for (int r = blockIdx.x * RPB + rowOff; r < nrows; r += gridDim.x * RPB) {
    float v = in[r * C + col];
    s += v; s2 += v * v;
  }
  __shared__ float ls[256], ls2[256];
  ls[tid] = s; ls2[tid] = s2;
  __syncthreads();
  for (int off = 128; off >= C; off >>= 1) {
    if (tid < off) { ls[tid] += ls[tid + off]; ls2[tid] += ls2[tid + off]; }
    __syncthreads();
  }
  if (tid < C) {
    atomicAdd(&stats[tid], ls[tid]);
    atomicAdd(&stats[C + tid], ls2[tid]);
  }
}

// ---------------- fold BN into weights (stage0 & head) ----------------
template <int CIN, int COUT>
__global__ void k_foldbn(const float* __restrict__ stats, float invN,
                         const float* __restrict__ bnw, const float* __restrict__ bnb,
                         const float* __restrict__ W, const float* __restrict__ bias,
                         float* __restrict__ Wf, float* __restrict__ bf) {
  __shared__ float a[CIN], sh[CIN];
  int tid = threadIdx.x;
  if (tid < CIN) {
    float m = stats[tid] * invN;
    float v = stats[CIN + tid] * invN - m * m;
    float inv = rsqrtf(v + BN_EPS);
    float aa = bnw[tid] * inv;
    a[tid] = aa;
    sh[tid] = bnb[tid] - m * aa;
  }
  __syncthreads();
  for (int i = tid; i < CIN * COUT; i += 256) {
    int r = i / COUT;
    Wf[i] = a[r] * W[i];
  }
  if (tid < COUT) {
    float acc = bias ? bias[tid] : 0.f;
    for (int r = 0; r < CIN; ++r) acc += sh[r] * W[r * COUT + tid];
    bf[tid] = acc;
  }
}

// ---------------- head matmul: out[N,64] = in @ W + bias, relu ----------------
template <int K, bool RELU>
__global__ void k_nodemm(const float* __restrict__ in, int nrows,
                         const float* __restrict__ W, const float* __restrict__ bias,
                         float* __restrict__ out) {
  int tid = threadIdx.x;
  int lane = tid & 63;
  float w[K];
#pragma unroll
  for (int k = 0; k < K; ++k) w[k] = W[k * 64 + lane];
  float bv = bias ? bias[lane] : 0.f;
  int wave = (blockIdx.x * blockDim.x + tid) >> 6;
  int nwaves = (gridDim.x * blockDim.x) >> 6;
  for (int r = wave; r < nrows; r += nwaves) {
    float rv = (lane < K) ? in[(size_t)r * K + lane] : 0.f;
    float acc = bv;
#pragma unroll
    for (int k = 0; k < K; ++k) acc = fmaf(bcast(rv, k), w[k], acc);
    if (RELU) acc = fmaxf(acc, 0.f);
    out[(size_t)r * 64 + lane] = acc;
  }
}

// ---------------- fused stage0: h0 = x@Wf+bf; hA = h0@WA+bA; hB = h0@WB; h = relu(h0) ----------------
__global__ void __launch_bounds__(256, 2) k_stage0(
    const float* __restrict__ x, int nrows,
    const float* __restrict__ Wf, const float* __restrict__ bfv,
    const float* __restrict__ WA, const float* __restrict__ bA,
    const float* __restrict__ WB,
    float* __restrict__ h, unsigned short* __restrict__ hAb,
    unsigned short* __restrict__ hBb) {
  int tid = threadIdx.x;
  int lane = tid & 63;
  float w0[FNODE], wA[64], wB[64];
#pragma unroll
  for (int k = 0; k < FNODE; ++k) w0[k] = Wf[k * 64 + lane];
#pragma unroll
  for (int k = 0; k < 64; ++k) wA[k] = WA[k * 64 + lane];
#pragma unroll
  for (int k = 0; k < 64; ++k) wB[k] = WB[k * 64 + lane];
  float b0 = bfv[lane];
  float b2 = bA[lane];
  int wave = (blockIdx.x * blockDim.x + tid) >> 6;
  int nwaves = (gridDim.x * blockDim.x) >> 6;
  for (int r = wave; r < nrows; r += nwaves) {
    float xv = (lane < FNODE) ? x[(size_t)r * FNODE + lane] : 0.f;
    float t0 = b0;
#pragma unroll
    for (int k = 0; k < FNODE; ++k) t0 = fmaf(bcast(xv, k), w0[k], t0);  // h0 (pre-relu)
    float aA = b2, aB = 0.f;
#pragma unroll
    for (int k = 0; k < 64; ++k) {
      float tb = bcast(t0, k);
      aA = fmaf(tb, wA[k], aA);
      aB = fmaf(tb, wB[k], aB);
    }
    h[(size_t)r * 64 + lane] = fmaxf(t0, 0.f);
    hAb[(size_t)r * 64 + lane] = f2bu(aA);
    hBb[(size_t)r * 64 + lane] = f2bu(aB);
  }
}

// ---------------- fused per-conv node prep (inline BN fold): ht, htA, htB ----------------
// htP col-PERMUTED (c' = (c&15)*4 + (c>>4)); htBb LINEAR.
__global__ void __launch_bounds__(256, 2) k_node3(
    const float* __restrict__ h, int nrows,
    const float* __restrict__ stats, float invN,
    const float* __restrict__ bnw, const float* __restrict__ bnb,
    const float* __restrict__ Wn_i, const float* __restrict__ Wnb_i,
    const float* __restrict__ WA, const float* __restrict__ Wab,
    const float* __restrict__ WB,
    uint32* __restrict__ htP, unsigned short* __restrict__ htBb) {
  __shared__ float a_s[64], sh_s[64];
  int tid = threadIdx.x;
  int lane = tid & 63;
  if (tid < 64) {
    float m = stats[tid] * invN;
    float v = stats[64 + tid] * invN - m * m;
    float inv = rsqrtf(v + BN_EPS);
    float aa = bnw[tid] * inv;
    a_s[tid] = aa;
    sh_s[tid] = bnb[tid] - m * aa;
  }
  __syncthreads();
  float w1[64], w2[64], w3[64];
  float b1 = Wnb_i[lane];
#pragma unroll
  for (int k = 0; k < 64; ++k) {
    float raw = Wn_i[k * 64 + lane];
    w1[k] = a_s[k] * raw;
    b1 = fmaf(sh_s[k], raw, b1);
  }
#pragma unroll
  for (int k = 0; k < 64; ++k) w2[k] = WA[k * 64 + lane];
#pragma unroll
  for (int k = 0; k < 64; ++k) w3[k] = WB[k * 64 + lane];
  float b2 = Wab[lane];
  int cperm = (lane & 15) * 4 + (lane >> 4);
  int wave = (blockIdx.x * blockDim.x + tid) >> 6;
  int nwaves = (gridDim.x * blockDim.x) >> 6;
  for (int r = wave; r < nrows; r += nwaves) {
    float hv = h[(size_t)r * 64 + lane];
    float t1 = b1;
#pragma unroll
    for (int k = 0; k < 64; ++k) t1 = fmaf(bcast(hv, k), w1[k], t1);  // ht
    float t2 = b2;
    float t3 = 0.f;
#pragma unroll
    for (int k = 0; k < 64; ++k) {
      float tb = bcast(t1, k);
      t2 = fmaf(tb, w2[k], t2);  // htA (+Web)
      t3 = fmaf(tb, w3[k], t3);  // htB
    }
    htP[(size_t)r * 64 + cperm] = ((uint32)f2bu(t2) << 16) | (uint32)f2bu(t1);
    htBb[(size_t)r * 64 + lane] = f2bu(t3);
  }
}

// ---------------- e = relu(hA[src]+hB[dst]+ea_s@We0c) -> bf16 (4-edge batched) ----------------
__global__ void k_edgeinit(const unsigned short* __restrict__ hAb,
                           const unsigned short* __restrict__ hBb,
                           const float* __restrict__ ea_s, const float* __restrict__ Wc,
                           const int* __restrict__ srcs, const int* __restrict__ dsts,
                           __hip_bfloat16* __restrict__ ebf) {
  int tid = threadIdx.x;
  int lane = tid & 63;
  float w[FEDGE];
#pragma unroll
  for (int k = 0; k < FEDGE; ++k) w[k] = Wc[k * 64 + lane];
  int wave = (blockIdx.x * blockDim.x + tid) >> 6;
  int nwaves = (gridDim.x * blockDim.x) >> 6;
  const int nquads = N_EDGESC / 4;
  int per = (nquads + nwaves - 1) / nwaves;
  int p0 = wave * per;
  int p1 = min(p0 + per, nquads);
  for (int pr = p0; pr < p1; ++pr) {
    int e = 4 * pr;
    int s0 = srcs[e],     d0 = dsts[e];
    int s1 = srcs[e + 1], d1 = dsts[e + 1];
    int s2 = srcs[e + 2], d2 = dsts[e + 2];
    int s3 = srcs[e + 3], d3 = dsts[e + 3];
    bool el = (lane < FEDGE);
    float av0 = el ? ea_s[(size_t)e * FEDGE + lane] : 0.f;
    float av1 = el ? ea_s[(size_t)(e + 1) * FEDGE + lane] : 0.f;
    float av2 = el ? ea_s[(size_t)(e + 2) * FEDGE + lane] : 0.f;
    float av3 = el ? ea_s[(size_t)(e + 3) * FEDGE + lane] : 0.f;
    unsigned short a0 = hAb[s0 * 64 + lane], b0 = hBb[d0 * 64 + lane];
    unsigned short a1 = hAb[s1 * 64 + lane], b1 = hBb[d1 * 64 + lane];
    unsigned short a2 = hAb[s2 * 64 + lane], b2 = hBb[d2 * 64 + lane];
    unsigned short a3 = hAb[s3 * 64 + lane], b3 = hBb[d3 * 64 + lane];
    float acc0 = bu2f(a0) + bu2f(b0);
    float acc1 = bu2f(a1) + bu2f(b1);
    float acc2 = bu2f(a2) + bu2f(b2);
    float acc3 = bu2f(a3) + bu2f(b3);
#pragma unroll
    for (int k = 0; k < FEDGE; ++k) {
      acc0 = fmaf(bcast(av0, k), w[k], acc0);
      acc1 = fmaf(bcast(av1, k), w[k], acc1);
      acc2 = fmaf(bcast(av2, k), w[k], acc2);
      acc3 = fmaf(bcast(av3, k), w[k], acc3);
    }
    unsigned short* ob = reinterpret_cast<unsigned short*>(ebf);
    __builtin_nontemporal_store(f2bu(fmaxf(acc0, 0.f)), ob + (size_t)e * 64 + lane);
    __builtin_nontemporal_store(f2bu(fmaxf(acc1, 0.f)), ob + (size_t)(e + 1) * 64 + lane);
    __builtin_nontemporal_store(f2bu(fmaxf(acc2, 0.f)), ob + (size_t)(e + 2) * 64 + lane);
    __builtin_nontemporal_store(f2bu(fmaxf(acc3, 0.f)), ob + (size_t)(e + 3) * 64 + lane);
  }
}

// ---------------- edge-gated conv: CSR node-ownership, LDS accumulate, h=relu out ----------------
__global__ void __launch_bounds__(256, 4) k_conv_mfma(
    const __hip_bfloat16* __restrict__ ebf,
    const float* __restrict__ We2,
    const uint32* __restrict__ htP, const unsigned short* __restrict__ htBb,
    const float* __restrict__ normf,
    const int* __restrict__ srcs, const int* __restrict__ dsts,
    const uint32* __restrict__ ptr,
    float* __restrict__ hout) {
  __shared__ float lds_acc[4][NPW * 65];
  __shared__ float lds_htB[4][NPW * 65];
  const int tid = threadIdx.x;
  const int lane = tid & 63;
  const int w = tid >> 6;
  const int m = lane & 15;
  const int kg = lane >> 4;

  int wave = blockIdx.x * 4 + w;
  int n0 = wave * NPW;
  if (n0 >= N_NODESC) return;

  // B fragments: b[t][s] -> B[k = s*32 + kg*8 + j][c = t*16 + m]
  bf16x8 b[4][2];
#pragma unroll
  for (int t = 0; t < 4; ++t)
#pragma unroll
    for (int s = 0; s < 2; ++s)
#pragma unroll
      for (int j = 0; j < 8; ++j) {
        int k = s * 32 + kg * 8 + j;
        int c = t * 16 + m;
        b[t][s][j] = (__bf16)We2[k * 64 + c];
      }

  float* acc_l = lds_acc[w];
  float* htB_l = lds_htB[w];
#pragma unroll
  for (int r = 0; r < NPW; ++r) {
    acc_l[r * 65 + lane] = 0.f;
    htB_l[r * 65 + lane] = bu2f(htBb[(size_t)(n0 + r) * 64 + lane]);
  }

  int e0 = (int)ptr[n0];
  int eend = (int)ptr[n0 + NPW];
  int tb0 = e0 & ~15;

  float run[4] = {0.f, 0.f, 0.f, 0.f};
  int dcur = -1, rcur = 0;

  // pipelined idx: current tile's idx pre-loaded before the loop
  int rb = tb0 + kg * 4;
  int4 sev = *reinterpret_cast<const int4*>(srcs + rb);
  int4 dev = *reinterpret_cast<const int4*>(dsts + rb);
  float4 nev = *reinterpret_cast<const float4*>(normf + rb);

  for (int tb = tb0; tb < eend; tb += 16) {
    // ---- prefetch next tile's idx (wave-uniform guard) ----
    int4 sev_n = sev, dev_n = dev;
    float4 nev_n = nev;
    int tbn = tb + 16;
    if (tbn < eend) {
      int rbn = tbn + kg * 4;
      sev_n = *reinterpret_cast<const int4*>(srcs + rbn);
      dev_n = *reinterpret_cast<const int4*>(dsts + rbn);
      nev_n = *reinterpret_cast<const float4*>(normf + rbn);
    }
    // ---- current tile loads (pv gathers depend on already-resolved sev) ----
    const bf16x8* arow = reinterpret_cast<const bf16x8*>(ebf + (size_t)(tb + m) * 64 + kg * 8);
    bf16x8 a0 = __builtin_nontemporal_load(arow);
    bf16x8 a1 = __builtin_nontemporal_load(arow + 4);
    int se[4] = {sev.x, sev.y, sev.z, sev.w};
    int de[4] = {dev.x, dev.y, dev.z, dev.w};
    float ne[4] = {nev.x, nev.y, nev.z, nev.w};
    uint4 pv[4];
#pragma unroll
    for (int j = 0; j < 4; ++j)
      pv[j] = *reinterpret_cast<const uint4*>(htP + (size_t)se[j] * 64 + m * 4);

    // ---- MFMA ----
    f32x4 acc[4];
#pragma unroll
    for (int t = 0; t < 4; ++t) {
      f32x4 z = {0.f, 0.f, 0.f, 0.f};
      acc[t] = __builtin_amdgcn_mfma_f32_16x16x32_bf16(a0, b[t][0], z, 0, 0, 0);
      acc[t] = __builtin_amdgcn_mfma_f32_16x16x32_bf16(a1, b[t][1], acc[t], 0, 0, 0);
    }

    // ---- msg + LDS run-accumulate ----
    int rbj = tb + kg * 4;
#pragma unroll
    for (int j = 0; j < 4; ++j) {
      int eidx = rbj + j;
      bool valid = (eidx >= e0) && (eidx < eend);
      if (valid) {
        if (de[j] != dcur) {
          if (dcur >= 0) {
#pragma unroll
            for (int t = 0; t < 4; ++t) {
              atomicAdd(&acc_l[rcur * 65 + t * 16 + m], run[t]);
              run[t] = 0.f;
            }
          }
          dcur = de[j];
          rcur = dcur - n0;
        }
        uint32 pd[4] = {pv[j].x, pv[j].y, pv[j].z, pv[j].w};
#pragma unroll
        for (int t = 0; t < 4; ++t) {
          int c = t * 16 + m;
          float gate = acc[t][j] + bu2f((unsigned short)(pd[t] >> 16)) + htB_l[rcur * 65 + c];
          float sig = 1.0f / (1.0f + __expf(-gate));
          run[t] = fmaf(ne[j] * bu2f((unsigned short)(pd[t] & 0xffffu)), sig, run[t]);
        }
      }
    }
    sev = sev_n; dev = dev_n; nev = nev_n;
  }
  if (dcur >= 0) {
#pragma unroll
    for (int t = 0; t < 4; ++t)
      atomicAdd(&acc_l[rcur * 65 + t * 16 + m], run[t]);
  }
  // ---- epilogue: h = relu(acc), plain coalesced stores ----
#pragma unroll
  for (int r = 0; r < NPW; ++r)
    hout[(size_t)(n0 + r) * 64 + lane] = fmaxf(acc_l[r * 65 + lane], 0.f);
}

// ---------------- global_add_pool (batch is sorted) ----------------
__global__ void k_pool(const float* __restrict__ h, const int* __restrict__ batch,
                       float* __restrict__ g) {
  int lane = threadIdx.x & 63;
  int wave = (blockIdx.x * blockDim.x + threadIdx.x) >> 6;
  int nwaves = (gridDim.x * blockDim.x) >> 6;
  int chunk = (N_NODESC + nwaves - 1) / nwaves;
  int r0 = wave * chunk;
  int r1 = min(r0 + chunk, N_NODESC);
  if (r0 >= r1) return;
  int cur = batch[r0];
  float acc = 0.f;
  for (int r = r0; r < r1; ++r) {
    int b = batch[r];
    if (b != cur) {
      atomicAdd(&g[cur * 64 + lane], acc);
      acc = 0.f;
      cur = b;
    }
    acc += h[r * 64 + lane];
  }
  atomicAdd(&g[cur * 64 + lane], acc);
}

// ---------------- classifier + log_softmax ----------------
__global__ void k_cls(const float* __restrict__ g2, const float* __restrict__ Wc,
                      const float* __restrict__ bc, float* __restrict__ out) {
  int r = blockIdx.x * blockDim.x + threadIdx.x;
  if (r >= N_GRAPHSC) return;
  float z[NCLS];
#pragma unroll
  for (int c = 0; c < NCLS; ++c) z[c] = bc[c];
  for (int k = 0; k < HDIM; ++k) {
    float v = g2[r * HDIM + k];
#pragma unroll
    for (int c = 0; c < NCLS; ++c) z[c] = fmaf(v, Wc[k * NCLS + c], z[c]);
  }
  float m = z[0];
#pragma unroll
  for (int c = 1; c < NCLS; ++c) m = fmaxf(m, z[c]);
  float ssum = 0.f;
#pragma unroll
  for (int c = 0; c < NCLS; ++c) ssum += __expf(z[c] - m);
  float l = __logf(ssum);
#pragma unroll
  for (int c = 0; c < NCLS; ++c) out[r * NCLS + c] = z[c] - m - l;
}

extern "C" void kernel_launch(void* const* d_in, const int* in_sizes, int n_in,
                              void* d_out, int out_size, void* d_ws, size_t ws_size,
                              hipStream_t stream) {
  const float* x         = (const float*)d_in[0];
  const float* edge_attr = (const float*)d_in[1];
  const int*   ei        = (const int*)d_in[2];
  const int*   batch     = (const int*)d_in[3];
  const float* bn_feat_w = (const float*)d_in[4];
  const float* bn_feat_b = (const float*)d_in[5];
  const float* Wn0       = (const float*)d_in[6];
  const float* bn0       = (const float*)d_in[7];
  const float* We0       = (const float*)d_in[8];
  const float* be0       = (const float*)d_in[9];
  const float* bns_w     = (const float*)d_in[10];
  const float* bns_b     = (const float*)d_in[11];
  const float* Wn        = (const float*)d_in[12];
  const float* Wnb       = (const float*)d_in[13];
  const float* We        = (const float*)d_in[14];
  const float* Web       = (const float*)d_in[15];
  const float* bn_fc_w   = (const float*)d_in[16];
  const float* bn_fc_b   = (const float*)d_in[17];
  const float* Wfc       = (const float*)d_in[18];
  const float* bfc       = (const float*)d_in[19];
  const float* bn_hid_w  = (const float*)d_in[20];
  const float* bn_hid_b  = (const float*)d_in[21];
  const float* Wcls      = (const float*)d_in[22];
  const float* bcls      = (const float*)d_in[23];
  float* out = (float*)d_out;
  const int* src = ei;
  const int* dst = ei + N_EDGESC;

  char* p = (char*)d_ws;
  auto carve = [&](size_t bytes) {
    char* q = p;
    p += (bytes + 255) & ~(size_t)255;
    return q;
  };
  __hip_bfloat16* ebf = (__hip_bfloat16*)carve((size_t)N_EDGESC * 64 * 2);
  float* h    = (float*)carve((size_t)N_NODESC * 64 * 4);
  uint32* htP = (uint32*)carve((size_t)N_NODESC * 64 * 4);       // {bf16 ht, bf16 htA}, col-permuted
  unsigned short* htBb = (unsigned short*)carve((size_t)N_NODESC * 64 * 2);  // linear
  unsigned short* hAb  = (unsigned short*)carve((size_t)N_NODESC * 64 * 2);
  unsigned short* hBb  = (unsigned short*)carve((size_t)N_NODESC * 64 * 2);
  float* dinv = (float*)carve((size_t)N_NODESC * 4);
  float* g    = (float*)carve((size_t)N_GRAPHSC * 64 * 4);
  float* g2   = (float*)carve((size_t)N_GRAPHSC * 64 * 4);
  float* stats= (float*)carve(6 * 128 * 4);  // 6 slots of 128 floats
  float* Wf   = (float*)carve(64 * 64 * 4);
  float* bf   = (float*)carve(64 * 4);
  uint32* degi   = (uint32*)carve((size_t)50176 * 4);
  uint32* ptr    = (uint32*)carve((size_t)50176 * 4);
  uint32* cursor = (uint32*)carve((size_t)50176 * 4);
  uint32* bsum   = (uint32*)carve(256 * 4);
  int* srcs  = (int*)carve((size_t)N_EDGESC * 4);
  int* dsts  = (int*)carve((size_t)N_EDGESC * 4);
  float* ea_s  = (float*)carve((size_t)N_EDGESC * FEDGE * 4);
  float* normf = (float*)carve((size_t)N_EDGESC * 4);

  float* st_x  = stats;            // x stats (2*32)
  float* st_h0 = stats + 128;      // h after stage0
  float* st_h1 = stats + 256;      // h after conv0
  float* st_h2 = stats + 384;      // h after conv1
  float* st_g  = stats + 512;      // pooled g
  float* st_g2 = stats + 640;      // g2

  // ---- one memset covers degi+ptr+cursor (contiguous carves); one for stats ----
  hipMemsetAsync(degi, 0, (size_t)3 * 50176 * 4, stream);
  hipMemsetAsync(stats, 0, 6 * 128 * 4, stream);

  // ---- degree, dinv, dst-sorted edge permutation (CSR) ----
  k_deg<<<(N_EDGESC + 255) / 256, 256, 0, stream>>>(dst, degi);
  k_dinv<<<(N_NODESC + 255) / 256, 256, 0, stream>>>(degi, dinv);
  k_scan1<<<SCAN_G, SCAN_B, 0, stream>>>(degi, ptr, bsum);
  k_scan2<<<1, 256, 0, stream>>>(bsum);
  k_scan3<<<SCAN_G, SCAN_B, 0, stream>>>(ptr, bsum);
  k_scatter<<<(N_EDGESC + 255) / 256, 256, 0, stream>>>(src, dst, edge_attr, dinv, ptr, cursor,
                                                        srcs, dsts, ea_s, normf);

  // ---- stage0: BN-fold, fused h0/hA/hB/relu ----
  k_colstats<FNODE><<<256, 256, 0, stream>>>(x, N_NODESC, st_x);
  k_foldbn<FNODE, HDIM><<<1, 256, 0, stream>>>(st_x, 1.f / N_NODESC, bn_feat_w, bn_feat_b, Wn0, bn0, Wf, bf);
  k_stage0<<<512, 256, 0, stream>>>(x, N_NODESC, Wf, bf, We0, be0, We0 + 64 * 64, h, hAb, hBb);
  k_edgeinit<<<1024, 256, 0, stream>>>(hAb, hBb, ea_s, We0 + 128 * 64, srcs, dsts, ebf);
  k_colstats<HDIM><<<256, 256, 0, stream>>>(h, N_NODESC, st_h0);

  // ---- 3 conv rounds ----
  const int convBlocks = (N_NODESC / NPW + 3) / 4;
  float* slots[3] = {st_h0, st_h1, st_h2};
  for (int i = 0; i < 3; ++i) {
    const float* WeI = We + (size_t)i * 192 * 64;
    k_node3<<<512, 256, 0, stream>>>(h, N_NODESC, slots[i], 1.f / N_NODESC,
                                     bns_w + i * 64, bns_b + i * 64,
                                     Wn + (size_t)i * 64 * 64, Wnb + i * 64,
                                     WeI, Web + i * 64, WeI + 64 * 64, htP, htBb);
    k_conv_mfma<<<convBlocks, 256, 0, stream>>>(ebf, WeI + 128 * 64, htP, htBb, normf,
                                                srcs, dsts, ptr, h);
    if (i < 2) k_colstats<HDIM><<<256, 256, 0, stream>>>(h, N_NODESC, slots[i + 1]);
  }

  // ---- pool + head ----
  hipMemsetAsync(g, 0, N_GRAPHSC * 64 * 4, stream);
  k_pool<<<64, 256, 0, stream>>>(h, batch, g);
  k_colstats<HDIM><<<32, 256, 0, stream>>>(g, N_GRAPHSC, st_g);
  k_foldbn<HDIM, HDIM><<<1, 256, 0, stream>>>(st_g, 1.f / N_GRAPHSC, bn_fc_w, bn_fc_b, Wfc, bfc, Wf, bf);
  k_nodemm<HDIM, true><<<128, 256, 0, stream>>>(g, N_GRAPHSC, Wf, bf, g2);
  k_colstats<HDIM><<<32, 256, 0, stream>>>(g2, N_GRAPHSC, st_g2);
  k_foldbn<HDIM, NCLS><<<1, 256, 0, stream>>>(st_g2, 1.f / N_GRAPHSC, bn_hid_w, bn_hid_b, Wcls, bcls, Wf, bf);
  k_cls<<<(N_GRAPHSC + 255) / 256, 256, 0, stream>>>(g2, Wf, bf, out);
}